// Round 2
// baseline (4386.610 us; speedup 1.0000x reference)
//
#include <hip/hip_runtime.h>

#define NN 50000
#define NE 500000

// ---------------- zero helpers (avoid hipMemsetAsync under graph capture) ---
__global__ __launch_bounds__(256) void k_zero_f4(float4* __restrict__ p, int n4)
{
  for (int i = blockIdx.x * 256 + threadIdx.x; i < n4; i += gridDim.x * 256)
    p[i] = make_float4(0.f, 0.f, 0.f, 0.f);
}
__global__ __launch_bounds__(256) void k_zero_i(int* __restrict__ p, int n)
{
  for (int i = blockIdx.x * 256 + threadIdx.x; i < n; i += gridDim.x * 256)
    p[i] = 0;
}

// ---------------- embed: x = relu(nf @ We + be), [NN,7]@[7,64] ----------------
__global__ __launch_bounds__(256) void k_embed(
    const float* __restrict__ nf, const float* __restrict__ We,
    const float* __restrict__ be, float* __restrict__ x)
{
  int idx = blockIdx.x * 256 + threadIdx.x;
  int n = idx >> 4, g = idx & 15;
  if (n >= NN) return;
  int j0 = g * 4;
  float4 b4 = *(const float4*)&be[j0];
  float a0 = b4.x, a1 = b4.y, a2 = b4.z, a3 = b4.w;
  #pragma unroll
  for (int k = 0; k < 7; ++k) {
    float v = nf[n * 7 + k];
    float4 w = *(const float4*)&We[k * 64 + j0];
    a0 += v * w.x; a1 += v * w.y; a2 += v * w.z; a3 += v * w.w;
  }
  *(float4*)&x[n * 64 + j0] =
      make_float4(fmaxf(a0, 0.f), fmaxf(a1, 0.f), fmaxf(a2, 0.f), fmaxf(a3, 0.f));
}

// ---------------- degree histogram ----------------
__global__ __launch_bounds__(256) void k_hist(const int* __restrict__ dst, int* __restrict__ cnt)
{
  int e = blockIdx.x * 256 + threadIdx.x;
  if (e < NE) atomicAdd(&cnt[dst[e]], 1);
}

// ---------------- exclusive scan (single block) -> ptr, cur ----------------
__global__ __launch_bounds__(1024) void k_scan(const int* __restrict__ cnt,
                                               int* __restrict__ ptr, int* __restrict__ cur)
{
  __shared__ int s[1024];
  __shared__ int carry_s;
  const int t = threadIdx.x;
  if (t == 0) carry_s = 0;
  __syncthreads();
  for (int base = 0; base < NN; base += 1024) {
    int v = (base + t < NN) ? cnt[base + t] : 0;
    s[t] = v;
    __syncthreads();
    for (int off = 1; off < 1024; off <<= 1) {
      int a = s[t];
      int b = (t >= off) ? s[t - off] : 0;
      __syncthreads();
      s[t] = a + b;
      __syncthreads();
    }
    int carry = carry_s;
    if (base + t < NN) {
      int ex = carry + s[t] - v;   // exclusive
      ptr[base + t] = ex;
      cur[base + t] = ex;
    }
    __syncthreads();
    if (t == 1023) carry_s = carry + s[1023];
    __syncthreads();
  }
  if (t == 0) ptr[NN] = carry_s;
}

// ---------------- CSR fill (also records CSR-ordered dst) ----------------
__global__ __launch_bounds__(256) void k_fill(const int* __restrict__ dst,
                                              int* __restrict__ cur, int* __restrict__ eid,
                                              int* __restrict__ dstc)
{
  int e = blockIdx.x * 256 + threadIdx.x;
  if (e < NE) {
    int d = dst[e];
    int s = atomicAdd(&cur[d], 1);
    eid[s] = e;
    dstc[s] = d;
  }
}

// ---------------- fused edge message MLP + scatter-agg (per layer) ----------
// Processes edges in CSR (dst-sorted) order. For CSR position p, edge e=eid[p]:
//   edge_in = [x[src[e]](64) | x[dst[e]](64) | ea[e](8)]
//   h = relu(edge_in@W1+b1); msg = h@W2+b2; agg[dst[e]] += msg (run-compressed)
// Tile: 64 CSR positions x 128 out, 256 threads, micro-tile 8e x 4j.
// LDS: W1 rows 0..119 (60KB) + W2 (64KB) + A-tile [128][68] (34KB) = 158KB
__global__ __launch_bounds__(256, 1) void k_msg(
    const float* __restrict__ x, const float* __restrict__ ea,
    const int* __restrict__ src, const int* __restrict__ eid,
    const int* __restrict__ dstc,
    const float* __restrict__ W1, const float* __restrict__ b1,
    const float* __restrict__ W2, const float* __restrict__ b2,
    float* __restrict__ agg)
{
  __shared__ __align__(16) float sW1[120 * 128];
  __shared__ __align__(16) float sW2[128 * 128];
  __shared__ __align__(16) float sA[128 * 68];
  const int t = threadIdx.x;
  for (int i = t * 4; i < 120 * 128; i += 1024) *(float4*)&sW1[i] = *(const float4*)&W1[i];
  for (int i = t * 4; i < 128 * 128; i += 1024) *(float4*)&sW2[i] = *(const float4*)&W2[i];

  const int j0 = (t & 31) * 4;   // 0..124
  const int e0 = (t >> 5) * 8;   // 0..56
  const int wv = t >> 6, ln = t & 63;

  // W1 rows 128..135 (edge_attr part) in registers
  float w1t[8][4];
  #pragma unroll
  for (int f = 0; f < 8; ++f) {
    float4 w = *(const float4*)&W1[(128 + f) * 128 + j0];
    w1t[f][0] = w.x; w1t[f][1] = w.y; w1t[f][2] = w.z; w1t[f][3] = w.w;
  }
  const float4 bias1 = *(const float4*)&b1[j0];
  const float4 bias2 = *(const float4*)&b2[j0];
  __syncthreads();

  for (int tile = blockIdx.x; tile < (NE + 63) / 64; tile += gridDim.x) {
    const int ebase = tile * 64;
    __syncthreads();  // previous tile's readers done
    // stage A: wave wv -> CSR positions [wv*16, wv*16+16)
    for (int i = 0; i < 16; ++i) {
      int el = wv * 16 + i;
      int p = ebase + el;
      float vs = 0.f, vd = 0.f;
      if (p < NE) {
        int e = eid[p];          // wave-uniform -> scalar load
        int s_ = src[e];
        int d_ = dstc[p];
        vs = x[(size_t)s_ * 64 + ln];
        vd = x[(size_t)d_ * 64 + ln];
      }
      sA[ln * 68 + el] = vs;
      sA[(64 + ln) * 68 + el] = vd;
    }
    __syncthreads();

    float acc[8][4];
    #pragma unroll
    for (int ee = 0; ee < 8; ++ee) {
      acc[ee][0] = bias1.x; acc[ee][1] = bias1.y; acc[ee][2] = bias1.z; acc[ee][3] = bias1.w;
    }
    // edge_attr contribution
    #pragma unroll
    for (int ee = 0; ee < 8; ++ee) {
      int p = ebase + e0 + ee;
      if (p < NE) {
        int e = eid[p];
        float4 q0 = *(const float4*)&ea[(size_t)e * 8];
        float4 q1 = *(const float4*)&ea[(size_t)e * 8 + 4];
        float av[8] = {q0.x, q0.y, q0.z, q0.w, q1.x, q1.y, q1.z, q1.w};
        #pragma unroll
        for (int f = 0; f < 8; ++f) {
          #pragma unroll
          for (int jj = 0; jj < 4; ++jj) acc[ee][jj] += av[f] * w1t[f][jj];
        }
      }
    }
    // GEMM1 main (k<120 from LDS)
    #pragma unroll 8
    for (int k = 0; k < 120; ++k) {
      float4 bf = *(const float4*)&sW1[k * 128 + j0];
      float4 p0 = *(const float4*)&sA[k * 68 + e0];
      float4 p1 = *(const float4*)&sA[k * 68 + e0 + 4];
      float af[8] = {p0.x, p0.y, p0.z, p0.w, p1.x, p1.y, p1.z, p1.w};
      #pragma unroll
      for (int ee = 0; ee < 8; ++ee) {
        acc[ee][0] += af[ee] * bf.x; acc[ee][1] += af[ee] * bf.y;
        acc[ee][2] += af[ee] * bf.z; acc[ee][3] += af[ee] * bf.w;
      }
    }
    // GEMM1 tail (k=120..127, W1 row from global; L1-hot)
    #pragma unroll
    for (int k = 120; k < 128; ++k) {
      float4 bf = *(const float4*)&W1[k * 128 + j0];
      float4 p0 = *(const float4*)&sA[k * 68 + e0];
      float4 p1 = *(const float4*)&sA[k * 68 + e0 + 4];
      float af[8] = {p0.x, p0.y, p0.z, p0.w, p1.x, p1.y, p1.z, p1.w};
      #pragma unroll
      for (int ee = 0; ee < 8; ++ee) {
        acc[ee][0] += af[ee] * bf.x; acc[ee][1] += af[ee] * bf.y;
        acc[ee][2] += af[ee] * bf.z; acc[ee][3] += af[ee] * bf.w;
      }
    }
    #pragma unroll
    for (int ee = 0; ee < 8; ++ee) {
      #pragma unroll
      for (int jj = 0; jj < 4; ++jj) acc[ee][jj] = fmaxf(acc[ee][jj], 0.f);
    }
    __syncthreads();  // all GEMM1 A-reads done
    // write h transposed: row = j, col = e
    #pragma unroll
    for (int jj = 0; jj < 4; ++jj) {
      int r = j0 + jj;
      *(float4*)&sA[r * 68 + e0]     = make_float4(acc[0][jj], acc[1][jj], acc[2][jj], acc[3][jj]);
      *(float4*)&sA[r * 68 + e0 + 4] = make_float4(acc[4][jj], acc[5][jj], acc[6][jj], acc[7][jj]);
    }
    __syncthreads();
    // GEMM2
    float m[8][4];
    #pragma unroll
    for (int ee = 0; ee < 8; ++ee) {
      m[ee][0] = bias2.x; m[ee][1] = bias2.y; m[ee][2] = bias2.z; m[ee][3] = bias2.w;
    }
    #pragma unroll 8
    for (int k = 0; k < 128; ++k) {
      float4 bf = *(const float4*)&sW2[k * 128 + j0];
      float4 p0 = *(const float4*)&sA[k * 68 + e0];
      float4 p1 = *(const float4*)&sA[k * 68 + e0 + 4];
      float af[8] = {p0.x, p0.y, p0.z, p0.w, p1.x, p1.y, p1.z, p1.w};
      #pragma unroll
      for (int ee = 0; ee < 8; ++ee) {
        m[ee][0] += af[ee] * bf.x; m[ee][1] += af[ee] * bf.y;
        m[ee][2] += af[ee] * bf.z; m[ee][3] += af[ee] * bf.w;
      }
    }
    // run-compressed scatter-add: CSR order => equal dst are consecutive
    {
      int prevd = -1;
      float r0 = 0.f, r1 = 0.f, r2 = 0.f, r3 = 0.f;
      #pragma unroll
      for (int ee = 0; ee < 8; ++ee) {
        int p = ebase + e0 + ee;
        if (p < NE) {
          int d = dstc[p];
          if (d != prevd) {
            if (prevd >= 0) {
              atomicAdd(&agg[(size_t)prevd * 128 + j0 + 0], r0);
              atomicAdd(&agg[(size_t)prevd * 128 + j0 + 1], r1);
              atomicAdd(&agg[(size_t)prevd * 128 + j0 + 2], r2);
              atomicAdd(&agg[(size_t)prevd * 128 + j0 + 3], r3);
            }
            prevd = d;
            r0 = m[ee][0]; r1 = m[ee][1]; r2 = m[ee][2]; r3 = m[ee][3];
          } else {
            r0 += m[ee][0]; r1 += m[ee][1]; r2 += m[ee][2]; r3 += m[ee][3];
          }
        }
      }
      if (prevd >= 0) {
        atomicAdd(&agg[(size_t)prevd * 128 + j0 + 0], r0);
        atomicAdd(&agg[(size_t)prevd * 128 + j0 + 1], r1);
        atomicAdd(&agg[(size_t)prevd * 128 + j0 + 2], r2);
        atomicAdd(&agg[(size_t)prevd * 128 + j0 + 3], r3);
      }
    }
  }
}

// ---------------- update MLP + residual + LayerNorm (per layer) ----------------
// upd_in = [x(64) | agg/deg(128)]; x = LN(x + relu(upd_in@Wu+bu))
// Tile: 128 nodes x 64 out, 256 threads, micro-tile 8n x 4j. LDS = 48 + 99 KB.
__global__ __launch_bounds__(256, 1) void k_upd(
    float* __restrict__ x, const float* __restrict__ agg,
    const int* __restrict__ cnt,
    const float* __restrict__ Wu, const float* __restrict__ bu,
    const float* __restrict__ lng, const float* __restrict__ lnb)
{
  __shared__ __align__(16) float sWu[192 * 64];
  __shared__ __align__(16) float sA2[192 * 132];
  const int t = threadIdx.x;
  for (int i = t * 4; i < 192 * 64; i += 1024) *(float4*)&sWu[i] = *(const float4*)&Wu[i];
  const int j0 = (t & 15) * 4;   // 0..60
  const int n0 = (t >> 4) * 8;   // 0..120
  const int wv = t >> 6, ln = t & 63;
  const float4 bias = *(const float4*)&bu[j0];
  const float4 g4 = *(const float4*)&lng[j0];
  const float4 be4 = *(const float4*)&lnb[j0];
  __syncthreads();

  for (int tile = blockIdx.x; tile < (NN + 127) / 128; tile += gridDim.x) {
    const int nbase = tile * 128;
    __syncthreads();
    for (int i = 0; i < 32; ++i) {
      int nl = wv * 32 + i;
      int n = nbase + nl;
      float vx = 0.f, va = 0.f, vb = 0.f;
      if (n < NN) {
        float inv = 1.f / ((float)cnt[n] + 1e-6f);   // wave-uniform scalar load
        vx = x[(size_t)n * 64 + ln];
        va = agg[(size_t)n * 128 + ln] * inv;
        vb = agg[(size_t)n * 128 + 64 + ln] * inv;
      }
      sA2[ln * 132 + nl] = vx;
      sA2[(64 + ln) * 132 + nl] = va;
      sA2[(128 + ln) * 132 + nl] = vb;
    }
    __syncthreads();
    float acc[8][4];
    #pragma unroll
    for (int ee = 0; ee < 8; ++ee) {
      acc[ee][0] = bias.x; acc[ee][1] = bias.y; acc[ee][2] = bias.z; acc[ee][3] = bias.w;
    }
    #pragma unroll 8
    for (int k = 0; k < 192; ++k) {
      float4 bf = *(const float4*)&sWu[k * 64 + j0];
      float4 p0 = *(const float4*)&sA2[k * 132 + n0];
      float4 p1 = *(const float4*)&sA2[k * 132 + n0 + 4];
      float af[8] = {p0.x, p0.y, p0.z, p0.w, p1.x, p1.y, p1.z, p1.w};
      #pragma unroll
      for (int ee = 0; ee < 8; ++ee) {
        acc[ee][0] += af[ee] * bf.x; acc[ee][1] += af[ee] * bf.y;
        acc[ee][2] += af[ee] * bf.z; acc[ee][3] += af[ee] * bf.w;
      }
    }
    // residual (x rows still in sA2 rows 0..63) + relu
    float ov[8][4];
    #pragma unroll
    for (int jj = 0; jj < 4; ++jj) {
      float4 r0 = *(const float4*)&sA2[(j0 + jj) * 132 + n0];
      float4 r1 = *(const float4*)&sA2[(j0 + jj) * 132 + n0 + 4];
      ov[0][jj] = r0.x + fmaxf(acc[0][jj], 0.f);
      ov[1][jj] = r0.y + fmaxf(acc[1][jj], 0.f);
      ov[2][jj] = r0.z + fmaxf(acc[2][jj], 0.f);
      ov[3][jj] = r0.w + fmaxf(acc[3][jj], 0.f);
      ov[4][jj] = r1.x + fmaxf(acc[4][jj], 0.f);
      ov[5][jj] = r1.y + fmaxf(acc[5][jj], 0.f);
      ov[6][jj] = r1.z + fmaxf(acc[6][jj], 0.f);
      ov[7][jj] = r1.w + fmaxf(acc[7][jj], 0.f);
    }
    // LayerNorm across 64 j (16-lane shuffle groups share a node)
    #pragma unroll
    for (int ee = 0; ee < 8; ++ee) {
      float s1 = ov[ee][0] + ov[ee][1] + ov[ee][2] + ov[ee][3];
      float s2 = ov[ee][0] * ov[ee][0] + ov[ee][1] * ov[ee][1] +
                 ov[ee][2] * ov[ee][2] + ov[ee][3] * ov[ee][3];
      #pragma unroll
      for (int off = 1; off < 16; off <<= 1) {
        s1 += __shfl_xor(s1, off, 64);
        s2 += __shfl_xor(s2, off, 64);
      }
      float mu = s1 * 0.015625f;
      float var = s2 * 0.015625f - mu * mu;
      float rs = rsqrtf(var + 1e-5f);
      int n = nbase + n0 + ee;
      if (n < NN) {
        float4 y;
        y.x = (ov[ee][0] - mu) * rs * g4.x + be4.x;
        y.y = (ov[ee][1] - mu) * rs * g4.y + be4.y;
        y.z = (ov[ee][2] - mu) * rs * g4.z + be4.z;
        y.w = (ov[ee][3] - mu) * rs * g4.w + be4.w;
        *(float4*)&x[(size_t)n * 64 + j0] = y;
      }
    }
  }
}

// ---------------- edge predictor: 136->128->64->1 + tanh ----------------
__global__ __launch_bounds__(256, 1) void k_pred(
    const float* __restrict__ x, const float* __restrict__ ea,
    const int* __restrict__ src, const int* __restrict__ dst,
    const float* __restrict__ W1, const float* __restrict__ b1,
    const float* __restrict__ W2, const float* __restrict__ b2,
    const float* __restrict__ W3, const float* __restrict__ b3,
    float* __restrict__ out)
{
  __shared__ __align__(16) float sW1[128 * 128];
  __shared__ __align__(16) float sW2[128 * 64];
  __shared__ __align__(16) float sA[128 * 68];
  const int t = threadIdx.x;
  for (int i = t * 4; i < 128 * 128; i += 1024) *(float4*)&sW1[i] = *(const float4*)&W1[i];
  for (int i = t * 4; i < 128 * 64; i += 1024) *(float4*)&sW2[i] = *(const float4*)&W2[i];
  const int j0 = (t & 31) * 4, e0 = (t >> 5) * 8;     // GEMM1 mapping
  const int j0b = (t & 15) * 4, e0b = (t >> 4) * 4;   // GEMM2 mapping
  const int wv = t >> 6, ln = t & 63;
  float w1t[8][4];
  #pragma unroll
  for (int f = 0; f < 8; ++f) {
    float4 w = *(const float4*)&W1[(128 + f) * 128 + j0];
    w1t[f][0] = w.x; w1t[f][1] = w.y; w1t[f][2] = w.z; w1t[f][3] = w.w;
  }
  const float4 bias1 = *(const float4*)&b1[j0];
  const float4 bias2 = *(const float4*)&b2[j0b];
  const float w3 = W3[ln];
  const float b3v = b3[0];
  __syncthreads();

  for (int tile = blockIdx.x; tile < (NE + 63) / 64; tile += gridDim.x) {
    const int ebase = tile * 64;
    __syncthreads();
    for (int i = 0; i < 16; ++i) {
      int el = wv * 16 + i;
      int e = ebase + el;
      float vs = 0.f, vd = 0.f;
      if (e < NE) {
        int s_ = src[e], d_ = dst[e];
        vs = x[(size_t)s_ * 64 + ln];
        vd = x[(size_t)d_ * 64 + ln];
      }
      sA[ln * 68 + el] = vs;
      sA[(64 + ln) * 68 + el] = vd;
    }
    __syncthreads();
    // GEMM1 -> h1 (relu)
    float acc[8][4];
    #pragma unroll
    for (int ee = 0; ee < 8; ++ee) {
      acc[ee][0] = bias1.x; acc[ee][1] = bias1.y; acc[ee][2] = bias1.z; acc[ee][3] = bias1.w;
    }
    #pragma unroll
    for (int ee = 0; ee < 8; ++ee) {
      int e = ebase + e0 + ee;
      if (e < NE) {
        float4 q0 = *(const float4*)&ea[(size_t)e * 8];
        float4 q1 = *(const float4*)&ea[(size_t)e * 8 + 4];
        float av[8] = {q0.x, q0.y, q0.z, q0.w, q1.x, q1.y, q1.z, q1.w};
        #pragma unroll
        for (int f = 0; f < 8; ++f) {
          #pragma unroll
          for (int jj = 0; jj < 4; ++jj) acc[ee][jj] += av[f] * w1t[f][jj];
        }
      }
    }
    #pragma unroll 8
    for (int k = 0; k < 128; ++k) {
      float4 bf = *(const float4*)&sW1[k * 128 + j0];
      float4 p0 = *(const float4*)&sA[k * 68 + e0];
      float4 p1 = *(const float4*)&sA[k * 68 + e0 + 4];
      float af[8] = {p0.x, p0.y, p0.z, p0.w, p1.x, p1.y, p1.z, p1.w};
      #pragma unroll
      for (int ee = 0; ee < 8; ++ee) {
        acc[ee][0] += af[ee] * bf.x; acc[ee][1] += af[ee] * bf.y;
        acc[ee][2] += af[ee] * bf.z; acc[ee][3] += af[ee] * bf.w;
      }
    }
    #pragma unroll
    for (int ee = 0; ee < 8; ++ee) {
      #pragma unroll
      for (int jj = 0; jj < 4; ++jj) acc[ee][jj] = fmaxf(acc[ee][jj], 0.f);
    }
    __syncthreads();
    #pragma unroll
    for (int jj = 0; jj < 4; ++jj) {
      int r = j0 + jj;
      *(float4*)&sA[r * 68 + e0]     = make_float4(acc[0][jj], acc[1][jj], acc[2][jj], acc[3][jj]);
      *(float4*)&sA[r * 68 + e0 + 4] = make_float4(acc[4][jj], acc[5][jj], acc[6][jj], acc[7][jj]);
    }
    __syncthreads();
    // GEMM2 -> h2 (relu), 64x64 tile, 4e x 4j
    float h2[4][4];
    #pragma unroll
    for (int ee = 0; ee < 4; ++ee) {
      h2[ee][0] = bias2.x; h2[ee][1] = bias2.y; h2[ee][2] = bias2.z; h2[ee][3] = bias2.w;
    }
    #pragma unroll 8
    for (int k = 0; k < 128; ++k) {
      float4 bf = *(const float4*)&sW2[k * 64 + j0b];
      float4 p0 = *(const float4*)&sA[k * 68 + e0b];
      float af[4] = {p0.x, p0.y, p0.z, p0.w};
      #pragma unroll
      for (int ee = 0; ee < 4; ++ee) {
        h2[ee][0] += af[ee] * bf.x; h2[ee][1] += af[ee] * bf.y;
        h2[ee][2] += af[ee] * bf.z; h2[ee][3] += af[ee] * bf.w;
      }
    }
    #pragma unroll
    for (int ee = 0; ee < 4; ++ee) {
      #pragma unroll
      for (int jj = 0; jj < 4; ++jj) h2[ee][jj] = fmaxf(h2[ee][jj], 0.f);
    }
    __syncthreads();
    #pragma unroll
    for (int jj = 0; jj < 4; ++jj) {
      *(float4*)&sA[(j0b + jj) * 68 + e0b] =
          make_float4(h2[0][jj], h2[1][jj], h2[2][jj], h2[3][jj]);
    }
    __syncthreads();
    // GEMM3 + tanh: wave wv owns edges [wv*16, wv*16+16)
    for (int i = 0; i < 16; ++i) {
      int el = wv * 16 + i;
      float v = sA[ln * 68 + el] * w3;
      #pragma unroll
      for (int off = 1; off < 64; off <<= 1) v += __shfl_xor(v, off, 64);
      int e = ebase + el;
      if (ln == 0 && e < NE) out[e] = tanhf(v + b3v);
    }
  }
}

extern "C" void kernel_launch(void* const* d_in, const int* in_sizes, int n_in,
                              void* d_out, int out_size, void* d_ws, size_t ws_size,
                              hipStream_t stream)
{
  (void)in_sizes; (void)n_in; (void)out_size; (void)ws_size;
  const float* nf  = (const float*)d_in[0];
  const float* ea  = (const float*)d_in[1];
  const float* eW  = (const float*)d_in[2];
  const float* eb  = (const float*)d_in[3];
  const float* mW1 = (const float*)d_in[4];
  const float* mb1 = (const float*)d_in[5];
  const float* mW2 = (const float*)d_in[6];
  const float* mb2 = (const float*)d_in[7];
  const float* uW  = (const float*)d_in[8];
  const float* ub  = (const float*)d_in[9];
  const float* lg  = (const float*)d_in[10];
  const float* lb  = (const float*)d_in[11];
  const float* pW1 = (const float*)d_in[12];
  const float* pb1 = (const float*)d_in[13];
  const float* pW2 = (const float*)d_in[14];
  const float* pb2 = (const float*)d_in[15];
  const float* pW3 = (const float*)d_in[16];
  const float* pb3 = (const float*)d_in[17];
  const int*   ei  = (const int*)d_in[18];
  const int* srcI = ei;
  const int* dstI = ei + NE;
  float* out = (float*)d_out;

  // workspace (~43 MB)
  char* w = (char*)d_ws;
  float* x    = (float*)w;  w += (size_t)NN * 64 * 4;      // 12.8 MB
  float* agg  = (float*)w;  w += (size_t)NN * 128 * 4;     // 25.6 MB
  int*   cnt  = (int*)w;    w += (size_t)NN * 4;
  int*   ptr  = (int*)w;    w += (size_t)(NN + 1) * 4;
  int*   cur  = (int*)w;    w += (size_t)NN * 4;
  int*   eid  = (int*)w;    w += (size_t)NE * 4;           // 2 MB
  int*   dstc = (int*)w;                                   // 2 MB

  k_zero_i<<<64, 256, 0, stream>>>(cnt, NN);
  k_embed<<<(NN * 16 + 255) / 256, 256, 0, stream>>>(nf, eW, eb, x);
  k_hist<<<(NE + 255) / 256, 256, 0, stream>>>(dstI, cnt);
  k_scan<<<1, 1024, 0, stream>>>(cnt, ptr, cur);
  k_fill<<<(NE + 255) / 256, 256, 0, stream>>>(dstI, cur, eid, dstc);

  for (int l = 0; l < 3; ++l) {
    k_zero_f4<<<1024, 256, 0, stream>>>((float4*)agg, NN * 128 / 4);
    k_msg<<<1024, 256, 0, stream>>>(x, ea, srcI, eid, dstc,
        mW1 + (size_t)l * 136 * 128, mb1 + (size_t)l * 128,
        mW2 + (size_t)l * 128 * 128, mb2 + (size_t)l * 128, agg);
    k_upd<<<391, 256, 0, stream>>>(x, agg, cnt,
        uW + (size_t)l * 192 * 64, ub + (size_t)l * 64,
        lg + (size_t)l * 64, lb + (size_t)l * 64);
  }
  k_pred<<<1024, 256, 0, stream>>>(x, ea, srcI, dstI,
      pW1, pb1, pW2, pb2, pW3, pb3, out);
}

// Round 3
// 2026.029 us; speedup vs baseline: 2.1651x; 2.1651x over previous
//
#include <hip/hip_runtime.h>

#define NN 50000
#define NE 500000

typedef __attribute__((ext_vector_type(8))) short bf8_t;   // 8 x bf16
typedef __attribute__((ext_vector_type(4))) float f4_t;    // MFMA acc
#define MFMA16(a, b, c) __builtin_amdgcn_mfma_f32_16x16x32_bf16(a, b, c, 0, 0, 0)

__device__ __forceinline__ short f2bf(float f) {
  unsigned u = __float_as_uint(f);
  u += 0x7fffu + ((u >> 16) & 1u);   // RNE
  return (short)(u >> 16);
}

// ---------------- zero helpers ----------------
__global__ __launch_bounds__(256) void k_zero_f4(float4* __restrict__ p, int n4)
{
  for (int i = blockIdx.x * 256 + threadIdx.x; i < n4; i += gridDim.x * 256)
    p[i] = make_float4(0.f, 0.f, 0.f, 0.f);
}
__global__ __launch_bounds__(256) void k_zero_i(int* __restrict__ p, int n)
{
  for (int i = blockIdx.x * 256 + threadIdx.x; i < n; i += gridDim.x * 256)
    p[i] = 0;
}

// ---------------- weight / edge_attr prep (fp32 -> bf16, transposed) --------
// w1t[l][n][k] (k padded 136->160 with zeros), w2t[l][n][k]
__global__ __launch_bounds__(256) void k_prep_w1(const float* __restrict__ W1,
                                                 short* __restrict__ w1t)
{
  int idx = blockIdx.x * 256 + threadIdx.x;
  if (idx >= 3 * 128 * 160) return;
  int l = idx / (128 * 160);
  int rem = idx - l * 128 * 160;
  int n = rem / 160, k = rem % 160;
  float v = (k < 136) ? W1[(size_t)l * 136 * 128 + (size_t)k * 128 + n] : 0.f;
  w1t[idx] = f2bf(v);
}
__global__ __launch_bounds__(256) void k_prep_w2(const float* __restrict__ W2,
                                                 short* __restrict__ w2t)
{
  int idx = blockIdx.x * 256 + threadIdx.x;
  if (idx >= 3 * 128 * 128) return;
  int l = idx >> 14;
  int n = (idx >> 7) & 127, k = idx & 127;
  w2t[idx] = f2bf(W2[(size_t)l * 128 * 128 + (size_t)k * 128 + n]);
}
__global__ __launch_bounds__(256) void k_prep_ea(const float* __restrict__ ea,
                                                 short* __restrict__ eab)
{
  int i = blockIdx.x * 256 + threadIdx.x;           // one float4 per thread
  if (i >= NE * 2) return;                          // NE*8 elems / 4
  float4 v = *(const float4*)&ea[(size_t)i * 4];
  short4 o;
  o.x = f2bf(v.x); o.y = f2bf(v.y); o.z = f2bf(v.z); o.w = f2bf(v.w);
  *(short4*)&eab[(size_t)i * 4] = o;
}

// ---------------- embed: x = relu(nf @ We + be) ----------------
__global__ __launch_bounds__(256) void k_embed(
    const float* __restrict__ nf, const float* __restrict__ We,
    const float* __restrict__ be, float* __restrict__ x, short* __restrict__ xb)
{
  int idx = blockIdx.x * 256 + threadIdx.x;
  int n = idx >> 4, g = idx & 15;
  if (n >= NN) return;
  int j0 = g * 4;
  float4 b4 = *(const float4*)&be[j0];
  float a0 = b4.x, a1 = b4.y, a2 = b4.z, a3 = b4.w;
  #pragma unroll
  for (int k = 0; k < 7; ++k) {
    float v = nf[n * 7 + k];
    float4 w = *(const float4*)&We[k * 64 + j0];
    a0 += v * w.x; a1 += v * w.y; a2 += v * w.z; a3 += v * w.w;
  }
  a0 = fmaxf(a0, 0.f); a1 = fmaxf(a1, 0.f); a2 = fmaxf(a2, 0.f); a3 = fmaxf(a3, 0.f);
  *(float4*)&x[(size_t)n * 64 + j0] = make_float4(a0, a1, a2, a3);
  short4 o; o.x = f2bf(a0); o.y = f2bf(a1); o.z = f2bf(a2); o.w = f2bf(a3);
  *(short4*)&xb[(size_t)n * 64 + j0] = o;
}

// ---------------- degree histogram ----------------
__global__ __launch_bounds__(256) void k_hist(const int* __restrict__ dst, int* __restrict__ cnt)
{
  int e = blockIdx.x * 256 + threadIdx.x;
  if (e < NE) atomicAdd(&cnt[dst[e]], 1);
}

// ---------------- exclusive scan (single block) ----------------
__global__ __launch_bounds__(1024) void k_scan(const int* __restrict__ cnt,
                                               int* __restrict__ ptr, int* __restrict__ cur)
{
  __shared__ int s[1024];
  __shared__ int carry_s;
  const int t = threadIdx.x;
  if (t == 0) carry_s = 0;
  __syncthreads();
  for (int base = 0; base < NN; base += 1024) {
    int v = (base + t < NN) ? cnt[base + t] : 0;
    s[t] = v;
    __syncthreads();
    for (int off = 1; off < 1024; off <<= 1) {
      int a = s[t];
      int b = (t >= off) ? s[t - off] : 0;
      __syncthreads();
      s[t] = a + b;
      __syncthreads();
    }
    int carry = carry_s;
    if (base + t < NN) {
      int ex = carry + s[t] - v;
      ptr[base + t] = ex;
      cur[base + t] = ex;
    }
    __syncthreads();
    if (t == 1023) carry_s = carry + s[1023];
    __syncthreads();
  }
  if (t == 0) ptr[NN] = carry_s;
}

// ---------------- CSR fill ----------------
__global__ __launch_bounds__(256) void k_fill(const int* __restrict__ dst,
                                              int* __restrict__ cur, int* __restrict__ eid,
                                              int* __restrict__ dstc)
{
  int e = blockIdx.x * 256 + threadIdx.x;
  if (e < NE) {
    int d = dst[e];
    int s = atomicAdd(&cur[d], 1);
    eid[s] = e;
    dstc[s] = d;
  }
}

// ---------------- MFMA edge message MLP + scatter-agg (per layer) ----------
// Tile = 64 CSR positions per block (4 waves x 16 edges). Wave wv owns edges
// [tile*64 + wv*16, +16) and computes their full 128-wide message.
// A-frags gathered straight from global xb (bf16); B-frags from w1t/w2t (L1).
// Only per-wave h-tile (16x136 bf16) in LDS; no __syncthreads in the kernel.
__global__ __launch_bounds__(256, 4) void k_msg_mfma(
    const short* __restrict__ xb, const short* __restrict__ eab,
    const int* __restrict__ src, const int* __restrict__ eid,
    const int* __restrict__ dstc,
    const short* __restrict__ w1, const float* __restrict__ b1,
    const short* __restrict__ w2, const float* __restrict__ b2,
    float* __restrict__ agg)
{
  __shared__ short sH[4 * 16 * 136];   // 17.4 KB
  const int t = threadIdx.x;
  const int wv = t >> 6, l = t & 63;
  const int m16 = l & 15, g = l >> 4;
  const int ebase = blockIdx.x * 64;

  // ---- A-row indices for this lane's edge (row m16 of the wave tile) ----
  int p = ebase + wv * 16 + m16;
  int pc = p < NE ? p : NE - 1;
  int e = eid[pc];
  int s = src[e];
  int d = dstc[pc];
  const short* rs = xb + (size_t)s * 64;
  const short* rd = xb + (size_t)d * 64;

  // ---- A fragments: k = [0,32)[32,64) of src row, [64,96)[96,128) dst, [128,160) ea|0
  bf8_t a0 = *(const bf8_t*)(rs + g * 8);
  bf8_t a1 = *(const bf8_t*)(rs + 32 + g * 8);
  bf8_t a2 = *(const bf8_t*)(rd + g * 8);
  bf8_t a3 = *(const bf8_t*)(rd + 32 + g * 8);
  bf8_t a4 = {0, 0, 0, 0, 0, 0, 0, 0};
  if (g == 0) a4 = *(const bf8_t*)(eab + (size_t)e * 8);

  // ---- GEMM1: h = relu(edge_in @ W1 + b1), K=160 (5 ksteps) ----
  f4_t acc[8];
  #pragma unroll
  for (int nt = 0; nt < 8; ++nt) {
    float bv = b1[nt * 16 + m16];
    acc[nt] = (f4_t){bv, bv, bv, bv};
  }
  #pragma unroll
  for (int ks = 0; ks < 5; ++ks) {
    bf8_t af = (ks == 0) ? a0 : (ks == 1) ? a1 : (ks == 2) ? a2 : (ks == 3) ? a3 : a4;
    #pragma unroll
    for (int nt = 0; nt < 8; ++nt) {
      bf8_t bf = *(const bf8_t*)(w1 + (size_t)(nt * 16 + m16) * 160 + ks * 32 + g * 8);
      acc[nt] = MFMA16(af, bf, acc[nt]);
    }
  }

  // ---- relu -> bf16 -> per-wave LDS h tile [16 m][136 k2] ----
  short* sh = sH + wv * 16 * 136;
  #pragma unroll
  for (int nt = 0; nt < 8; ++nt) {
    #pragma unroll
    for (int r = 0; r < 4; ++r) {
      sh[(g * 4 + r) * 136 + nt * 16 + m16] = f2bf(fmaxf(acc[nt][r], 0.f));
    }
  }
  // same-wave produce/consume: compiler inserts lgkmcnt; no barrier needed.

  // ---- GEMM2: msg = h @ W2 + b2, K=128 (4 ksteps) ----
  f4_t acc2[8];
  #pragma unroll
  for (int nt = 0; nt < 8; ++nt) {
    float bv = b2[nt * 16 + m16];
    acc2[nt] = (f4_t){bv, bv, bv, bv};
  }
  #pragma unroll
  for (int ks = 0; ks < 4; ++ks) {
    bf8_t af = *(const bf8_t*)(sh + m16 * 136 + ks * 32 + g * 8);
    #pragma unroll
    for (int nt = 0; nt < 8; ++nt) {
      bf8_t bf = *(const bf8_t*)(w2 + (size_t)(nt * 16 + m16) * 128 + ks * 32 + g * 8);
      acc2[nt] = MFMA16(af, bf, acc2[nt]);
    }
  }

  // ---- scatter-add: lane holds rows m = g*4 + r (CSR-consecutive) ----
  const int prow = ebase + wv * 16 + g * 4;
  const int4 dv = *(const int4*)(dstc + prow);   // padded alloc: safe at tail
  const bool v0 = prow < NE, v1 = prow + 1 < NE, v2 = prow + 2 < NE, v3 = prow + 3 < NE;
  #pragma unroll
  for (int nt = 0; nt < 8; ++nt) {
    const int col = nt * 16 + m16;
    float v = acc2[nt][0];
    int dc = dv.x;
    bool st = v0;
    if (v1 && st && dv.y == dc) { v += acc2[nt][1]; }
    else { if (st) atomicAdd(&agg[(size_t)dc * 128 + col], v); st = v1; dc = dv.y; v = acc2[nt][1]; }
    if (v2 && st && dv.z == dc) { v += acc2[nt][2]; }
    else { if (st) atomicAdd(&agg[(size_t)dc * 128 + col], v); st = v2; dc = dv.z; v = acc2[nt][2]; }
    if (v3 && st && dv.w == dc) { v += acc2[nt][3]; }
    else { if (st) atomicAdd(&agg[(size_t)dc * 128 + col], v); st = v3; dc = dv.w; v = acc2[nt][3]; }
    if (st) atomicAdd(&agg[(size_t)dc * 128 + col], v);
  }
}

// ---------------- update MLP + residual + LayerNorm (per layer) -------------
__global__ __launch_bounds__(256, 1) void k_upd(
    float* __restrict__ x, short* __restrict__ xb, const float* __restrict__ agg,
    const int* __restrict__ cnt,
    const float* __restrict__ Wu, const float* __restrict__ bu,
    const float* __restrict__ lng, const float* __restrict__ lnb)
{
  __shared__ __align__(16) float sWu[192 * 64];
  __shared__ __align__(16) float sA2[192 * 132];
  const int t = threadIdx.x;
  for (int i = t * 4; i < 192 * 64; i += 1024) *(float4*)&sWu[i] = *(const float4*)&Wu[i];
  const int j0 = (t & 15) * 4;
  const int n0 = (t >> 4) * 8;
  const int wv = t >> 6, ln = t & 63;
  const float4 bias = *(const float4*)&bu[j0];
  const float4 g4 = *(const float4*)&lng[j0];
  const float4 be4 = *(const float4*)&lnb[j0];
  __syncthreads();

  for (int tile = blockIdx.x; tile < (NN + 127) / 128; tile += gridDim.x) {
    const int nbase = tile * 128;
    __syncthreads();
    for (int i = 0; i < 32; ++i) {
      int nl = wv * 32 + i;
      int n = nbase + nl;
      float vx = 0.f, va = 0.f, vb = 0.f;
      if (n < NN) {
        float inv = 1.f / ((float)cnt[n] + 1e-6f);
        vx = x[(size_t)n * 64 + ln];
        va = agg[(size_t)n * 128 + ln] * inv;
        vb = agg[(size_t)n * 128 + 64 + ln] * inv;
      }
      sA2[ln * 132 + nl] = vx;
      sA2[(64 + ln) * 132 + nl] = va;
      sA2[(128 + ln) * 132 + nl] = vb;
    }
    __syncthreads();
    float acc[8][4];
    #pragma unroll
    for (int ee = 0; ee < 8; ++ee) {
      acc[ee][0] = bias.x; acc[ee][1] = bias.y; acc[ee][2] = bias.z; acc[ee][3] = bias.w;
    }
    #pragma unroll 8
    for (int k = 0; k < 192; ++k) {
      float4 bf = *(const float4*)&sWu[k * 64 + j0];
      float4 p0 = *(const float4*)&sA2[k * 132 + n0];
      float4 p1 = *(const float4*)&sA2[k * 132 + n0 + 4];
      float af[8] = {p0.x, p0.y, p0.z, p0.w, p1.x, p1.y, p1.z, p1.w};
      #pragma unroll
      for (int ee = 0; ee < 8; ++ee) {
        acc[ee][0] += af[ee] * bf.x; acc[ee][1] += af[ee] * bf.y;
        acc[ee][2] += af[ee] * bf.z; acc[ee][3] += af[ee] * bf.w;
      }
    }
    float ov[8][4];
    #pragma unroll
    for (int jj = 0; jj < 4; ++jj) {
      float4 r0 = *(const float4*)&sA2[(j0 + jj) * 132 + n0];
      float4 r1 = *(const float4*)&sA2[(j0 + jj) * 132 + n0 + 4];
      ov[0][jj] = r0.x + fmaxf(acc[0][jj], 0.f);
      ov[1][jj] = r0.y + fmaxf(acc[1][jj], 0.f);
      ov[2][jj] = r0.z + fmaxf(acc[2][jj], 0.f);
      ov[3][jj] = r0.w + fmaxf(acc[3][jj], 0.f);
      ov[4][jj] = r1.x + fmaxf(acc[4][jj], 0.f);
      ov[5][jj] = r1.y + fmaxf(acc[5][jj], 0.f);
      ov[6][jj] = r1.z + fmaxf(acc[6][jj], 0.f);
      ov[7][jj] = r1.w + fmaxf(acc[7][jj], 0.f);
    }
    #pragma unroll
    for (int ee = 0; ee < 8; ++ee) {
      float s1 = ov[ee][0] + ov[ee][1] + ov[ee][2] + ov[ee][3];
      float s2 = ov[ee][0] * ov[ee][0] + ov[ee][1] * ov[ee][1] +
                 ov[ee][2] * ov[ee][2] + ov[ee][3] * ov[ee][3];
      #pragma unroll
      for (int off = 1; off < 16; off <<= 1) {
        s1 += __shfl_xor(s1, off, 64);
        s2 += __shfl_xor(s2, off, 64);
      }
      float mu = s1 * 0.015625f;
      float var = s2 * 0.015625f - mu * mu;
      float rs = rsqrtf(var + 1e-5f);
      int n = nbase + n0 + ee;
      if (n < NN) {
        float4 y;
        y.x = (ov[ee][0] - mu) * rs * g4.x + be4.x;
        y.y = (ov[ee][1] - mu) * rs * g4.y + be4.y;
        y.z = (ov[ee][2] - mu) * rs * g4.z + be4.z;
        y.w = (ov[ee][3] - mu) * rs * g4.w + be4.w;
        *(float4*)&x[(size_t)n * 64 + j0] = y;
        short4 o; o.x = f2bf(y.x); o.y = f2bf(y.y); o.z = f2bf(y.z); o.w = f2bf(y.w);
        *(short4*)&xb[(size_t)n * 64 + j0] = o;
      }
    }
  }
}

// ---------------- edge predictor: 136->128->64->1 + tanh (fp32) -------------
__global__ __launch_bounds__(256, 1) void k_pred(
    const float* __restrict__ x, const float* __restrict__ ea,
    const int* __restrict__ src, const int* __restrict__ dst,
    const float* __restrict__ W1, const float* __restrict__ b1,
    const float* __restrict__ W2, const float* __restrict__ b2,
    const float* __restrict__ W3, const float* __restrict__ b3,
    float* __restrict__ out)
{
  __shared__ __align__(16) float sW1[128 * 128];
  __shared__ __align__(16) float sW2[128 * 64];
  __shared__ __align__(16) float sA[128 * 68];
  const int t = threadIdx.x;
  for (int i = t * 4; i < 128 * 128; i += 1024) *(float4*)&sW1[i] = *(const float4*)&W1[i];
  for (int i = t * 4; i < 128 * 64; i += 1024) *(float4*)&sW2[i] = *(const float4*)&W2[i];
  const int j0 = (t & 31) * 4, e0 = (t >> 5) * 8;
  const int j0b = (t & 15) * 4, e0b = (t >> 4) * 4;
  const int wv = t >> 6, ln = t & 63;
  float w1t[8][4];
  #pragma unroll
  for (int f = 0; f < 8; ++f) {
    float4 w = *(const float4*)&W1[(128 + f) * 128 + j0];
    w1t[f][0] = w.x; w1t[f][1] = w.y; w1t[f][2] = w.z; w1t[f][3] = w.w;
  }
  const float4 bias1 = *(const float4*)&b1[j0];
  const float4 bias2 = *(const float4*)&b2[j0b];
  const float w3 = W3[ln];
  const float b3v = b3[0];
  __syncthreads();

  for (int tile = blockIdx.x; tile < (NE + 63) / 64; tile += gridDim.x) {
    const int ebase = tile * 64;
    __syncthreads();
    for (int i = 0; i < 16; ++i) {
      int el = wv * 16 + i;
      int e = ebase + el;
      float vs = 0.f, vd = 0.f;
      if (e < NE) {
        int s_ = src[e], d_ = dst[e];
        vs = x[(size_t)s_ * 64 + ln];
        vd = x[(size_t)d_ * 64 + ln];
      }
      sA[ln * 68 + el] = vs;
      sA[(64 + ln) * 68 + el] = vd;
    }
    __syncthreads();
    float acc[8][4];
    #pragma unroll
    for (int ee = 0; ee < 8; ++ee) {
      acc[ee][0] = bias1.x; acc[ee][1] = bias1.y; acc[ee][2] = bias1.z; acc[ee][3] = bias1.w;
    }
    #pragma unroll
    for (int ee = 0; ee < 8; ++ee) {
      int e = ebase + e0 + ee;
      if (e < NE) {
        float4 q0 = *(const float4*)&ea[(size_t)e * 8];
        float4 q1 = *(const float4*)&ea[(size_t)e * 8 + 4];
        float av[8] = {q0.x, q0.y, q0.z, q0.w, q1.x, q1.y, q1.z, q1.w};
        #pragma unroll
        for (int f = 0; f < 8; ++f) {
          #pragma unroll
          for (int jj = 0; jj < 4; ++jj) acc[ee][jj] += av[f] * w1t[f][jj];
        }
      }
    }
    #pragma unroll 8
    for (int k = 0; k < 128; ++k) {
      float4 bf = *(const float4*)&sW1[k * 128 + j0];
      float4 p0 = *(const float4*)&sA[k * 68 + e0];
      float4 p1 = *(const float4*)&sA[k * 68 + e0 + 4];
      float af[8] = {p0.x, p0.y, p0.z, p0.w, p1.x, p1.y, p1.z, p1.w};
      #pragma unroll
      for (int ee = 0; ee < 8; ++ee) {
        acc[ee][0] += af[ee] * bf.x; acc[ee][1] += af[ee] * bf.y;
        acc[ee][2] += af[ee] * bf.z; acc[ee][3] += af[ee] * bf.w;
      }
    }
    #pragma unroll
    for (int ee = 0; ee < 8; ++ee) {
      #pragma unroll
      for (int jj = 0; jj < 4; ++jj) acc[ee][jj] = fmaxf(acc[ee][jj], 0.f);
    }
    __syncthreads();
    #pragma unroll
    for (int jj = 0; jj < 4; ++jj) {
      int r = j0 + jj;
      *(float4*)&sA[r * 68 + e0]     = make_float4(acc[0][jj], acc[1][jj], acc[2][jj], acc[3][jj]);
      *(float4*)&sA[r * 68 + e0 + 4] = make_float4(acc[4][jj], acc[5][jj], acc[6][jj], acc[7][jj]);
    }
    __syncthreads();
    float h2[4][4];
    #pragma unroll
    for (int ee = 0; ee < 4; ++ee) {
      h2[ee][0] = bias2.x; h2[ee][1] = bias2.y; h2[ee][2] = bias2.z; h2[ee][3] = bias2.w;
    }
    #pragma unroll 8
    for (int k = 0; k < 128; ++k) {
      float4 bf = *(const float4*)&sW2[k * 64 + j0b];
      float4 p0 = *(const float4*)&sA[k * 68 + e0b];
      float af[4] = {p0.x, p0.y, p0.z, p0.w};
      #pragma unroll
      for (int ee = 0; ee < 4; ++ee) {
        h2[ee][0] += af[ee] * bf.x; h2[ee][1] += af[ee] * bf.y;
        h2[ee][2] += af[ee] * bf.z; h2[ee][3] += af[ee] * bf.w;
      }
    }
    #pragma unroll
    for (int ee = 0; ee < 4; ++ee) {
      #pragma unroll
      for (int jj = 0; jj < 4; ++jj) h2[ee][jj] = fmaxf(h2[ee][jj], 0.f);
    }
    __syncthreads();
    #pragma unroll
    for (int jj = 0; jj < 4; ++jj) {
      *(float4*)&sA[(j0b + jj) * 68 + e0b] =
          make_float4(h2[0][jj], h2[1][jj], h2[2][jj], h2[3][jj]);
    }
    __syncthreads();
    for (int i = 0; i < 16; ++i) {
      int el = wv * 16 + i;
      float v = sA[ln * 68 + el] * w3;
      #pragma unroll
      for (int off = 1; off < 64; off <<= 1) v += __shfl_xor(v, off, 64);
      int e = ebase + el;
      if (ln == 0 && e < NE) out[e] = tanhf(v + b3v);
    }
  }
}

extern "C" void kernel_launch(void* const* d_in, const int* in_sizes, int n_in,
                              void* d_out, int out_size, void* d_ws, size_t ws_size,
                              hipStream_t stream)
{
  (void)in_sizes; (void)n_in; (void)out_size; (void)ws_size;
  const float* nf  = (const float*)d_in[0];
  const float* ea  = (const float*)d_in[1];
  const float* eW  = (const float*)d_in[2];
  const float* eb  = (const float*)d_in[3];
  const float* mW1 = (const float*)d_in[4];
  const float* mb1 = (const float*)d_in[5];
  const float* mW2 = (const float*)d_in[6];
  const float* mb2 = (const float*)d_in[7];
  const float* uW  = (const float*)d_in[8];
  const float* ub  = (const float*)d_in[9];
  const float* lg  = (const float*)d_in[10];
  const float* lb  = (const float*)d_in[11];
  const float* pW1 = (const float*)d_in[12];
  const float* pb1 = (const float*)d_in[13];
  const float* pW2 = (const float*)d_in[14];
  const float* pb2 = (const float*)d_in[15];
  const float* pW3 = (const float*)d_in[16];
  const float* pb3 = (const float*)d_in[17];
  const int*   ei  = (const int*)d_in[18];
  const int* srcI = ei;
  const int* dstI = ei + NE;
  float* out = (float*)d_out;

  // workspace (~56 MB)
  char* w = (char*)d_ws;
  float* x    = (float*)w;  w += (size_t)NN * 64 * 4;          // 12.8 MB
  float* agg  = (float*)w;  w += (size_t)NN * 128 * 4;         // 25.6 MB
  short* xb   = (short*)w;  w += (size_t)NN * 64 * 2;          // 6.4 MB
  short* eab  = (short*)w;  w += (size_t)NE * 8 * 2;           // 8 MB
  short* w1t  = (short*)w;  w += (size_t)3 * 128 * 160 * 2;    // 123 KB
  short* w2t  = (short*)w;  w += (size_t)3 * 128 * 128 * 2;    // 98 KB
  int*   cnt  = (int*)w;    w += (size_t)NN * 4;
  int*   ptr  = (int*)w;    w += (size_t)(NN + 4) * 4;
  int*   cur  = (int*)w;    w += (size_t)NN * 4;
  int*   eid  = (int*)w;    w += (size_t)NE * 4;
  int*   dstc = (int*)w;    w += (size_t)(NE + 128) * 4;       // padded for int4 tail reads

  k_zero_i<<<64, 256, 0, stream>>>(cnt, NN);
  k_embed<<<(NN * 16 + 255) / 256, 256, 0, stream>>>(nf, eW, eb, x, xb);
  k_hist<<<(NE + 255) / 256, 256, 0, stream>>>(dstI, cnt);
  k_scan<<<1, 1024, 0, stream>>>(cnt, ptr, cur);
  k_fill<<<(NE + 255) / 256, 256, 0, stream>>>(dstI, cur, eid, dstc);
  k_prep_w1<<<240, 256, 0, stream>>>(mW1, w1t);
  k_prep_w2<<<192, 256, 0, stream>>>(mW2, w2t);
  k_prep_ea<<<(NE * 2 + 255) / 256, 256, 0, stream>>>(ea, eab);

  for (int l = 0; l < 3; ++l) {
    k_zero_f4<<<1024, 256, 0, stream>>>((float4*)agg, NN * 128 / 4);
    k_msg_mfma<<<(NE + 63) / 64, 256, 0, stream>>>(xb, eab, srcI, eid, dstc,
        w1t + (size_t)l * 128 * 160, mb1 + (size_t)l * 128,
        w2t + (size_t)l * 128 * 128, mb2 + (size_t)l * 128, agg);
    k_upd<<<391, 256, 0, stream>>>(x, xb, agg, cnt,
        uW + (size_t)l * 192 * 64, ub + (size_t)l * 64,
        lg + (size_t)l * 64, lb + (size_t)l * 64);
  }
  k_pred<<<1024, 256, 0, stream>>>(x, ea, srcI, dstI,
      pW1, pb1, pW2, pb2, pW3, pb3, out);
}

// Round 4
// 1349.783 us; speedup vs baseline: 3.2499x; 1.5010x over previous
//
#include <hip/hip_runtime.h>

#define NN 50000
#define NE 500000

typedef __attribute__((ext_vector_type(8))) short bf8_t;   // 8 x bf16
typedef __attribute__((ext_vector_type(4))) float f4_t;    // MFMA acc
#define MFMA16(a, b, c) __builtin_amdgcn_mfma_f32_16x16x32_bf16(a, b, c, 0, 0, 0)

__device__ __forceinline__ short f2bf(float f) {
  unsigned u = __float_as_uint(f);
  u += 0x7fffu + ((u >> 16) & 1u);   // RNE
  return (short)(u >> 16);
}

// ---------------- zero helpers ----------------
__global__ __launch_bounds__(256) void k_zero_f4(float4* __restrict__ p, int n4)
{
  for (int i = blockIdx.x * 256 + threadIdx.x; i < n4; i += gridDim.x * 256)
    p[i] = make_float4(0.f, 0.f, 0.f, 0.f);
}
__global__ __launch_bounds__(256) void k_zero_i(int* __restrict__ p, int n)
{
  for (int i = blockIdx.x * 256 + threadIdx.x; i < n; i += gridDim.x * 256)
    p[i] = 0;
}

// ---------------- weight / edge_attr prep (fp32 -> bf16, transposed) --------
// w1t[l][n][k] (k padded 136->160 with zeros), w2t[l][n][k]
__global__ __launch_bounds__(256) void k_prep_w1(const float* __restrict__ W1,
                                                 short* __restrict__ w1t)
{
  int idx = blockIdx.x * 256 + threadIdx.x;
  if (idx >= 3 * 128 * 160) return;
  int l = idx / (128 * 160);
  int rem = idx - l * 128 * 160;
  int n = rem / 160, k = rem % 160;
  float v = (k < 136) ? W1[(size_t)l * 136 * 128 + (size_t)k * 128 + n] : 0.f;
  w1t[idx] = f2bf(v);
}
__global__ __launch_bounds__(256) void k_prep_w2(const float* __restrict__ W2,
                                                 short* __restrict__ w2t)
{
  int idx = blockIdx.x * 256 + threadIdx.x;
  if (idx >= 3 * 128 * 128) return;
  int l = idx >> 14;
  int n = (idx >> 7) & 127, k = idx & 127;
  w2t[idx] = f2bf(W2[(size_t)l * 128 * 128 + (size_t)k * 128 + n]);
}
// pred W1 [136,128] -> [128][160] bf16
__global__ __launch_bounds__(256) void k_prep_pw1(const float* __restrict__ W1,
                                                  short* __restrict__ wt)
{
  int idx = blockIdx.x * 256 + threadIdx.x;
  if (idx >= 128 * 160) return;
  int n = idx / 160, k = idx % 160;
  float v = (k < 136) ? W1[(size_t)k * 128 + n] : 0.f;
  wt[idx] = f2bf(v);
}
// pred W2 [128,64] -> [64][128] bf16
__global__ __launch_bounds__(256) void k_prep_pw2(const float* __restrict__ W2,
                                                  short* __restrict__ wt)
{
  int idx = blockIdx.x * 256 + threadIdx.x;
  if (idx >= 64 * 128) return;
  int n = idx >> 7, k = idx & 127;
  wt[idx] = f2bf(W2[(size_t)k * 64 + n]);
}
__global__ __launch_bounds__(256) void k_prep_ea(const float* __restrict__ ea,
                                                 short* __restrict__ eab)
{
  int i = blockIdx.x * 256 + threadIdx.x;           // one float4 per thread
  if (i >= NE * 2) return;                          // NE*8 elems / 4
  float4 v = *(const float4*)&ea[(size_t)i * 4];
  short4 o;
  o.x = f2bf(v.x); o.y = f2bf(v.y); o.z = f2bf(v.z); o.w = f2bf(v.w);
  *(short4*)&eab[(size_t)i * 4] = o;
}

// ---------------- embed: x = relu(nf @ We + be) ----------------
__global__ __launch_bounds__(256) void k_embed(
    const float* __restrict__ nf, const float* __restrict__ We,
    const float* __restrict__ be, float* __restrict__ x, short* __restrict__ xb)
{
  int idx = blockIdx.x * 256 + threadIdx.x;
  int n = idx >> 4, g = idx & 15;
  if (n >= NN) return;
  int j0 = g * 4;
  float4 b4 = *(const float4*)&be[j0];
  float a0 = b4.x, a1 = b4.y, a2 = b4.z, a3 = b4.w;
  #pragma unroll
  for (int k = 0; k < 7; ++k) {
    float v = nf[n * 7 + k];
    float4 w = *(const float4*)&We[k * 64 + j0];
    a0 += v * w.x; a1 += v * w.y; a2 += v * w.z; a3 += v * w.w;
  }
  a0 = fmaxf(a0, 0.f); a1 = fmaxf(a1, 0.f); a2 = fmaxf(a2, 0.f); a3 = fmaxf(a3, 0.f);
  *(float4*)&x[(size_t)n * 64 + j0] = make_float4(a0, a1, a2, a3);
  short4 o; o.x = f2bf(a0); o.y = f2bf(a1); o.z = f2bf(a2); o.w = f2bf(a3);
  *(short4*)&xb[(size_t)n * 64 + j0] = o;
}

// ---------------- degree histogram ----------------
__global__ __launch_bounds__(256) void k_hist(const int* __restrict__ dst, int* __restrict__ cnt)
{
  int e = blockIdx.x * 256 + threadIdx.x;
  if (e < NE) atomicAdd(&cnt[dst[e]], 1);
}

// ---------------- exclusive scan (single block) ----------------
__global__ __launch_bounds__(1024) void k_scan(const int* __restrict__ cnt,
                                               int* __restrict__ ptr, int* __restrict__ cur)
{
  __shared__ int s[1024];
  __shared__ int carry_s;
  const int t = threadIdx.x;
  if (t == 0) carry_s = 0;
  __syncthreads();
  for (int base = 0; base < NN; base += 1024) {
    int v = (base + t < NN) ? cnt[base + t] : 0;
    s[t] = v;
    __syncthreads();
    for (int off = 1; off < 1024; off <<= 1) {
      int a = s[t];
      int b = (t >= off) ? s[t - off] : 0;
      __syncthreads();
      s[t] = a + b;
      __syncthreads();
    }
    int carry = carry_s;
    if (base + t < NN) {
      int ex = carry + s[t] - v;
      ptr[base + t] = ex;
      cur[base + t] = ex;
    }
    __syncthreads();
    if (t == 1023) carry_s = carry + s[1023];
    __syncthreads();
  }
  if (t == 0) ptr[NN] = carry_s;
}

// ---------------- CSR fill ----------------
__global__ __launch_bounds__(256) void k_fill(const int* __restrict__ dst,
                                              int* __restrict__ cur, int* __restrict__ eid,
                                              int* __restrict__ dstc)
{
  int e = blockIdx.x * 256 + threadIdx.x;
  if (e < NE) {
    int d = dst[e];
    int s = atomicAdd(&cur[d], 1);
    eid[s] = e;
    dstc[s] = d;
  }
}

// ---------------- MFMA edge message MLP + scatter-agg (per layer) ----------
__global__ __launch_bounds__(256, 4) void k_msg_mfma(
    const short* __restrict__ xb, const short* __restrict__ eab,
    const int* __restrict__ src, const int* __restrict__ eid,
    const int* __restrict__ dstc,
    const short* __restrict__ w1, const float* __restrict__ b1,
    const short* __restrict__ w2, const float* __restrict__ b2,
    float* __restrict__ agg)
{
  __shared__ short sH[4 * 16 * 136];   // 17.4 KB
  const int t = threadIdx.x;
  const int wv = t >> 6, l = t & 63;
  const int m16 = l & 15, g = l >> 4;
  const int ebase = blockIdx.x * 64;

  int p = ebase + wv * 16 + m16;
  int pc = p < NE ? p : NE - 1;
  int e = eid[pc];
  int s = src[e];
  int d = dstc[pc];
  const short* rs = xb + (size_t)s * 64;
  const short* rd = xb + (size_t)d * 64;

  bf8_t a0 = *(const bf8_t*)(rs + g * 8);
  bf8_t a1 = *(const bf8_t*)(rs + 32 + g * 8);
  bf8_t a2 = *(const bf8_t*)(rd + g * 8);
  bf8_t a3 = *(const bf8_t*)(rd + 32 + g * 8);
  bf8_t a4 = {0, 0, 0, 0, 0, 0, 0, 0};
  if (g == 0) a4 = *(const bf8_t*)(eab + (size_t)e * 8);

  f4_t acc[8];
  #pragma unroll
  for (int nt = 0; nt < 8; ++nt) {
    float bv = b1[nt * 16 + m16];
    acc[nt] = (f4_t){bv, bv, bv, bv};
  }
  #pragma unroll
  for (int ks = 0; ks < 5; ++ks) {
    bf8_t af = (ks == 0) ? a0 : (ks == 1) ? a1 : (ks == 2) ? a2 : (ks == 3) ? a3 : a4;
    #pragma unroll
    for (int nt = 0; nt < 8; ++nt) {
      bf8_t bf = *(const bf8_t*)(w1 + (size_t)(nt * 16 + m16) * 160 + ks * 32 + g * 8);
      acc[nt] = MFMA16(af, bf, acc[nt]);
    }
  }

  short* sh = sH + wv * 16 * 136;
  #pragma unroll
  for (int nt = 0; nt < 8; ++nt) {
    #pragma unroll
    for (int r = 0; r < 4; ++r) {
      sh[(g * 4 + r) * 136 + nt * 16 + m16] = f2bf(fmaxf(acc[nt][r], 0.f));
    }
  }

  f4_t acc2[8];
  #pragma unroll
  for (int nt = 0; nt < 8; ++nt) {
    float bv = b2[nt * 16 + m16];
    acc2[nt] = (f4_t){bv, bv, bv, bv};
  }
  #pragma unroll
  for (int ks = 0; ks < 4; ++ks) {
    bf8_t af = *(const bf8_t*)(sh + m16 * 136 + ks * 32 + g * 8);
    #pragma unroll
    for (int nt = 0; nt < 8; ++nt) {
      bf8_t bf = *(const bf8_t*)(w2 + (size_t)(nt * 16 + m16) * 128 + ks * 32 + g * 8);
      acc2[nt] = MFMA16(af, bf, acc2[nt]);
    }
  }

  const int prow = ebase + wv * 16 + g * 4;
  const int4 dv = *(const int4*)(dstc + prow);
  const bool v0 = prow < NE, v1 = prow + 1 < NE, v2 = prow + 2 < NE, v3 = prow + 3 < NE;
  #pragma unroll
  for (int nt = 0; nt < 8; ++nt) {
    const int col = nt * 16 + m16;
    float v = acc2[nt][0];
    int dc = dv.x;
    bool st = v0;
    if (v1 && st && dv.y == dc) { v += acc2[nt][1]; }
    else { if (st) atomicAdd(&agg[(size_t)dc * 128 + col], v); st = v1; dc = dv.y; v = acc2[nt][1]; }
    if (v2 && st && dv.z == dc) { v += acc2[nt][2]; }
    else { if (st) atomicAdd(&agg[(size_t)dc * 128 + col], v); st = v2; dc = dv.z; v = acc2[nt][2]; }
    if (v3 && st && dv.w == dc) { v += acc2[nt][3]; }
    else { if (st) atomicAdd(&agg[(size_t)dc * 128 + col], v); st = v3; dc = dv.w; v = acc2[nt][3]; }
    if (st) atomicAdd(&agg[(size_t)dc * 128 + col], v);
  }
}

// ---------------- MFMA edge predictor: 136->128->64->1 + tanh --------------
// Same structure as k_msg_mfma; GEMM3 is an in-register 64-dot + 16-lane reduce.
__global__ __launch_bounds__(256, 4) void k_pred_mfma(
    const short* __restrict__ xb, const short* __restrict__ eab,
    const int* __restrict__ src, const int* __restrict__ dst,
    const short* __restrict__ w1, const float* __restrict__ b1,
    const short* __restrict__ w2, const float* __restrict__ b2,
    const float* __restrict__ W3, const float* __restrict__ b3,
    float* __restrict__ out)
{
  __shared__ short sH[4 * 16 * 136];   // 17.4 KB
  const int t = threadIdx.x;
  const int wv = t >> 6, l = t & 63;
  const int m16 = l & 15, g = l >> 4;
  const int ebase = blockIdx.x * 64;

  int p = ebase + wv * 16 + m16;
  int pc = p < NE ? p : NE - 1;
  int s = src[pc];
  int d = dst[pc];
  const short* rs = xb + (size_t)s * 64;
  const short* rd = xb + (size_t)d * 64;

  bf8_t a0 = *(const bf8_t*)(rs + g * 8);
  bf8_t a1 = *(const bf8_t*)(rs + 32 + g * 8);
  bf8_t a2 = *(const bf8_t*)(rd + g * 8);
  bf8_t a3 = *(const bf8_t*)(rd + 32 + g * 8);
  bf8_t a4 = {0, 0, 0, 0, 0, 0, 0, 0};
  if (g == 0) a4 = *(const bf8_t*)(eab + (size_t)pc * 8);

  // GEMM1: 136->128 (K padded to 160)
  f4_t acc[8];
  #pragma unroll
  for (int nt = 0; nt < 8; ++nt) {
    float bv = b1[nt * 16 + m16];
    acc[nt] = (f4_t){bv, bv, bv, bv};
  }
  #pragma unroll
  for (int ks = 0; ks < 5; ++ks) {
    bf8_t af = (ks == 0) ? a0 : (ks == 1) ? a1 : (ks == 2) ? a2 : (ks == 3) ? a3 : a4;
    #pragma unroll
    for (int nt = 0; nt < 8; ++nt) {
      bf8_t bf = *(const bf8_t*)(w1 + (size_t)(nt * 16 + m16) * 160 + ks * 32 + g * 8);
      acc[nt] = MFMA16(af, bf, acc[nt]);
    }
  }
  short* sh = sH + wv * 16 * 136;
  #pragma unroll
  for (int nt = 0; nt < 8; ++nt) {
    #pragma unroll
    for (int r = 0; r < 4; ++r) {
      sh[(g * 4 + r) * 136 + nt * 16 + m16] = f2bf(fmaxf(acc[nt][r], 0.f));
    }
  }

  // GEMM2: 128->64 (4 n-tiles)
  f4_t acc2[4];
  #pragma unroll
  for (int nt = 0; nt < 4; ++nt) {
    float bv = b2[nt * 16 + m16];
    acc2[nt] = (f4_t){bv, bv, bv, bv};
  }
  #pragma unroll
  for (int ks = 0; ks < 4; ++ks) {
    bf8_t af = *(const bf8_t*)(sh + m16 * 136 + ks * 32 + g * 8);
    #pragma unroll
    for (int nt = 0; nt < 4; ++nt) {
      bf8_t bf = *(const bf8_t*)(w2 + (size_t)(nt * 16 + m16) * 128 + ks * 32 + g * 8);
      acc2[nt] = MFMA16(af, bf, acc2[nt]);
    }
  }

  // GEMM3 + tanh: lane (g,m16) holds h2[g*4+r][nt*16+m16]
  float w3v[4];
  #pragma unroll
  for (int nt = 0; nt < 4; ++nt) w3v[nt] = W3[nt * 16 + m16];
  const float b3v = b3[0];
  #pragma unroll
  for (int r = 0; r < 4; ++r) {
    float v = fmaxf(acc2[0][r], 0.f) * w3v[0] + fmaxf(acc2[1][r], 0.f) * w3v[1] +
              fmaxf(acc2[2][r], 0.f) * w3v[2] + fmaxf(acc2[3][r], 0.f) * w3v[3];
    #pragma unroll
    for (int off = 1; off < 16; off <<= 1) v += __shfl_xor(v, off, 64);
    int e = ebase + wv * 16 + g * 4 + r;
    if (m16 == 0 && e < NE) out[e] = tanhf(v + b3v);
  }
}

// ---------------- update MLP + residual + LayerNorm (per layer) -------------
__global__ __launch_bounds__(256, 1) void k_upd(
    float* __restrict__ x, short* __restrict__ xb, const float* __restrict__ agg,
    const int* __restrict__ cnt,
    const float* __restrict__ Wu, const float* __restrict__ bu,
    const float* __restrict__ lng, const float* __restrict__ lnb)
{
  __shared__ __align__(16) float sWu[192 * 64];
  __shared__ __align__(16) float sA2[192 * 132];
  const int t = threadIdx.x;
  for (int i = t * 4; i < 192 * 64; i += 1024) *(float4*)&sWu[i] = *(const float4*)&Wu[i];
  const int j0 = (t & 15) * 4;
  const int n0 = (t >> 4) * 8;
  const int wv = t >> 6, ln = t & 63;
  const float4 bias = *(const float4*)&bu[j0];
  const float4 g4 = *(const float4*)&lng[j0];
  const float4 be4 = *(const float4*)&lnb[j0];
  __syncthreads();

  for (int tile = blockIdx.x; tile < (NN + 127) / 128; tile += gridDim.x) {
    const int nbase = tile * 128;
    __syncthreads();
    for (int i = 0; i < 32; ++i) {
      int nl = wv * 32 + i;
      int n = nbase + nl;
      float vx = 0.f, va = 0.f, vb = 0.f;
      if (n < NN) {
        float inv = 1.f / ((float)cnt[n] + 1e-6f);
        vx = x[(size_t)n * 64 + ln];
        va = agg[(size_t)n * 128 + ln] * inv;
        vb = agg[(size_t)n * 128 + 64 + ln] * inv;
      }
      sA2[ln * 132 + nl] = vx;
      sA2[(64 + ln) * 132 + nl] = va;
      sA2[(128 + ln) * 132 + nl] = vb;
    }
    __syncthreads();
    float acc[8][4];
    #pragma unroll
    for (int ee = 0; ee < 8; ++ee) {
      acc[ee][0] = bias.x; acc[ee][1] = bias.y; acc[ee][2] = bias.z; acc[ee][3] = bias.w;
    }
    #pragma unroll 8
    for (int k = 0; k < 192; ++k) {
      float4 bf = *(const float4*)&sWu[k * 64 + j0];
      float4 p0 = *(const float4*)&sA2[k * 132 + n0];
      float4 p1 = *(const float4*)&sA2[k * 132 + n0 + 4];
      float af[8] = {p0.x, p0.y, p0.z, p0.w, p1.x, p1.y, p1.z, p1.w};
      #pragma unroll
      for (int ee = 0; ee < 8; ++ee) {
        acc[ee][0] += af[ee] * bf.x; acc[ee][1] += af[ee] * bf.y;
        acc[ee][2] += af[ee] * bf.z; acc[ee][3] += af[ee] * bf.w;
      }
    }
    float ov[8][4];
    #pragma unroll
    for (int jj = 0; jj < 4; ++jj) {
      float4 r0 = *(const float4*)&sA2[(j0 + jj) * 132 + n0];
      float4 r1 = *(const float4*)&sA2[(j0 + jj) * 132 + n0 + 4];
      ov[0][jj] = r0.x + fmaxf(acc[0][jj], 0.f);
      ov[1][jj] = r0.y + fmaxf(acc[1][jj], 0.f);
      ov[2][jj] = r0.z + fmaxf(acc[2][jj], 0.f);
      ov[3][jj] = r0.w + fmaxf(acc[3][jj], 0.f);
      ov[4][jj] = r1.x + fmaxf(acc[4][jj], 0.f);
      ov[5][jj] = r1.y + fmaxf(acc[5][jj], 0.f);
      ov[6][jj] = r1.z + fmaxf(acc[6][jj], 0.f);
      ov[7][jj] = r1.w + fmaxf(acc[7][jj], 0.f);
    }
    #pragma unroll
    for (int ee = 0; ee < 8; ++ee) {
      float s1 = ov[ee][0] + ov[ee][1] + ov[ee][2] + ov[ee][3];
      float s2 = ov[ee][0] * ov[ee][0] + ov[ee][1] * ov[ee][1] +
                 ov[ee][2] * ov[ee][2] + ov[ee][3] * ov[ee][3];
      #pragma unroll
      for (int off = 1; off < 16; off <<= 1) {
        s1 += __shfl_xor(s1, off, 64);
        s2 += __shfl_xor(s2, off, 64);
      }
      float mu = s1 * 0.015625f;
      float var = s2 * 0.015625f - mu * mu;
      float rs = rsqrtf(var + 1e-5f);
      int n = nbase + n0 + ee;
      if (n < NN) {
        float4 y;
        y.x = (ov[ee][0] - mu) * rs * g4.x + be4.x;
        y.y = (ov[ee][1] - mu) * rs * g4.y + be4.y;
        y.z = (ov[ee][2] - mu) * rs * g4.z + be4.z;
        y.w = (ov[ee][3] - mu) * rs * g4.w + be4.w;
        *(float4*)&x[(size_t)n * 64 + j0] = y;
        short4 o; o.x = f2bf(y.x); o.y = f2bf(y.y); o.z = f2bf(y.z); o.w = f2bf(y.w);
        *(short4*)&xb[(size_t)n * 64 + j0] = o;
      }
    }
  }
}

extern "C" void kernel_launch(void* const* d_in, const int* in_sizes, int n_in,
                              void* d_out, int out_size, void* d_ws, size_t ws_size,
                              hipStream_t stream)
{
  (void)in_sizes; (void)n_in; (void)out_size; (void)ws_size;
  const float* nf  = (const float*)d_in[0];
  const float* ea  = (const float*)d_in[1];
  const float* eW  = (const float*)d_in[2];
  const float* eb  = (const float*)d_in[3];
  const float* mW1 = (const float*)d_in[4];
  const float* mb1 = (const float*)d_in[5];
  const float* mW2 = (const float*)d_in[6];
  const float* mb2 = (const float*)d_in[7];
  const float* uW  = (const float*)d_in[8];
  const float* ub  = (const float*)d_in[9];
  const float* lg  = (const float*)d_in[10];
  const float* lb  = (const float*)d_in[11];
  const float* pW1 = (const float*)d_in[12];
  const float* pb1 = (const float*)d_in[13];
  const float* pW2 = (const float*)d_in[14];
  const float* pb2 = (const float*)d_in[15];
  const float* pW3 = (const float*)d_in[16];
  const float* pb3 = (const float*)d_in[17];
  const int*   ei  = (const int*)d_in[18];
  const int* srcI = ei;
  const int* dstI = ei + NE;
  float* out = (float*)d_out;

  // workspace (~56 MB)
  char* w = (char*)d_ws;
  float* x    = (float*)w;  w += (size_t)NN * 64 * 4;          // 12.8 MB
  float* agg  = (float*)w;  w += (size_t)NN * 128 * 4;         // 25.6 MB
  short* xb   = (short*)w;  w += (size_t)NN * 64 * 2;          // 6.4 MB
  short* eab  = (short*)w;  w += (size_t)NE * 8 * 2;           // 8 MB
  short* w1t  = (short*)w;  w += (size_t)3 * 128 * 160 * 2;    // 123 KB
  short* w2t  = (short*)w;  w += (size_t)3 * 128 * 128 * 2;    // 98 KB
  short* pw1t = (short*)w;  w += (size_t)128 * 160 * 2;        // 41 KB
  short* pw2t = (short*)w;  w += (size_t)64 * 128 * 2;         // 16 KB
  int*   cnt  = (int*)w;    w += (size_t)NN * 4;
  int*   ptr  = (int*)w;    w += (size_t)(NN + 4) * 4;
  int*   cur  = (int*)w;    w += (size_t)NN * 4;
  int*   eid  = (int*)w;    w += (size_t)NE * 4;
  int*   dstc = (int*)w;    w += (size_t)(NE + 128) * 4;       // padded for int4 tail reads

  k_zero_i<<<64, 256, 0, stream>>>(cnt, NN);
  k_embed<<<(NN * 16 + 255) / 256, 256, 0, stream>>>(nf, eW, eb, x, xb);
  k_hist<<<(NE + 255) / 256, 256, 0, stream>>>(dstI, cnt);
  k_scan<<<1, 1024, 0, stream>>>(cnt, ptr, cur);
  k_fill<<<(NE + 255) / 256, 256, 0, stream>>>(dstI, cur, eid, dstc);
  k_prep_w1<<<240, 256, 0, stream>>>(mW1, w1t);
  k_prep_w2<<<192, 256, 0, stream>>>(mW2, w2t);
  k_prep_pw1<<<80, 256, 0, stream>>>(pW1, pw1t);
  k_prep_pw2<<<32, 256, 0, stream>>>(pW2, pw2t);
  k_prep_ea<<<(NE * 2 + 255) / 256, 256, 0, stream>>>(ea, eab);

  for (int l = 0; l < 3; ++l) {
    k_zero_f4<<<1024, 256, 0, stream>>>((float4*)agg, NN * 128 / 4);
    k_msg_mfma<<<(NE + 63) / 64, 256, 0, stream>>>(xb, eab, srcI, eid, dstc,
        w1t + (size_t)l * 128 * 160, mb1 + (size_t)l * 128,
        w2t + (size_t)l * 128 * 128, mb2 + (size_t)l * 128, agg);
    k_upd<<<391, 256, 0, stream>>>(x, xb, agg, cnt,
        uW + (size_t)l * 192 * 64, ub + (size_t)l * 64,
        lg + (size_t)l * 64, lb + (size_t)l * 64);
  }
  k_pred_mfma<<<(NE + 63) / 64, 256, 0, stream>>>(xb, eab, srcI, dstI,
      pw1t, pb1, pw2t, pb2, pW3, pb3, out);
}

// Round 5
// 1155.670 us; speedup vs baseline: 3.7957x; 1.1680x over previous
//
#include <hip/hip_runtime.h>

#define NN 50000
#define NE 500000

typedef __attribute__((ext_vector_type(8))) short bf8_t;   // 8 x bf16
typedef __attribute__((ext_vector_type(4))) float f4_t;    // MFMA acc
#define MFMA16(a, b, c) __builtin_amdgcn_mfma_f32_16x16x32_bf16(a, b, c, 0, 0, 0)

__device__ __forceinline__ short f2bf(float f) {
  unsigned u = __float_as_uint(f);
  u += 0x7fffu + ((u >> 16) & 1u);   // RNE
  return (short)(u >> 16);
}

// ---------------- zero helpers ----------------
__global__ __launch_bounds__(256) void k_zero_f4(float4* __restrict__ p, int n4)
{
  for (int i = blockIdx.x * 256 + threadIdx.x; i < n4; i += gridDim.x * 256)
    p[i] = make_float4(0.f, 0.f, 0.f, 0.f);
}
__global__ __launch_bounds__(256) void k_zero_i(int* __restrict__ p, int n)
{
  for (int i = blockIdx.x * 256 + threadIdx.x; i < n; i += gridDim.x * 256)
    p[i] = 0;
}

// ---------------- weight prep: fragment-contiguous bf16 layouts -------------
// w1f[l][ks(5)][nt(8)][lane(64)][8] ; element = W1[k=ks*32+(lane>>4)*8+j][n=nt*16+(lane&15)]
__global__ __launch_bounds__(256) void k_prep_w1(const float* __restrict__ W1,
                                                 short* __restrict__ w1f)
{
  int idx = blockIdx.x * 256 + threadIdx.x;
  if (idx >= 3 * 5 * 8 * 64 * 8) return;
  int l = idx / 20480;
  int rem = idx - l * 20480;
  int ks = rem / 4096;
  int nt = (rem >> 9) & 7;
  int lane = (rem >> 3) & 63;
  int j = rem & 7;
  int k = ks * 32 + (lane >> 4) * 8 + j;
  int n = nt * 16 + (lane & 15);
  float v = (k < 136) ? W1[(size_t)l * 136 * 128 + (size_t)k * 128 + n] : 0.f;
  w1f[idx] = f2bf(v);
}
// w2f[l][ks(4)][nt(8)][64][8] ; element = W2[k=ks*32+(lane>>4)*8+j][n=nt*16+(lane&15)]
__global__ __launch_bounds__(256) void k_prep_w2(const float* __restrict__ W2,
                                                 short* __restrict__ w2f)
{
  int idx = blockIdx.x * 256 + threadIdx.x;
  if (idx >= 3 * 4 * 8 * 64 * 8) return;
  int l = idx / 16384;
  int rem = idx - l * 16384;
  int ks = rem / 4096;
  int nt = (rem >> 9) & 7;
  int lane = (rem >> 3) & 63;
  int j = rem & 7;
  int k = ks * 32 + (lane >> 4) * 8 + j;
  int n = nt * 16 + (lane & 15);
  w2f[idx] = f2bf(W2[(size_t)l * 128 * 128 + (size_t)k * 128 + n]);
}
// pred W1 [136,128] -> pw1f[ks(5)][nt(8)][64][8]
__global__ __launch_bounds__(256) void k_prep_pw1(const float* __restrict__ W1,
                                                  short* __restrict__ wf)
{
  int idx = blockIdx.x * 256 + threadIdx.x;
  if (idx >= 5 * 8 * 64 * 8) return;
  int ks = idx / 4096;
  int nt = (idx >> 9) & 7;
  int lane = (idx >> 3) & 63;
  int j = idx & 7;
  int k = ks * 32 + (lane >> 4) * 8 + j;
  int n = nt * 16 + (lane & 15);
  float v = (k < 136) ? W1[(size_t)k * 128 + n] : 0.f;
  wf[idx] = f2bf(v);
}
// pred W2 [128,64] -> pw2f[ks(4)][nt(4)][64][8]
__global__ __launch_bounds__(256) void k_prep_pw2(const float* __restrict__ W2,
                                                  short* __restrict__ wf)
{
  int idx = blockIdx.x * 256 + threadIdx.x;
  if (idx >= 4 * 4 * 64 * 8) return;
  int ks = idx / 2048;
  int nt = (idx >> 9) & 3;
  int lane = (idx >> 3) & 63;
  int j = idx & 7;
  int k = ks * 32 + (lane >> 4) * 8 + j;
  int n = nt * 16 + (lane & 15);
  wf[idx] = f2bf(W2[(size_t)k * 64 + n]);
}
__global__ __launch_bounds__(256) void k_prep_ea(const float* __restrict__ ea,
                                                 short* __restrict__ eab)
{
  int i = blockIdx.x * 256 + threadIdx.x;
  if (i >= NE * 2) return;
  float4 v = *(const float4*)&ea[(size_t)i * 4];
  short4 o;
  o.x = f2bf(v.x); o.y = f2bf(v.y); o.z = f2bf(v.z); o.w = f2bf(v.w);
  *(short4*)&eab[(size_t)i * 4] = o;
}

// ---------------- embed: x = relu(nf @ We + be) ----------------
__global__ __launch_bounds__(256) void k_embed(
    const float* __restrict__ nf, const float* __restrict__ We,
    const float* __restrict__ be, float* __restrict__ x, short* __restrict__ xb)
{
  int idx = blockIdx.x * 256 + threadIdx.x;
  int n = idx >> 4, g = idx & 15;
  if (n >= NN) return;
  int j0 = g * 4;
  float4 b4 = *(const float4*)&be[j0];
  float a0 = b4.x, a1 = b4.y, a2 = b4.z, a3 = b4.w;
  #pragma unroll
  for (int k = 0; k < 7; ++k) {
    float v = nf[n * 7 + k];
    float4 w = *(const float4*)&We[k * 64 + j0];
    a0 += v * w.x; a1 += v * w.y; a2 += v * w.z; a3 += v * w.w;
  }
  a0 = fmaxf(a0, 0.f); a1 = fmaxf(a1, 0.f); a2 = fmaxf(a2, 0.f); a3 = fmaxf(a3, 0.f);
  *(float4*)&x[(size_t)n * 64 + j0] = make_float4(a0, a1, a2, a3);
  short4 o; o.x = f2bf(a0); o.y = f2bf(a1); o.z = f2bf(a2); o.w = f2bf(a3);
  *(short4*)&xb[(size_t)n * 64 + j0] = o;
}

// ---------------- degree histogram ----------------
__global__ __launch_bounds__(256) void k_hist(const int* __restrict__ dst, int* __restrict__ cnt)
{
  int e = blockIdx.x * 256 + threadIdx.x;
  if (e < NE) atomicAdd(&cnt[dst[e]], 1);
}

// ---------------- exclusive scan (single block) ----------------
__global__ __launch_bounds__(1024) void k_scan(const int* __restrict__ cnt,
                                               int* __restrict__ ptr, int* __restrict__ cur)
{
  __shared__ int s[1024];
  __shared__ int carry_s;
  const int t = threadIdx.x;
  if (t == 0) carry_s = 0;
  __syncthreads();
  for (int base = 0; base < NN; base += 1024) {
    int v = (base + t < NN) ? cnt[base + t] : 0;
    s[t] = v;
    __syncthreads();
    for (int off = 1; off < 1024; off <<= 1) {
      int a = s[t];
      int b = (t >= off) ? s[t - off] : 0;
      __syncthreads();
      s[t] = a + b;
      __syncthreads();
    }
    int carry = carry_s;
    if (base + t < NN) {
      int ex = carry + s[t] - v;
      ptr[base + t] = ex;
      cur[base + t] = ex;
    }
    __syncthreads();
    if (t == 1023) carry_s = carry + s[1023];
    __syncthreads();
  }
  if (t == 0) ptr[NN] = carry_s;
}

// ---------------- CSR fill ----------------
__global__ __launch_bounds__(256) void k_fill(const int* __restrict__ dst,
                                              int* __restrict__ cur, int* __restrict__ eid,
                                              int* __restrict__ dstc)
{
  int e = blockIdx.x * 256 + threadIdx.x;
  if (e < NE) {
    int d = dst[e];
    int s = atomicAdd(&cur[d], 1);
    eid[s] = e;
    dstc[s] = d;
  }
}

// ---------------- MFMA edge message MLP + scatter-agg (per layer) ----------
// Block = 128 CSR positions (4 waves x 32 edges = 2 subtiles of 16/wave).
// B-frags (weights) are fragment-contiguous 1KB bursts shared by 2 MFMAs.
__global__ __launch_bounds__(256, 2) void k_msg_mfma(
    const short* __restrict__ xb, const short* __restrict__ eab,
    const int* __restrict__ src, const int* __restrict__ eid,
    const int* __restrict__ dstc,
    const short* __restrict__ w1, const float* __restrict__ b1,
    const short* __restrict__ w2, const float* __restrict__ b2,
    float* __restrict__ agg)
{
  __shared__ short sH[4 * 2 * 16 * 136];   // 34.8 KB
  const int t = threadIdx.x;
  const int wv = t >> 6, l = t & 63;
  const int m16 = l & 15, g = l >> 4;
  const int ebase = blockIdx.x * 128 + wv * 32;

  // ---- gather A fragments for 2 subtiles ----
  bf8_t a[2][5];
  #pragma unroll
  for (int st = 0; st < 2; ++st) {
    int p = ebase + st * 16 + m16;
    int pc = p < NE ? p : NE - 1;
    int e = eid[pc];
    int s = src[e];
    int d = dstc[pc];
    const short* rs = xb + (size_t)s * 64;
    const short* rd = xb + (size_t)d * 64;
    a[st][0] = *(const bf8_t*)(rs + g * 8);
    a[st][1] = *(const bf8_t*)(rs + 32 + g * 8);
    a[st][2] = *(const bf8_t*)(rd + g * 8);
    a[st][3] = *(const bf8_t*)(rd + 32 + g * 8);
    bf8_t z = {0, 0, 0, 0, 0, 0, 0, 0};
    a[st][4] = z;
    if (g == 0) a[st][4] = *(const bf8_t*)(eab + (size_t)e * 8);
  }

  // ---- GEMM1: K=160 (5 ksteps), shared B ----
  const short* w1l = w1 + l * 8;
  f4_t acc[2][8];
  #pragma unroll
  for (int nt = 0; nt < 8; ++nt) {
    float bv = b1[nt * 16 + m16];
    acc[0][nt] = (f4_t){bv, bv, bv, bv};
    acc[1][nt] = (f4_t){bv, bv, bv, bv};
  }
  #pragma unroll
  for (int ks = 0; ks < 5; ++ks) {
    #pragma unroll
    for (int nt = 0; nt < 8; ++nt) {
      bf8_t bf = *(const bf8_t*)(w1l + (ks * 8 + nt) * 512);
      acc[0][nt] = MFMA16(a[0][ks], bf, acc[0][nt]);
      acc[1][nt] = MFMA16(a[1][ks], bf, acc[1][nt]);
    }
  }

  // ---- relu -> bf16 -> per-wave LDS h tiles ----
  short* sh = sH + wv * (2 * 16 * 136);
  #pragma unroll
  for (int st = 0; st < 2; ++st) {
    #pragma unroll
    for (int nt = 0; nt < 8; ++nt) {
      #pragma unroll
      for (int r = 0; r < 4; ++r) {
        sh[st * 2176 + (g * 4 + r) * 136 + nt * 16 + m16] =
            f2bf(fmaxf(acc[st][nt][r], 0.f));
      }
    }
  }

  // ---- GEMM2: K=128 (4 ksteps), shared B ----
  const short* w2l = w2 + l * 8;
  f4_t acc2[2][8];
  #pragma unroll
  for (int nt = 0; nt < 8; ++nt) {
    float bv = b2[nt * 16 + m16];
    acc2[0][nt] = (f4_t){bv, bv, bv, bv};
    acc2[1][nt] = (f4_t){bv, bv, bv, bv};
  }
  #pragma unroll
  for (int ks = 0; ks < 4; ++ks) {
    bf8_t af0 = *(const bf8_t*)(sh + m16 * 136 + ks * 32 + g * 8);
    bf8_t af1 = *(const bf8_t*)(sh + 2176 + m16 * 136 + ks * 32 + g * 8);
    #pragma unroll
    for (int nt = 0; nt < 8; ++nt) {
      bf8_t bf = *(const bf8_t*)(w2l + (ks * 8 + nt) * 512);
      acc2[0][nt] = MFMA16(af0, bf, acc2[0][nt]);
      acc2[1][nt] = MFMA16(af1, bf, acc2[1][nt]);
    }
  }

  // ---- scatter-add with run-compression (per subtile) ----
  #pragma unroll
  for (int st = 0; st < 2; ++st) {
    const int prow = ebase + st * 16 + g * 4;
    const int4 dv = *(const int4*)(dstc + prow);
    const bool v0 = prow < NE, v1 = prow + 1 < NE, v2 = prow + 2 < NE, v3 = prow + 3 < NE;
    #pragma unroll
    for (int nt = 0; nt < 8; ++nt) {
      const int col = nt * 16 + m16;
      float v = acc2[st][nt][0];
      int dc = dv.x;
      bool stf = v0;
      if (v1 && stf && dv.y == dc) { v += acc2[st][nt][1]; }
      else { if (stf) atomicAdd(&agg[(size_t)dc * 128 + col], v); stf = v1; dc = dv.y; v = acc2[st][nt][1]; }
      if (v2 && stf && dv.z == dc) { v += acc2[st][nt][2]; }
      else { if (stf) atomicAdd(&agg[(size_t)dc * 128 + col], v); stf = v2; dc = dv.z; v = acc2[st][nt][2]; }
      if (v3 && stf && dv.w == dc) { v += acc2[st][nt][3]; }
      else { if (stf) atomicAdd(&agg[(size_t)dc * 128 + col], v); stf = v3; dc = dv.w; v = acc2[st][nt][3]; }
      if (stf) atomicAdd(&agg[(size_t)dc * 128 + col], v);
    }
  }
}

// ---------------- MFMA edge predictor: 136->128->64->1 + tanh --------------
__global__ __launch_bounds__(256, 2) void k_pred_mfma(
    const short* __restrict__ xb, const short* __restrict__ eab,
    const int* __restrict__ src, const int* __restrict__ dst,
    const short* __restrict__ w1, const float* __restrict__ b1,
    const short* __restrict__ w2, const float* __restrict__ b2,
    const float* __restrict__ W3, const float* __restrict__ b3,
    float* __restrict__ out)
{
  __shared__ short sH[4 * 2 * 16 * 136];   // 34.8 KB
  const int t = threadIdx.x;
  const int wv = t >> 6, l = t & 63;
  const int m16 = l & 15, g = l >> 4;
  const int ebase = blockIdx.x * 128 + wv * 32;

  bf8_t a[2][5];
  #pragma unroll
  for (int st = 0; st < 2; ++st) {
    int p = ebase + st * 16 + m16;
    int pc = p < NE ? p : NE - 1;
    int s = src[pc];
    int d = dst[pc];
    const short* rs = xb + (size_t)s * 64;
    const short* rd = xb + (size_t)d * 64;
    a[st][0] = *(const bf8_t*)(rs + g * 8);
    a[st][1] = *(const bf8_t*)(rs + 32 + g * 8);
    a[st][2] = *(const bf8_t*)(rd + g * 8);
    a[st][3] = *(const bf8_t*)(rd + 32 + g * 8);
    bf8_t z = {0, 0, 0, 0, 0, 0, 0, 0};
    a[st][4] = z;
    if (g == 0) a[st][4] = *(const bf8_t*)(eab + (size_t)pc * 8);
  }

  // GEMM1: 136->128 (K padded to 160)
  const short* w1l = w1 + l * 8;
  f4_t acc[2][8];
  #pragma unroll
  for (int nt = 0; nt < 8; ++nt) {
    float bv = b1[nt * 16 + m16];
    acc[0][nt] = (f4_t){bv, bv, bv, bv};
    acc[1][nt] = (f4_t){bv, bv, bv, bv};
  }
  #pragma unroll
  for (int ks = 0; ks < 5; ++ks) {
    #pragma unroll
    for (int nt = 0; nt < 8; ++nt) {
      bf8_t bf = *(const bf8_t*)(w1l + (ks * 8 + nt) * 512);
      acc[0][nt] = MFMA16(a[0][ks], bf, acc[0][nt]);
      acc[1][nt] = MFMA16(a[1][ks], bf, acc[1][nt]);
    }
  }
  short* sh = sH + wv * (2 * 16 * 136);
  #pragma unroll
  for (int st = 0; st < 2; ++st) {
    #pragma unroll
    for (int nt = 0; nt < 8; ++nt) {
      #pragma unroll
      for (int r = 0; r < 4; ++r) {
        sh[st * 2176 + (g * 4 + r) * 136 + nt * 16 + m16] =
            f2bf(fmaxf(acc[st][nt][r], 0.f));
      }
    }
  }

  // GEMM2: 128->64 (4 n-tiles)
  const short* w2l = w2 + l * 8;
  f4_t acc2[2][4];
  #pragma unroll
  for (int nt = 0; nt < 4; ++nt) {
    float bv = b2[nt * 16 + m16];
    acc2[0][nt] = (f4_t){bv, bv, bv, bv};
    acc2[1][nt] = (f4_t){bv, bv, bv, bv};
  }
  #pragma unroll
  for (int ks = 0; ks < 4; ++ks) {
    bf8_t af0 = *(const bf8_t*)(sh + m16 * 136 + ks * 32 + g * 8);
    bf8_t af1 = *(const bf8_t*)(sh + 2176 + m16 * 136 + ks * 32 + g * 8);
    #pragma unroll
    for (int nt = 0; nt < 4; ++nt) {
      bf8_t bf = *(const bf8_t*)(w2l + (ks * 4 + nt) * 512);
      acc2[0][nt] = MFMA16(af0, bf, acc2[0][nt]);
      acc2[1][nt] = MFMA16(af1, bf, acc2[1][nt]);
    }
  }

  // GEMM3 + tanh
  float w3v[4];
  #pragma unroll
  for (int nt = 0; nt < 4; ++nt) w3v[nt] = W3[nt * 16 + m16];
  const float b3v = b3[0];
  #pragma unroll
  for (int st = 0; st < 2; ++st) {
    #pragma unroll
    for (int r = 0; r < 4; ++r) {
      float v = fmaxf(acc2[st][0][r], 0.f) * w3v[0] + fmaxf(acc2[st][1][r], 0.f) * w3v[1] +
                fmaxf(acc2[st][2][r], 0.f) * w3v[2] + fmaxf(acc2[st][3][r], 0.f) * w3v[3];
      #pragma unroll
      for (int off = 1; off < 16; off <<= 1) v += __shfl_xor(v, off, 64);
      int e = ebase + st * 16 + g * 4 + r;
      if (m16 == 0 && e < NE) out[e] = tanhf(v + b3v);
    }
  }
}

// ---------------- update MLP + residual + LayerNorm (per layer) -------------
__global__ __launch_bounds__(256, 1) void k_upd(
    float* __restrict__ x, short* __restrict__ xb, const float* __restrict__ agg,
    const int* __restrict__ cnt,
    const float* __restrict__ Wu, const float* __restrict__ bu,
    const float* __restrict__ lng, const float* __restrict__ lnb)
{
  __shared__ __align__(16) float sWu[192 * 64];
  __shared__ __align__(16) float sA2[192 * 132];
  const int t = threadIdx.x;
  for (int i = t * 4; i < 192 * 64; i += 1024) *(float4*)&sWu[i] = *(const float4*)&Wu[i];
  const int j0 = (t & 15) * 4;
  const int n0 = (t >> 4) * 8;
  const int wv = t >> 6, ln = t & 63;
  const float4 bias = *(const float4*)&bu[j0];
  const float4 g4 = *(const float4*)&lng[j0];
  const float4 be4 = *(const float4*)&lnb[j0];
  __syncthreads();

  for (int tile = blockIdx.x; tile < (NN + 127) / 128; tile += gridDim.x) {
    const int nbase = tile * 128;
    __syncthreads();
    for (int i = 0; i < 32; ++i) {
      int nl = wv * 32 + i;
      int n = nbase + nl;
      float vx = 0.f, va = 0.f, vb = 0.f;
      if (n < NN) {
        float inv = 1.f / ((float)cnt[n] + 1e-6f);
        vx = x[(size_t)n * 64 + ln];
        va = agg[(size_t)n * 128 + ln] * inv;
        vb = agg[(size_t)n * 128 + 64 + ln] * inv;
      }
      sA2[ln * 132 + nl] = vx;
      sA2[(64 + ln) * 132 + nl] = va;
      sA2[(128 + ln) * 132 + nl] = vb;
    }
    __syncthreads();
    float acc[8][4];
    #pragma unroll
    for (int ee = 0; ee < 8; ++ee) {
      acc[ee][0] = bias.x; acc[ee][1] = bias.y; acc[ee][2] = bias.z; acc[ee][3] = bias.w;
    }
    #pragma unroll 8
    for (int k = 0; k < 192; ++k) {
      float4 bf = *(const float4*)&sWu[k * 64 + j0];
      float4 p0 = *(const float4*)&sA2[k * 132 + n0];
      float4 p1 = *(const float4*)&sA2[k * 132 + n0 + 4];
      float af[8] = {p0.x, p0.y, p0.z, p0.w, p1.x, p1.y, p1.z, p1.w};
      #pragma unroll
      for (int ee = 0; ee < 8; ++ee) {
        acc[ee][0] += af[ee] * bf.x; acc[ee][1] += af[ee] * bf.y;
        acc[ee][2] += af[ee] * bf.z; acc[ee][3] += af[ee] * bf.w;
      }
    }
    float ov[8][4];
    #pragma unroll
    for (int jj = 0; jj < 4; ++jj) {
      float4 r0 = *(const float4*)&sA2[(j0 + jj) * 132 + n0];
      float4 r1 = *(const float4*)&sA2[(j0 + jj) * 132 + n0 + 4];
      ov[0][jj] = r0.x + fmaxf(acc[0][jj], 0.f);
      ov[1][jj] = r0.y + fmaxf(acc[1][jj], 0.f);
      ov[2][jj] = r0.z + fmaxf(acc[2][jj], 0.f);
      ov[3][jj] = r0.w + fmaxf(acc[3][jj], 0.f);
      ov[4][jj] = r1.x + fmaxf(acc[4][jj], 0.f);
      ov[5][jj] = r1.y + fmaxf(acc[5][jj], 0.f);
      ov[6][jj] = r1.z + fmaxf(acc[6][jj], 0.f);
      ov[7][jj] = r1.w + fmaxf(acc[7][jj], 0.f);
    }
    #pragma unroll
    for (int ee = 0; ee < 8; ++ee) {
      float s1 = ov[ee][0] + ov[ee][1] + ov[ee][2] + ov[ee][3];
      float s2 = ov[ee][0] * ov[ee][0] + ov[ee][1] * ov[ee][1] +
                 ov[ee][2] * ov[ee][2] + ov[ee][3] * ov[ee][3];
      #pragma unroll
      for (int off = 1; off < 16; off <<= 1) {
        s1 += __shfl_xor(s1, off, 64);
        s2 += __shfl_xor(s2, off, 64);
      }
      float mu = s1 * 0.015625f;
      float var = s2 * 0.015625f - mu * mu;
      float rs = rsqrtf(var + 1e-5f);
      int n = nbase + n0 + ee;
      if (n < NN) {
        float4 y;
        y.x = (ov[ee][0] - mu) * rs * g4.x + be4.x;
        y.y = (ov[ee][1] - mu) * rs * g4.y + be4.y;
        y.z = (ov[ee][2] - mu) * rs * g4.z + be4.z;
        y.w = (ov[ee][3] - mu) * rs * g4.w + be4.w;
        *(float4*)&x[(size_t)n * 64 + j0] = y;
        short4 o; o.x = f2bf(y.x); o.y = f2bf(y.y); o.z = f2bf(y.z); o.w = f2bf(y.w);
        *(short4*)&xb[(size_t)n * 64 + j0] = o;
      }
    }
  }
}

extern "C" void kernel_launch(void* const* d_in, const int* in_sizes, int n_in,
                              void* d_out, int out_size, void* d_ws, size_t ws_size,
                              hipStream_t stream)
{
  (void)in_sizes; (void)n_in; (void)out_size; (void)ws_size;
  const float* nf  = (const float*)d_in[0];
  const float* ea  = (const float*)d_in[1];
  const float* eW  = (const float*)d_in[2];
  const float* eb  = (const float*)d_in[3];
  const float* mW1 = (const float*)d_in[4];
  const float* mb1 = (const float*)d_in[5];
  const float* mW2 = (const float*)d_in[6];
  const float* mb2 = (const float*)d_in[7];
  const float* uW  = (const float*)d_in[8];
  const float* ub  = (const float*)d_in[9];
  const float* lg  = (const float*)d_in[10];
  const float* lb  = (const float*)d_in[11];
  const float* pW1 = (const float*)d_in[12];
  const float* pb1 = (const float*)d_in[13];
  const float* pW2 = (const float*)d_in[14];
  const float* pb2 = (const float*)d_in[15];
  const float* pW3 = (const float*)d_in[16];
  const float* pb3 = (const float*)d_in[17];
  const int*   ei  = (const int*)d_in[18];
  const int* srcI = ei;
  const int* dstI = ei + NE;
  float* out = (float*)d_out;

  // workspace (~56 MB)
  char* w = (char*)d_ws;
  float* x    = (float*)w;  w += (size_t)NN * 64 * 4;          // 12.8 MB
  float* agg  = (float*)w;  w += (size_t)NN * 128 * 4;         // 25.6 MB
  short* xb   = (short*)w;  w += (size_t)NN * 64 * 2;          // 6.4 MB
  short* eab  = (short*)w;  w += (size_t)NE * 8 * 2;           // 8 MB
  short* w1f  = (short*)w;  w += (size_t)3 * 20480 * 2;        // 123 KB
  short* w2f  = (short*)w;  w += (size_t)3 * 16384 * 2;        // 98 KB
  short* pw1f = (short*)w;  w += (size_t)20480 * 2;            // 41 KB
  short* pw2f = (short*)w;  w += (size_t)8192 * 2;             // 16 KB
  int*   cnt  = (int*)w;    w += (size_t)NN * 4;
  int*   ptr  = (int*)w;    w += (size_t)(NN + 4) * 4;
  int*   cur  = (int*)w;    w += (size_t)NN * 4;
  int*   eid  = (int*)w;    w += (size_t)NE * 4;
  int*   dstc = (int*)w;    w += (size_t)(NE + 128) * 4;       // padded for int4 tail reads

  k_zero_i<<<64, 256, 0, stream>>>(cnt, NN);
  k_embed<<<(NN * 16 + 255) / 256, 256, 0, stream>>>(nf, eW, eb, x, xb);
  k_hist<<<(NE + 255) / 256, 256, 0, stream>>>(dstI, cnt);
  k_scan<<<1, 1024, 0, stream>>>(cnt, ptr, cur);
  k_fill<<<(NE + 255) / 256, 256, 0, stream>>>(dstI, cur, eid, dstc);
  k_prep_w1<<<240, 256, 0, stream>>>(mW1, w1f);
  k_prep_w2<<<192, 256, 0, stream>>>(mW2, w2f);
  k_prep_pw1<<<80, 256, 0, stream>>>(pW1, pw1f);
  k_prep_pw2<<<32, 256, 0, stream>>>(pW2, pw2f);
  k_prep_ea<<<(NE * 2 + 255) / 256, 256, 0, stream>>>(ea, eab);

  const int egrid = (NE + 127) / 128;
  for (int l = 0; l < 3; ++l) {
    k_zero_f4<<<1024, 256, 0, stream>>>((float4*)agg, NN * 128 / 4);
    k_msg_mfma<<<egrid, 256, 0, stream>>>(xb, eab, srcI, eid, dstc,
        w1f + (size_t)l * 20480, mb1 + (size_t)l * 128,
        w2f + (size_t)l * 16384, mb2 + (size_t)l * 128, agg);
    k_upd<<<391, 256, 0, stream>>>(x, xb, agg, cnt,
        uW + (size_t)l * 192 * 64, ub + (size_t)l * 64,
        lg + (size_t)l * 64, lb + (size_t)l * 64);
  }
  k_pred_mfma<<<egrid, 256, 0, stream>>>(xb, eab, srcI, dstI,
      pw1f, pb1, pw2f, pb2, pW3, pb3, out);
}

// Round 6
// 844.499 us; speedup vs baseline: 5.1943x; 1.3685x over previous
//
#include <hip/hip_runtime.h>

#define NN 50000
#define NE 500000

typedef __attribute__((ext_vector_type(8))) short bf8_t;   // 8 x bf16
typedef __attribute__((ext_vector_type(4))) float f4_t;    // MFMA acc
#define MFMA16(a, b, c) __builtin_amdgcn_mfma_f32_16x16x32_bf16(a, b, c, 0, 0, 0)

__device__ __forceinline__ short f2bf(float f) {
  unsigned u = __float_as_uint(f);
  u += 0x7fffu + ((u >> 16) & 1u);   // RNE
  return (short)(u >> 16);
}
__device__ __forceinline__ float bf_lo(unsigned u) { return __uint_as_float(u << 16); }
__device__ __forceinline__ float bf_hi(unsigned u) { return __uint_as_float(u & 0xffff0000u); }

// ---------------- zero helpers ----------------
__global__ __launch_bounds__(256) void k_zero_f4(float4* __restrict__ p, int n4)
{
  for (int i = blockIdx.x * 256 + threadIdx.x; i < n4; i += gridDim.x * 256)
    p[i] = make_float4(0.f, 0.f, 0.f, 0.f);
}
__global__ __launch_bounds__(256) void k_zero_i(int* __restrict__ p, int n)
{
  for (int i = blockIdx.x * 256 + threadIdx.x; i < n; i += gridDim.x * 256)
    p[i] = 0;
}

// ---------------- weight prep: fragment-contiguous bf16 layouts -------------
// w1f[l][ks(5)][nt(8)][lane(64)][8] ; element = W1[k=ks*32+(lane>>4)*8+j][n=nt*16+(lane&15)]
__global__ __launch_bounds__(256) void k_prep_w1(const float* __restrict__ W1,
                                                 short* __restrict__ w1f)
{
  int idx = blockIdx.x * 256 + threadIdx.x;
  if (idx >= 3 * 5 * 8 * 64 * 8) return;
  int l = idx / 20480;
  int rem = idx - l * 20480;
  int ks = rem / 4096;
  int nt = (rem >> 9) & 7;
  int lane = (rem >> 3) & 63;
  int j = rem & 7;
  int k = ks * 32 + (lane >> 4) * 8 + j;
  int n = nt * 16 + (lane & 15);
  float v = (k < 136) ? W1[(size_t)l * 136 * 128 + (size_t)k * 128 + n] : 0.f;
  w1f[idx] = f2bf(v);
}
// w2f[l][ks(4)][nt(8)][64][8]
__global__ __launch_bounds__(256) void k_prep_w2(const float* __restrict__ W2,
                                                 short* __restrict__ w2f)
{
  int idx = blockIdx.x * 256 + threadIdx.x;
  if (idx >= 3 * 4 * 8 * 64 * 8) return;
  int l = idx / 16384;
  int rem = idx - l * 16384;
  int ks = rem / 4096;
  int nt = (rem >> 9) & 7;
  int lane = (rem >> 3) & 63;
  int j = rem & 7;
  int k = ks * 32 + (lane >> 4) * 8 + j;
  int n = nt * 16 + (lane & 15);
  w2f[idx] = f2bf(W2[(size_t)l * 128 * 128 + (size_t)k * 128 + n]);
}
// pred W1 [136,128] -> pw1f[ks(5)][nt(8)][64][8]
__global__ __launch_bounds__(256) void k_prep_pw1(const float* __restrict__ W1,
                                                  short* __restrict__ wf)
{
  int idx = blockIdx.x * 256 + threadIdx.x;
  if (idx >= 5 * 8 * 64 * 8) return;
  int ks = idx / 4096;
  int nt = (idx >> 9) & 7;
  int lane = (idx >> 3) & 63;
  int j = idx & 7;
  int k = ks * 32 + (lane >> 4) * 8 + j;
  int n = nt * 16 + (lane & 15);
  float v = (k < 136) ? W1[(size_t)k * 128 + n] : 0.f;
  wf[idx] = f2bf(v);
}
// pred W2 [128,64] -> pw2f[ks(4)][nt(4)][64][8]
__global__ __launch_bounds__(256) void k_prep_pw2(const float* __restrict__ W2,
                                                  short* __restrict__ wf)
{
  int idx = blockIdx.x * 256 + threadIdx.x;
  if (idx >= 4 * 4 * 64 * 8) return;
  int ks = idx / 2048;
  int nt = (idx >> 9) & 3;
  int lane = (idx >> 3) & 63;
  int j = idx & 7;
  int k = ks * 32 + (lane >> 4) * 8 + j;
  int n = nt * 16 + (lane & 15);
  wf[idx] = f2bf(W2[(size_t)k * 64 + n]);
}
__global__ __launch_bounds__(256) void k_prep_ea(const float* __restrict__ ea,
                                                 short* __restrict__ eab)
{
  int i = blockIdx.x * 256 + threadIdx.x;
  if (i >= NE * 2) return;
  float4 v = *(const float4*)&ea[(size_t)i * 4];
  short4 o;
  o.x = f2bf(v.x); o.y = f2bf(v.y); o.z = f2bf(v.z); o.w = f2bf(v.w);
  *(short4*)&eab[(size_t)i * 4] = o;
}

// ---------------- embed: x = relu(nf @ We + be) ----------------
__global__ __launch_bounds__(256) void k_embed(
    const float* __restrict__ nf, const float* __restrict__ We,
    const float* __restrict__ be, float* __restrict__ x, short* __restrict__ xb)
{
  int idx = blockIdx.x * 256 + threadIdx.x;
  int n = idx >> 4, g = idx & 15;
  if (n >= NN) return;
  int j0 = g * 4;
  float4 b4 = *(const float4*)&be[j0];
  float a0 = b4.x, a1 = b4.y, a2 = b4.z, a3 = b4.w;
  #pragma unroll
  for (int k = 0; k < 7; ++k) {
    float v = nf[n * 7 + k];
    float4 w = *(const float4*)&We[k * 64 + j0];
    a0 += v * w.x; a1 += v * w.y; a2 += v * w.z; a3 += v * w.w;
  }
  a0 = fmaxf(a0, 0.f); a1 = fmaxf(a1, 0.f); a2 = fmaxf(a2, 0.f); a3 = fmaxf(a3, 0.f);
  *(float4*)&x[(size_t)n * 64 + j0] = make_float4(a0, a1, a2, a3);
  short4 o; o.x = f2bf(a0); o.y = f2bf(a1); o.z = f2bf(a2); o.w = f2bf(a3);
  *(short4*)&xb[(size_t)n * 64 + j0] = o;
}

// ---------------- degree histogram ----------------
__global__ __launch_bounds__(256) void k_hist(const int* __restrict__ dst, int* __restrict__ cnt)
{
  int e = blockIdx.x * 256 + threadIdx.x;
  if (e < NE) atomicAdd(&cnt[dst[e]], 1);
}

// ---------------- exclusive scan (single block) ----------------
__global__ __launch_bounds__(1024) void k_scan(const int* __restrict__ cnt,
                                               int* __restrict__ ptr, int* __restrict__ cur)
{
  __shared__ int s[1024];
  __shared__ int carry_s;
  const int t = threadIdx.x;
  if (t == 0) carry_s = 0;
  __syncthreads();
  for (int base = 0; base < NN; base += 1024) {
    int v = (base + t < NN) ? cnt[base + t] : 0;
    s[t] = v;
    __syncthreads();
    for (int off = 1; off < 1024; off <<= 1) {
      int a = s[t];
      int b = (t >= off) ? s[t - off] : 0;
      __syncthreads();
      s[t] = a + b;
      __syncthreads();
    }
    int carry = carry_s;
    if (base + t < NN) {
      int ex = carry + s[t] - v;
      ptr[base + t] = ex;
      cur[base + t] = ex;
    }
    __syncthreads();
    if (t == 1023) carry_s = carry + s[1023];
    __syncthreads();
  }
  if (t == 0) ptr[NN] = carry_s;
}

// ---------------- CSR fill: CSR-ordered dst, src, edge_attr ----------------
__global__ __launch_bounds__(256) void k_fill(
    const int* __restrict__ src, const int* __restrict__ dst,
    const short* __restrict__ eab, int* __restrict__ cur,
    int* __restrict__ dstc, int* __restrict__ srcc, short* __restrict__ eac)
{
  int e = blockIdx.x * 256 + threadIdx.x;
  if (e < 128) { dstc[NE + e] = 0; srcc[NE + e] = 0; }   // zero pads (tail safety)
  if (e < NE) {
    int d = dst[e];
    int s = atomicAdd(&cur[d], 1);
    dstc[s] = d;
    srcc[s] = src[e];
    *(bf8_t*)(eac + (size_t)s * 8) = *(const bf8_t*)(eab + (size_t)e * 8);
  }
}

// ---------------- k_y1: per-node projections (per layer) --------------------
// y1s = xb @ W1[0:64]  (bf16) ; y1d = xb @ W1[64:128] + b1 (bf16)
__global__ __launch_bounds__(256, 4) void k_y1(
    const short* __restrict__ xb, const short* __restrict__ w1f_l,
    const float* __restrict__ b1,
    short* __restrict__ y1s, short* __restrict__ y1d)
{
  const int t = threadIdx.x;
  const int wv = t >> 6, l = t & 63;
  const int m16 = l & 15, g = l >> 4;
  const int nb = blockIdx.x * 64 + wv * 16;
  if (nb >= NN) return;
  int row = nb + m16; if (row >= NN) row = NN - 1;
  const short* xr = xb + (size_t)row * 64;
  bf8_t a0 = *(const bf8_t*)(xr + g * 8);
  bf8_t a1 = *(const bf8_t*)(xr + 32 + g * 8);
  const short* wl = w1f_l + l * 8;

  f4_t accS[8], accD[8];
  #pragma unroll
  for (int nt = 0; nt < 8; ++nt) {
    float bv = b1[nt * 16 + m16];
    accS[nt] = (f4_t){0.f, 0.f, 0.f, 0.f};
    accD[nt] = (f4_t){bv, bv, bv, bv};
  }
  #pragma unroll
  for (int nt = 0; nt < 8; ++nt) {
    bf8_t b0 = *(const bf8_t*)(wl + (0 * 8 + nt) * 512);   // W1 rows 0..31
    bf8_t b1f = *(const bf8_t*)(wl + (1 * 8 + nt) * 512);  // rows 32..63
    bf8_t b2f = *(const bf8_t*)(wl + (2 * 8 + nt) * 512);  // rows 64..95
    bf8_t b3f = *(const bf8_t*)(wl + (3 * 8 + nt) * 512);  // rows 96..127
    accS[nt] = MFMA16(a0, b0, accS[nt]);
    accS[nt] = MFMA16(a1, b1f, accS[nt]);
    accD[nt] = MFMA16(a0, b2f, accD[nt]);
    accD[nt] = MFMA16(a1, b3f, accD[nt]);
  }
  #pragma unroll
  for (int nt = 0; nt < 8; ++nt) {
    #pragma unroll
    for (int r = 0; r < 4; ++r) {
      int n = nb + g * 4 + r;
      if (n < NN) {
        y1s[(size_t)n * 128 + nt * 16 + m16] = f2bf(accS[nt][r]);
        y1d[(size_t)n * 128 + nt * 16 + m16] = f2bf(accD[nt][r]);
      }
    }
  }
}

// ---------------- k_msg_h: streaming edge h + run-compressed atomic agg -----
// Wave = 16 CSR edges, lane = column pair (2ln, 2ln+1).
// h = relu(y1s[src] + y1d[dst] + ea@W1e); hagg[dst] += sum of h over runs.
__global__ __launch_bounds__(256, 4) void k_msg_h(
    const short* __restrict__ y1s, const short* __restrict__ y1d,
    const short* __restrict__ eac,
    const int* __restrict__ srcc, const int* __restrict__ dstc,
    const float* __restrict__ W1l,   // layer's fp32 W1 (for rows 128..135)
    float* __restrict__ hagg)
{
  const int t = threadIdx.x;
  const int wv = t >> 6, ln = t & 63;
  const int p0 = blockIdx.x * 64 + wv * 16;
  if (p0 >= NE) return;

  // W1e columns for this lane (fp32, L2-hot)
  float we[8][2];
  #pragma unroll
  for (int f = 0; f < 8; ++f) {
    we[f][0] = W1l[(128 + f) * 128 + 2 * ln];
    we[f][1] = W1l[(128 + f) * 128 + 2 * ln + 1];
  }
  // stage indices / edge attrs
  const int li = ln & 15;
  int srcv = srcc[p0 + li];
  int dstv = dstc[p0 + li];
  unsigned eaw = ((const unsigned*)eac)[(size_t)(p0 + (ln >> 2)) * 4 + (ln & 3)];

  // burst-issue gathers (one coalesced 256B row per instruction)
  unsigned ys[16], yd[16];
  #pragma unroll
  for (int i = 0; i < 16; ++i) {
    int s = __shfl(srcv, i, 64);
    int d = __shfl(dstv, i, 64);
    ys[i] = *(const unsigned*)(y1s + (size_t)s * 128 + 2 * ln);
    yd[i] = *(const unsigned*)(y1d + (size_t)d * 128 + 2 * ln);
  }

  // serial walk with run compression (all control wave-uniform)
  float s0 = 0.f, s1 = 0.f;
  int cur = -1;
  #pragma unroll
  for (int i = 0; i < 16; ++i) {
    if (p0 + i >= NE) break;
    int d = __shfl(dstv, i, 64);
    if (d != cur) {
      if (cur >= 0) {
        atomicAdd(&hagg[(size_t)cur * 128 + 2 * ln], s0);
        atomicAdd(&hagg[(size_t)cur * 128 + 2 * ln + 1], s1);
      }
      cur = d; s0 = 0.f; s1 = 0.f;
    }
    float z0 = 0.f, z1 = 0.f;
    #pragma unroll
    for (int w = 0; w < 4; ++w) {
      unsigned u = __shfl(eaw, 4 * i + w, 64);
      float e0 = bf_lo(u), e1 = bf_hi(u);
      z0 += e0 * we[2 * w][0] + e1 * we[2 * w + 1][0];
      z1 += e0 * we[2 * w][1] + e1 * we[2 * w + 1][1];
    }
    float h0 = fmaxf(bf_lo(ys[i]) + bf_lo(yd[i]) + z0, 0.f);
    float h1 = fmaxf(bf_hi(ys[i]) + bf_hi(yd[i]) + z1, 0.f);
    s0 += h0; s1 += h1;
  }
  if (cur >= 0) {
    atomicAdd(&hagg[(size_t)cur * 128 + 2 * ln], s0);
    atomicAdd(&hagg[(size_t)cur * 128 + 2 * ln + 1], s1);
  }
}

// ---------------- k_aggw2: agg = (hagg@W2 + deg*b2) / (deg+1e-6), in place --
__global__ __launch_bounds__(256, 4) void k_aggw2(
    float* __restrict__ hagg, const int* __restrict__ cnt,
    const short* __restrict__ w2f_l, const float* __restrict__ b2)
{
  const int t = threadIdx.x;
  const int wv = t >> 6, l = t & 63;
  const int m16 = l & 15, g = l >> 4;
  const int nb = blockIdx.x * 64 + wv * 16;
  if (nb >= NN) return;
  int row = nb + m16; if (row >= NN) row = NN - 1;
  const float* hr = hagg + (size_t)row * 128;

  bf8_t a[4];
  #pragma unroll
  for (int ks = 0; ks < 4; ++ks) {
    float4 q0 = *(const float4*)(hr + ks * 32 + g * 8);
    float4 q1 = *(const float4*)(hr + ks * 32 + g * 8 + 4);
    bf8_t av = {f2bf(q0.x), f2bf(q0.y), f2bf(q0.z), f2bf(q0.w),
                f2bf(q1.x), f2bf(q1.y), f2bf(q1.z), f2bf(q1.w)};
    a[ks] = av;
  }
  float dg[4], iv[4];
  #pragma unroll
  for (int r = 0; r < 4; ++r) {
    int n = nb + g * 4 + r;
    int c = (n < NN) ? cnt[n] : 0;
    dg[r] = (float)c;
    iv[r] = 1.f / ((float)c + 1e-6f);
  }
  const short* wl = w2f_l + l * 8;
  f4_t acc[8];
  #pragma unroll
  for (int nt = 0; nt < 8; ++nt) {
    float bv = b2[nt * 16 + m16];
    acc[nt] = (f4_t){dg[0] * bv, dg[1] * bv, dg[2] * bv, dg[3] * bv};
  }
  #pragma unroll
  for (int ks = 0; ks < 4; ++ks) {
    #pragma unroll
    for (int nt = 0; nt < 8; ++nt) {
      bf8_t bf = *(const bf8_t*)(wl + (ks * 8 + nt) * 512);
      acc[nt] = MFMA16(a[ks], bf, acc[nt]);
    }
  }
  #pragma unroll
  for (int nt = 0; nt < 8; ++nt) {
    #pragma unroll
    for (int r = 0; r < 4; ++r) {
      int n = nb + g * 4 + r;
      if (n < NN) hagg[(size_t)n * 128 + nt * 16 + m16] = acc[nt][r] * iv[r];
    }
  }
}

// ---------------- update MLP + residual + LayerNorm (per layer) -------------
// agg is pre-scaled (mean + bias already applied by k_aggw2)
__global__ __launch_bounds__(256, 1) void k_upd(
    float* __restrict__ x, short* __restrict__ xb, const float* __restrict__ agg,
    const float* __restrict__ Wu, const float* __restrict__ bu,
    const float* __restrict__ lng, const float* __restrict__ lnb)
{
  __shared__ __align__(16) float sWu[192 * 64];
  __shared__ __align__(16) float sA2[192 * 132];
  const int t = threadIdx.x;
  for (int i = t * 4; i < 192 * 64; i += 1024) *(float4*)&sWu[i] = *(const float4*)&Wu[i];
  const int j0 = (t & 15) * 4;
  const int n0 = (t >> 4) * 8;
  const int wv = t >> 6, ln = t & 63;
  const float4 bias = *(const float4*)&bu[j0];
  const float4 g4 = *(const float4*)&lng[j0];
  const float4 be4 = *(const float4*)&lnb[j0];
  __syncthreads();

  for (int tile = blockIdx.x; tile < (NN + 127) / 128; tile += gridDim.x) {
    const int nbase = tile * 128;
    __syncthreads();
    for (int i = 0; i < 32; ++i) {
      int nl = wv * 32 + i;
      int n = nbase + nl;
      float vx = 0.f, va = 0.f, vb = 0.f;
      if (n < NN) {
        vx = x[(size_t)n * 64 + ln];
        va = agg[(size_t)n * 128 + ln];
        vb = agg[(size_t)n * 128 + 64 + ln];
      }
      sA2[ln * 132 + nl] = vx;
      sA2[(64 + ln) * 132 + nl] = va;
      sA2[(128 + ln) * 132 + nl] = vb;
    }
    __syncthreads();
    float acc[8][4];
    #pragma unroll
    for (int ee = 0; ee < 8; ++ee) {
      acc[ee][0] = bias.x; acc[ee][1] = bias.y; acc[ee][2] = bias.z; acc[ee][3] = bias.w;
    }
    #pragma unroll 8
    for (int k = 0; k < 192; ++k) {
      float4 bf = *(const float4*)&sWu[k * 64 + j0];
      float4 p0 = *(const float4*)&sA2[k * 132 + n0];
      float4 p1 = *(const float4*)&sA2[k * 132 + n0 + 4];
      float af[8] = {p0.x, p0.y, p0.z, p0.w, p1.x, p1.y, p1.z, p1.w};
      #pragma unroll
      for (int ee = 0; ee < 8; ++ee) {
        acc[ee][0] += af[ee] * bf.x; acc[ee][1] += af[ee] * bf.y;
        acc[ee][2] += af[ee] * bf.z; acc[ee][3] += af[ee] * bf.w;
      }
    }
    float ov[8][4];
    #pragma unroll
    for (int jj = 0; jj < 4; ++jj) {
      float4 r0 = *(const float4*)&sA2[(j0 + jj) * 132 + n0];
      float4 r1 = *(const float4*)&sA2[(j0 + jj) * 132 + n0 + 4];
      ov[0][jj] = r0.x + fmaxf(acc[0][jj], 0.f);
      ov[1][jj] = r0.y + fmaxf(acc[1][jj], 0.f);
      ov[2][jj] = r0.z + fmaxf(acc[2][jj], 0.f);
      ov[3][jj] = r0.w + fmaxf(acc[3][jj], 0.f);
      ov[4][jj] = r1.x + fmaxf(acc[4][jj], 0.f);
      ov[5][jj] = r1.y + fmaxf(acc[5][jj], 0.f);
      ov[6][jj] = r1.z + fmaxf(acc[6][jj], 0.f);
      ov[7][jj] = r1.w + fmaxf(acc[7][jj], 0.f);
    }
    #pragma unroll
    for (int ee = 0; ee < 8; ++ee) {
      float s1 = ov[ee][0] + ov[ee][1] + ov[ee][2] + ov[ee][3];
      float s2 = ov[ee][0] * ov[ee][0] + ov[ee][1] * ov[ee][1] +
                 ov[ee][2] * ov[ee][2] + ov[ee][3] * ov[ee][3];
      #pragma unroll
      for (int off = 1; off < 16; off <<= 1) {
        s1 += __shfl_xor(s1, off, 64);
        s2 += __shfl_xor(s2, off, 64);
      }
      float mu = s1 * 0.015625f;
      float var = s2 * 0.015625f - mu * mu;
      float rs = rsqrtf(var + 1e-5f);
      int n = nbase + n0 + ee;
      if (n < NN) {
        float4 y;
        y.x = (ov[ee][0] - mu) * rs * g4.x + be4.x;
        y.y = (ov[ee][1] - mu) * rs * g4.y + be4.y;
        y.z = (ov[ee][2] - mu) * rs * g4.z + be4.z;
        y.w = (ov[ee][3] - mu) * rs * g4.w + be4.w;
        *(float4*)&x[(size_t)n * 64 + j0] = y;
        short4 o; o.x = f2bf(y.x); o.y = f2bf(y.y); o.z = f2bf(y.z); o.w = f2bf(y.w);
        *(short4*)&xb[(size_t)n * 64 + j0] = o;
      }
    }
  }
}

// ---------------- MFMA edge predictor: 136->128->64->1 + tanh (unchanged) ---
__global__ __launch_bounds__(256, 2) void k_pred_mfma(
    const short* __restrict__ xb, const short* __restrict__ eab,
    const int* __restrict__ src, const int* __restrict__ dst,
    const short* __restrict__ w1, const float* __restrict__ b1,
    const short* __restrict__ w2, const float* __restrict__ b2,
    const float* __restrict__ W3, const float* __restrict__ b3,
    float* __restrict__ out)
{
  __shared__ short sH[4 * 2 * 16 * 136];   // 34.8 KB
  const int t = threadIdx.x;
  const int wv = t >> 6, l = t & 63;
  const int m16 = l & 15, g = l >> 4;
  const int ebase = blockIdx.x * 128 + wv * 32;

  bf8_t a[2][5];
  #pragma unroll
  for (int st = 0; st < 2; ++st) {
    int p = ebase + st * 16 + m16;
    int pc = p < NE ? p : NE - 1;
    int s = src[pc];
    int d = dst[pc];
    const short* rs = xb + (size_t)s * 64;
    const short* rd = xb + (size_t)d * 64;
    a[st][0] = *(const bf8_t*)(rs + g * 8);
    a[st][1] = *(const bf8_t*)(rs + 32 + g * 8);
    a[st][2] = *(const bf8_t*)(rd + g * 8);
    a[st][3] = *(const bf8_t*)(rd + 32 + g * 8);
    bf8_t z = {0, 0, 0, 0, 0, 0, 0, 0};
    a[st][4] = z;
    if (g == 0) a[st][4] = *(const bf8_t*)(eab + (size_t)pc * 8);
  }

  const short* w1l = w1 + l * 8;
  f4_t acc[2][8];
  #pragma unroll
  for (int nt = 0; nt < 8; ++nt) {
    float bv = b1[nt * 16 + m16];
    acc[0][nt] = (f4_t){bv, bv, bv, bv};
    acc[1][nt] = (f4_t){bv, bv, bv, bv};
  }
  #pragma unroll
  for (int ks = 0; ks < 5; ++ks) {
    #pragma unroll
    for (int nt = 0; nt < 8; ++nt) {
      bf8_t bf = *(const bf8_t*)(w1l + (ks * 8 + nt) * 512);
      acc[0][nt] = MFMA16(a[0][ks], bf, acc[0][nt]);
      acc[1][nt] = MFMA16(a[1][ks], bf, acc[1][nt]);
    }
  }
  short* sh = sH + wv * (2 * 16 * 136);
  #pragma unroll
  for (int st = 0; st < 2; ++st) {
    #pragma unroll
    for (int nt = 0; nt < 8; ++nt) {
      #pragma unroll
      for (int r = 0; r < 4; ++r) {
        sh[st * 2176 + (g * 4 + r) * 136 + nt * 16 + m16] =
            f2bf(fmaxf(acc[st][nt][r], 0.f));
      }
    }
  }

  const short* w2l = w2 + l * 8;
  f4_t acc2[2][4];
  #pragma unroll
  for (int nt = 0; nt < 4; ++nt) {
    float bv = b2[nt * 16 + m16];
    acc2[0][nt] = (f4_t){bv, bv, bv, bv};
    acc2[1][nt] = (f4_t){bv, bv, bv, bv};
  }
  #pragma unroll
  for (int ks = 0; ks < 4; ++ks) {
    bf8_t af0 = *(const bf8_t*)(sh + m16 * 136 + ks * 32 + g * 8);
    bf8_t af1 = *(const bf8_t*)(sh + 2176 + m16 * 136 + ks * 32 + g * 8);
    #pragma unroll
    for (int nt = 0; nt < 4; ++nt) {
      bf8_t bf = *(const bf8_t*)(w2l + (ks * 4 + nt) * 512);
      acc2[0][nt] = MFMA16(af0, bf, acc2[0][nt]);
      acc2[1][nt] = MFMA16(af1, bf, acc2[1][nt]);
    }
  }

  float w3v[4];
  #pragma unroll
  for (int nt = 0; nt < 4; ++nt) w3v[nt] = W3[nt * 16 + m16];
  const float b3v = b3[0];
  #pragma unroll
  for (int st = 0; st < 2; ++st) {
    #pragma unroll
    for (int r = 0; r < 4; ++r) {
      float v = fmaxf(acc2[st][0][r], 0.f) * w3v[0] + fmaxf(acc2[st][1][r], 0.f) * w3v[1] +
                fmaxf(acc2[st][2][r], 0.f) * w3v[2] + fmaxf(acc2[st][3][r], 0.f) * w3v[3];
      #pragma unroll
      for (int off = 1; off < 16; off <<= 1) v += __shfl_xor(v, off, 64);
      int e = ebase + st * 16 + g * 4 + r;
      if (m16 == 0 && e < NE) out[e] = tanhf(v + b3v);
    }
  }
}

extern "C" void kernel_launch(void* const* d_in, const int* in_sizes, int n_in,
                              void* d_out, int out_size, void* d_ws, size_t ws_size,
                              hipStream_t stream)
{
  (void)in_sizes; (void)n_in; (void)out_size; (void)ws_size;
  const float* nf  = (const float*)d_in[0];
  const float* ea  = (const float*)d_in[1];
  const float* eW  = (const float*)d_in[2];
  const float* eb  = (const float*)d_in[3];
  const float* mW1 = (const float*)d_in[4];
  const float* mb1 = (const float*)d_in[5];
  const float* mW2 = (const float*)d_in[6];
  const float* mb2 = (const float*)d_in[7];
  const float* uW  = (const float*)d_in[8];
  const float* ub  = (const float*)d_in[9];
  const float* lg  = (const float*)d_in[10];
  const float* lb  = (const float*)d_in[11];
  const float* pW1 = (const float*)d_in[12];
  const float* pb1 = (const float*)d_in[13];
  const float* pW2 = (const float*)d_in[14];
  const float* pb2 = (const float*)d_in[15];
  const float* pW3 = (const float*)d_in[16];
  const float* pb3 = (const float*)d_in[17];
  const int*   ei  = (const int*)d_in[18];
  const int* srcI = ei;
  const int* dstI = ei + NE;
  float* out = (float*)d_out;

  // workspace (~91 MB)
  char* w = (char*)d_ws;
  float* x    = (float*)w;  w += (size_t)NN * 64 * 4;          // 12.8 MB
  float* hagg = (float*)w;  w += (size_t)NN * 128 * 4;         // 25.6 MB (also final agg)
  short* xb   = (short*)w;  w += (size_t)NN * 64 * 2;          // 6.4 MB
  short* eab  = (short*)w;  w += (size_t)NE * 8 * 2;           // 8 MB
  short* eac  = (short*)w;  w += (size_t)(NE + 128) * 8 * 2;   // 8 MB (CSR order)
  short* y1s  = (short*)w;  w += (size_t)NN * 128 * 2;         // 12.8 MB
  short* y1d  = (short*)w;  w += (size_t)NN * 128 * 2;         // 12.8 MB
  short* w1f  = (short*)w;  w += (size_t)3 * 20480 * 2;
  short* w2f  = (short*)w;  w += (size_t)3 * 16384 * 2;
  short* pw1f = (short*)w;  w += (size_t)20480 * 2;
  short* pw2f = (short*)w;  w += (size_t)8192 * 2;
  int*   cnt  = (int*)w;    w += (size_t)NN * 4;
  int*   ptr  = (int*)w;    w += (size_t)(NN + 4) * 4;
  int*   cur  = (int*)w;    w += (size_t)NN * 4;
  int*   dstc = (int*)w;    w += (size_t)(NE + 128) * 4;
  int*   srcc = (int*)w;    w += (size_t)(NE + 128) * 4;

  k_zero_i<<<64, 256, 0, stream>>>(cnt, NN);
  k_embed<<<(NN * 16 + 255) / 256, 256, 0, stream>>>(nf, eW, eb, x, xb);
  k_hist<<<(NE + 255) / 256, 256, 0, stream>>>(dstI, cnt);
  k_scan<<<1, 1024, 0, stream>>>(cnt, ptr, cur);
  k_prep_ea<<<(NE * 2 + 255) / 256, 256, 0, stream>>>(ea, eab);
  k_fill<<<(NE + 255) / 256, 256, 0, stream>>>(srcI, dstI, eab, cur, dstc, srcc, eac);
  k_prep_w1<<<240, 256, 0, stream>>>(mW1, w1f);
  k_prep_w2<<<192, 256, 0, stream>>>(mW2, w2f);
  k_prep_pw1<<<80, 256, 0, stream>>>(pW1, pw1f);
  k_prep_pw2<<<32, 256, 0, stream>>>(pW2, pw2f);

  const int ngrid = (NN + 63) / 64;
  const int egrid = (NE + 63) / 64;
  for (int l = 0; l < 3; ++l) {
    k_zero_f4<<<1024, 256, 0, stream>>>((float4*)hagg, NN * 128 / 4);
    k_y1<<<ngrid, 256, 0, stream>>>(xb, w1f + (size_t)l * 20480,
        mb1 + (size_t)l * 128, y1s, y1d);
    k_msg_h<<<egrid, 256, 0, stream>>>(y1s, y1d, eac, srcc, dstc,
        mW1 + (size_t)l * 136 * 128, hagg);
    k_aggw2<<<ngrid, 256, 0, stream>>>(hagg, cnt,
        w2f + (size_t)l * 16384, mb2 + (size_t)l * 128);
    k_upd<<<391, 256, 0, stream>>>(x, xb, hagg,
        uW + (size_t)l * 192 * 64, ub + (size_t)l * 64,
        lg + (size_t)l * 64, lb + (size_t)l * 64);
  }
  k_pred_mfma<<<(NE + 127) / 128, 256, 0, stream>>>(xb, eab, srcI, dstI,
      pw1f, pb1, pw2f, pb2, pW3, pb3, out);
}

// Round 7
// 662.032 us; speedup vs baseline: 6.6260x; 1.2756x over previous
//
#include <hip/hip_runtime.h>

#define NN 50000
#define NE 500000

typedef __attribute__((ext_vector_type(8))) short bf8_t;   // 8 x bf16
typedef __attribute__((ext_vector_type(4))) float f4_t;    // MFMA acc
#define MFMA16(a, b, c) __builtin_amdgcn_mfma_f32_16x16x32_bf16(a, b, c, 0, 0, 0)

__device__ __forceinline__ short f2bf(float f) {
  unsigned u = __float_as_uint(f);
  u += 0x7fffu + ((u >> 16) & 1u);   // RNE
  return (short)(u >> 16);
}
__device__ __forceinline__ float bf_lo(unsigned u) { return __uint_as_float(u << 16); }
__device__ __forceinline__ float bf_hi(unsigned u) { return __uint_as_float(u & 0xffff0000u); }

// ---------------- zero helpers ----------------
__global__ __launch_bounds__(256) void k_zero_f4(float4* __restrict__ p, int n4)
{
  for (int i = blockIdx.x * 256 + threadIdx.x; i < n4; i += gridDim.x * 256)
    p[i] = make_float4(0.f, 0.f, 0.f, 0.f);
}
__global__ __launch_bounds__(256) void k_zero_i(int* __restrict__ p, int n)
{
  for (int i = blockIdx.x * 256 + threadIdx.x; i < n; i += gridDim.x * 256)
    p[i] = 0;
}

// ---------------- weight prep: fragment-contiguous bf16 layouts -------------
// w1f[l][ks(5)][nt(8)][lane(64)][8]
__global__ __launch_bounds__(256) void k_prep_w1(const float* __restrict__ W1,
                                                 short* __restrict__ w1f)
{
  int idx = blockIdx.x * 256 + threadIdx.x;
  if (idx >= 3 * 5 * 8 * 64 * 8) return;
  int l = idx / 20480;
  int rem = idx - l * 20480;
  int ks = rem / 4096;
  int nt = (rem >> 9) & 7;
  int lane = (rem >> 3) & 63;
  int j = rem & 7;
  int k = ks * 32 + (lane >> 4) * 8 + j;
  int n = nt * 16 + (lane & 15);
  float v = (k < 136) ? W1[(size_t)l * 136 * 128 + (size_t)k * 128 + n] : 0.f;
  w1f[idx] = f2bf(v);
}
// w2f[l][ks(4)][nt(8)][64][8]
__global__ __launch_bounds__(256) void k_prep_w2(const float* __restrict__ W2,
                                                 short* __restrict__ w2f)
{
  int idx = blockIdx.x * 256 + threadIdx.x;
  if (idx >= 3 * 4 * 8 * 64 * 8) return;
  int l = idx / 16384;
  int rem = idx - l * 16384;
  int ks = rem / 4096;
  int nt = (rem >> 9) & 7;
  int lane = (rem >> 3) & 63;
  int j = rem & 7;
  int k = ks * 32 + (lane >> 4) * 8 + j;
  int n = nt * 16 + (lane & 15);
  w2f[idx] = f2bf(W2[(size_t)l * 128 * 128 + (size_t)k * 128 + n]);
}
// wuf[l][ks(6)][nt(4)][64][8] ; element = Wu[l][k][n], K=192, N=64
__global__ __launch_bounds__(256) void k_prep_wu(const float* __restrict__ Wu,
                                                 short* __restrict__ wuf)
{
  int idx = blockIdx.x * 256 + threadIdx.x;
  if (idx >= 3 * 6 * 4 * 64 * 8) return;
  int l = idx / 12288;
  int rem = idx - l * 12288;
  int ks = rem / 2048;
  int nt = (rem >> 9) & 3;
  int lane = (rem >> 3) & 63;
  int j = rem & 7;
  int k = ks * 32 + (lane >> 4) * 8 + j;
  int n = nt * 16 + (lane & 15);
  wuf[idx] = f2bf(Wu[(size_t)l * 192 * 64 + (size_t)k * 64 + n]);
}
// pred W1 [136,128] -> pw1f[ks(5)][nt(8)][64][8]  (same layout as w1f per-layer)
__global__ __launch_bounds__(256) void k_prep_pw1(const float* __restrict__ W1,
                                                  short* __restrict__ wf)
{
  int idx = blockIdx.x * 256 + threadIdx.x;
  if (idx >= 5 * 8 * 64 * 8) return;
  int ks = idx / 4096;
  int nt = (idx >> 9) & 7;
  int lane = (idx >> 3) & 63;
  int j = idx & 7;
  int k = ks * 32 + (lane >> 4) * 8 + j;
  int n = nt * 16 + (lane & 15);
  float v = (k < 136) ? W1[(size_t)k * 128 + n] : 0.f;
  wf[idx] = f2bf(v);
}
// pred W2 [128,64] -> pw2f[ks(4)][nt(4)][64][8]
__global__ __launch_bounds__(256) void k_prep_pw2(const float* __restrict__ W2,
                                                  short* __restrict__ wf)
{
  int idx = blockIdx.x * 256 + threadIdx.x;
  if (idx >= 4 * 4 * 64 * 8) return;
  int ks = idx / 2048;
  int nt = (idx >> 9) & 3;
  int lane = (idx >> 3) & 63;
  int j = idx & 7;
  int k = ks * 32 + (lane >> 4) * 8 + j;
  int n = nt * 16 + (lane & 15);
  wf[idx] = f2bf(W2[(size_t)k * 64 + n]);
}
__global__ __launch_bounds__(256) void k_prep_ea(const float* __restrict__ ea,
                                                 short* __restrict__ eab)
{
  int i = blockIdx.x * 256 + threadIdx.x;
  if (i >= NE * 2) return;
  float4 v = *(const float4*)&ea[(size_t)i * 4];
  short4 o;
  o.x = f2bf(v.x); o.y = f2bf(v.y); o.z = f2bf(v.z); o.w = f2bf(v.w);
  *(short4*)&eab[(size_t)i * 4] = o;
}

// ---------------- embed: x = relu(nf @ We + be) ----------------
__global__ __launch_bounds__(256) void k_embed(
    const float* __restrict__ nf, const float* __restrict__ We,
    const float* __restrict__ be, float* __restrict__ x, short* __restrict__ xb)
{
  int idx = blockIdx.x * 256 + threadIdx.x;
  int n = idx >> 4, g = idx & 15;
  if (n >= NN) return;
  int j0 = g * 4;
  float4 b4 = *(const float4*)&be[j0];
  float a0 = b4.x, a1 = b4.y, a2 = b4.z, a3 = b4.w;
  #pragma unroll
  for (int k = 0; k < 7; ++k) {
    float v = nf[n * 7 + k];
    float4 w = *(const float4*)&We[k * 64 + j0];
    a0 += v * w.x; a1 += v * w.y; a2 += v * w.z; a3 += v * w.w;
  }
  a0 = fmaxf(a0, 0.f); a1 = fmaxf(a1, 0.f); a2 = fmaxf(a2, 0.f); a3 = fmaxf(a3, 0.f);
  *(float4*)&x[(size_t)n * 64 + j0] = make_float4(a0, a1, a2, a3);
  short4 o; o.x = f2bf(a0); o.y = f2bf(a1); o.z = f2bf(a2); o.w = f2bf(a3);
  *(short4*)&xb[(size_t)n * 64 + j0] = o;
}

// ---------------- degree histogram ----------------
__global__ __launch_bounds__(256) void k_hist(const int* __restrict__ dst, int* __restrict__ cnt)
{
  int e = blockIdx.x * 256 + threadIdx.x;
  if (e < NE) atomicAdd(&cnt[dst[e]], 1);
}

// ---------------- exclusive scan (single block) ----------------
__global__ __launch_bounds__(1024) void k_scan(const int* __restrict__ cnt,
                                               int* __restrict__ ptr, int* __restrict__ cur)
{
  __shared__ int s[1024];
  __shared__ int carry_s;
  const int t = threadIdx.x;
  if (t == 0) carry_s = 0;
  __syncthreads();
  for (int base = 0; base < NN; base += 1024) {
    int v = (base + t < NN) ? cnt[base + t] : 0;
    s[t] = v;
    __syncthreads();
    for (int off = 1; off < 1024; off <<= 1) {
      int a = s[t];
      int b = (t >= off) ? s[t - off] : 0;
      __syncthreads();
      s[t] = a + b;
      __syncthreads();
    }
    int carry = carry_s;
    if (base + t < NN) {
      int ex = carry + s[t] - v;
      ptr[base + t] = ex;
      cur[base + t] = ex;
    }
    __syncthreads();
    if (t == 1023) carry_s = carry + s[1023];
    __syncthreads();
  }
  if (t == 0) ptr[NN] = carry_s;
}

// ---------------- CSR fill: CSR-ordered dst, src, edge_attr ----------------
__global__ __launch_bounds__(256) void k_fill(
    const int* __restrict__ src, const int* __restrict__ dst,
    const short* __restrict__ eab, int* __restrict__ cur,
    int* __restrict__ dstc, int* __restrict__ srcc, short* __restrict__ eac)
{
  int e = blockIdx.x * 256 + threadIdx.x;
  if (e < 128) { dstc[NE + e] = 0; srcc[NE + e] = 0; }
  if (e < NE) {
    int d = dst[e];
    int s = atomicAdd(&cur[d], 1);
    dstc[s] = d;
    srcc[s] = src[e];
    *(bf8_t*)(eac + (size_t)s * 8) = *(const bf8_t*)(eab + (size_t)e * 8);
  }
}

// ---------------- k_y1: per-node dual projection (also used for pred) -------
// y1s = xb @ W[0:64] ; y1d = xb @ W[64:128] + b
__global__ __launch_bounds__(256, 4) void k_y1(
    const short* __restrict__ xb, const short* __restrict__ w1f_l,
    const float* __restrict__ b1,
    short* __restrict__ y1s, short* __restrict__ y1d)
{
  const int t = threadIdx.x;
  const int wv = t >> 6, l = t & 63;
  const int m16 = l & 15, g = l >> 4;
  const int nb = blockIdx.x * 64 + wv * 16;
  if (nb >= NN) return;
  int row = nb + m16; if (row >= NN) row = NN - 1;
  const short* xr = xb + (size_t)row * 64;
  bf8_t a0 = *(const bf8_t*)(xr + g * 8);
  bf8_t a1 = *(const bf8_t*)(xr + 32 + g * 8);
  const short* wl = w1f_l + l * 8;

  f4_t accS[8], accD[8];
  #pragma unroll
  for (int nt = 0; nt < 8; ++nt) {
    float bv = b1[nt * 16 + m16];
    accS[nt] = (f4_t){0.f, 0.f, 0.f, 0.f};
    accD[nt] = (f4_t){bv, bv, bv, bv};
  }
  #pragma unroll
  for (int nt = 0; nt < 8; ++nt) {
    bf8_t b0 = *(const bf8_t*)(wl + (0 * 8 + nt) * 512);
    bf8_t b1f = *(const bf8_t*)(wl + (1 * 8 + nt) * 512);
    bf8_t b2f = *(const bf8_t*)(wl + (2 * 8 + nt) * 512);
    bf8_t b3f = *(const bf8_t*)(wl + (3 * 8 + nt) * 512);
    accS[nt] = MFMA16(a0, b0, accS[nt]);
    accS[nt] = MFMA16(a1, b1f, accS[nt]);
    accD[nt] = MFMA16(a0, b2f, accD[nt]);
    accD[nt] = MFMA16(a1, b3f, accD[nt]);
  }
  #pragma unroll
  for (int nt = 0; nt < 8; ++nt) {
    #pragma unroll
    for (int r = 0; r < 4; ++r) {
      int n = nb + g * 4 + r;
      if (n < NN) {
        y1s[(size_t)n * 128 + nt * 16 + m16] = f2bf(accS[nt][r]);
        y1d[(size_t)n * 128 + nt * 16 + m16] = f2bf(accD[nt][r]);
      }
    }
  }
}

// ---------------- k_msg_h: streaming edge h + run-compressed atomic agg -----
__global__ __launch_bounds__(256, 4) void k_msg_h(
    const short* __restrict__ y1s, const short* __restrict__ y1d,
    const short* __restrict__ eac,
    const int* __restrict__ srcc, const int* __restrict__ dstc,
    const float* __restrict__ W1l,
    float* __restrict__ hagg)
{
  const int t = threadIdx.x;
  const int wv = t >> 6, ln = t & 63;
  const int p0 = blockIdx.x * 64 + wv * 16;
  if (p0 >= NE) return;

  float we[8][2];
  #pragma unroll
  for (int f = 0; f < 8; ++f) {
    we[f][0] = W1l[(128 + f) * 128 + 2 * ln];
    we[f][1] = W1l[(128 + f) * 128 + 2 * ln + 1];
  }
  const int li = ln & 15;
  int srcv = srcc[p0 + li];
  int dstv = dstc[p0 + li];
  unsigned eaw = ((const unsigned*)eac)[(size_t)(p0 + (ln >> 2)) * 4 + (ln & 3)];

  unsigned ys[16], yd[16];
  #pragma unroll
  for (int i = 0; i < 16; ++i) {
    int s = __shfl(srcv, i, 64);
    int d = __shfl(dstv, i, 64);
    ys[i] = *(const unsigned*)(y1s + (size_t)s * 128 + 2 * ln);
    yd[i] = *(const unsigned*)(y1d + (size_t)d * 128 + 2 * ln);
  }

  float s0 = 0.f, s1 = 0.f;
  int cur = -1;
  #pragma unroll
  for (int i = 0; i < 16; ++i) {
    if (p0 + i >= NE) break;
    int d = __shfl(dstv, i, 64);
    if (d != cur) {
      if (cur >= 0) {
        atomicAdd(&hagg[(size_t)cur * 128 + 2 * ln], s0);
        atomicAdd(&hagg[(size_t)cur * 128 + 2 * ln + 1], s1);
      }
      cur = d; s0 = 0.f; s1 = 0.f;
    }
    float z0 = 0.f, z1 = 0.f;
    #pragma unroll
    for (int w = 0; w < 4; ++w) {
      unsigned u = __shfl(eaw, 4 * i + w, 64);
      float e0 = bf_lo(u), e1 = bf_hi(u);
      z0 += e0 * we[2 * w][0] + e1 * we[2 * w + 1][0];
      z1 += e0 * we[2 * w][1] + e1 * we[2 * w + 1][1];
    }
    float h0 = fmaxf(bf_lo(ys[i]) + bf_lo(yd[i]) + z0, 0.f);
    float h1 = fmaxf(bf_hi(ys[i]) + bf_hi(yd[i]) + z1, 0.f);
    s0 += h0; s1 += h1;
  }
  if (cur >= 0) {
    atomicAdd(&hagg[(size_t)cur * 128 + 2 * ln], s0);
    atomicAdd(&hagg[(size_t)cur * 128 + 2 * ln + 1], s1);
  }
}

// ---------------- k_node: fused agg@W2 + update-MLP + residual + LN ---------
// Per-wave: 16 nodes. agg = (hagg@W2 + deg*b2)/(deg+1e-6) via MFMA;
// transpose agg through per-wave LDS; upd = relu([x|agg]@Wu + bu); x = LN(x+upd).
__global__ __launch_bounds__(256, 4) void k_node(
    float* __restrict__ x, short* __restrict__ xb,
    const float* __restrict__ hagg, const int* __restrict__ cnt,
    const short* __restrict__ w2f_l, const float* __restrict__ b2,
    const short* __restrict__ wuf_l, const float* __restrict__ bu,
    const float* __restrict__ lng, const float* __restrict__ lnb)
{
  __shared__ short sH[4 * 16 * 136];   // 17.4 KB (per-wave 16x128 agg tiles)
  const int t = threadIdx.x;
  const int wv = t >> 6, l = t & 63;
  const int m16 = l & 15, g = l >> 4;
  const int nb = blockIdx.x * 64 + wv * 16;
  if (nb >= NN) return;
  int row = nb + m16; if (row >= NN) row = NN - 1;

  // ---- A-frags of hagg row (fp32 -> bf16) ----
  const float* hr = hagg + (size_t)row * 128;
  bf8_t a2[4];
  #pragma unroll
  for (int ks = 0; ks < 4; ++ks) {
    float4 q0 = *(const float4*)(hr + ks * 32 + g * 8);
    float4 q1 = *(const float4*)(hr + ks * 32 + g * 8 + 4);
    bf8_t av = {f2bf(q0.x), f2bf(q0.y), f2bf(q0.z), f2bf(q0.w),
                f2bf(q1.x), f2bf(q1.y), f2bf(q1.z), f2bf(q1.w)};
    a2[ks] = av;
  }
  float dg[4], iv[4];
  #pragma unroll
  for (int r = 0; r < 4; ++r) {
    int n = nb + g * 4 + r;
    int c = (n < NN) ? cnt[n] : 0;
    dg[r] = (float)c;
    iv[r] = 1.f / ((float)c + 1e-6f);
  }

  // ---- GEMM: agg = hagg@W2 + deg*b2 ----
  const short* w2l = w2f_l + l * 8;
  f4_t aacc[8];
  #pragma unroll
  for (int nt = 0; nt < 8; ++nt) {
    float bv = b2[nt * 16 + m16];
    aacc[nt] = (f4_t){dg[0] * bv, dg[1] * bv, dg[2] * bv, dg[3] * bv};
  }
  #pragma unroll
  for (int ks = 0; ks < 4; ++ks) {
    #pragma unroll
    for (int nt = 0; nt < 8; ++nt) {
      bf8_t bf = *(const bf8_t*)(w2l + (ks * 8 + nt) * 512);
      aacc[nt] = MFMA16(a2[ks], bf, aacc[nt]);
    }
  }

  // ---- transpose agg (scaled) into per-wave LDS as bf16 ----
  short* sh = sH + wv * (16 * 136);
  #pragma unroll
  for (int nt = 0; nt < 8; ++nt) {
    #pragma unroll
    for (int r = 0; r < 4; ++r) {
      sh[(g * 4 + r) * 136 + nt * 16 + m16] = f2bf(aacc[nt][r] * iv[r]);
    }
  }

  // ---- GEMM: upd = [x(64) | agg(128)] @ Wu + bu  (K=192) ----
  const short* xr = xb + (size_t)row * 64;
  bf8_t a0 = *(const bf8_t*)(xr + g * 8);
  bf8_t a1 = *(const bf8_t*)(xr + 32 + g * 8);
  const short* wul = wuf_l + l * 8;
  f4_t acc[4];
  #pragma unroll
  for (int nt = 0; nt < 4; ++nt) {
    float bv = bu[nt * 16 + m16];
    acc[nt] = (f4_t){bv, bv, bv, bv};
  }
  #pragma unroll
  for (int nt = 0; nt < 4; ++nt) {
    acc[nt] = MFMA16(a0, *(const bf8_t*)(wul + (0 * 4 + nt) * 512), acc[nt]);
    acc[nt] = MFMA16(a1, *(const bf8_t*)(wul + (1 * 4 + nt) * 512), acc[nt]);
  }
  #pragma unroll
  for (int ks = 0; ks < 4; ++ks) {
    bf8_t af = *(const bf8_t*)(sh + m16 * 136 + ks * 32 + g * 8);
    #pragma unroll
    for (int nt = 0; nt < 4; ++nt) {
      acc[nt] = MFMA16(af, *(const bf8_t*)(wul + ((2 + ks) * 4 + nt) * 512), acc[nt]);
    }
  }

  // ---- relu + residual ----
  float ov[4][4];   // [nt][r]
  #pragma unroll
  for (int nt = 0; nt < 4; ++nt) {
    #pragma unroll
    for (int r = 0; r < 4; ++r) {
      int n = nb + g * 4 + r;
      float xv = (n < NN) ? x[(size_t)n * 64 + nt * 16 + m16] : 0.f;
      ov[nt][r] = xv + fmaxf(acc[nt][r], 0.f);
    }
  }
  // ---- LayerNorm across 64 cols (16-lane groups) ----
  const float lg_ = lng[0 * 16 + m16];  // placeholder to keep reg layout simple
  (void)lg_;
  #pragma unroll
  for (int r = 0; r < 4; ++r) {
    float s1 = ov[0][r] + ov[1][r] + ov[2][r] + ov[3][r];
    float s2 = ov[0][r] * ov[0][r] + ov[1][r] * ov[1][r] +
               ov[2][r] * ov[2][r] + ov[3][r] * ov[3][r];
    #pragma unroll
    for (int off = 1; off < 16; off <<= 1) {
      s1 += __shfl_xor(s1, off, 64);
      s2 += __shfl_xor(s2, off, 64);
    }
    float mu = s1 * 0.015625f;
    float var = s2 * 0.015625f - mu * mu;
    float rs = rsqrtf(var + 1e-5f);
    int n = nb + g * 4 + r;
    if (n < NN) {
      #pragma unroll
      for (int nt = 0; nt < 4; ++nt) {
        int col = nt * 16 + m16;
        float y = (ov[nt][r] - mu) * rs * lng[col] + lnb[col];
        x[(size_t)n * 64 + col] = y;
        xb[(size_t)n * 64 + col] = f2bf(y);
      }
    }
  }
}

// ---------------- k_pred2: edge predictor via linear split ------------------
// h1 = relu(py1s[src] + py1d[dst] + ea@pW1e)  (col-layout, coalesced gathers)
// -> LDS transpose -> GEMM2 MFMA (128->64) -> dot W3 + tanh
__global__ __launch_bounds__(256, 4) void k_pred2(
    const short* __restrict__ py1s, const short* __restrict__ py1d,
    const short* __restrict__ eab,
    const int* __restrict__ src, const int* __restrict__ dst,
    const float* __restrict__ pW1,
    const short* __restrict__ pw2f, const float* __restrict__ b2,
    const float* __restrict__ W3, const float* __restrict__ b3,
    float* __restrict__ out)
{
  __shared__ short sH[4 * 16 * 136];   // 17.4 KB
  const int t = threadIdx.x;
  const int wv = t >> 6, ln = t & 63;
  const int m16 = ln & 15, g = ln >> 4;
  const int p0 = blockIdx.x * 64 + wv * 16;
  if (p0 >= NE) return;

  float we[8][2];
  #pragma unroll
  for (int f = 0; f < 8; ++f) {
    we[f][0] = pW1[(128 + f) * 128 + 2 * ln];
    we[f][1] = pW1[(128 + f) * 128 + 2 * ln + 1];
  }
  const int li = ln & 15;
  int ei0 = p0 + li; if (ei0 >= NE) ei0 = NE - 1;
  int srcv = src[ei0];
  int dstv = dst[ei0];
  int ee = p0 + (ln >> 2); if (ee >= NE) ee = NE - 1;
  unsigned eaw = ((const unsigned*)eab)[(size_t)ee * 4 + (ln & 3)];

  unsigned ys[16], yd[16];
  #pragma unroll
  for (int i = 0; i < 16; ++i) {
    int s = __shfl(srcv, i, 64);
    int d = __shfl(dstv, i, 64);
    ys[i] = *(const unsigned*)(py1s + (size_t)s * 128 + 2 * ln);
    yd[i] = *(const unsigned*)(py1d + (size_t)d * 128 + 2 * ln);
  }

  short* sh = sH + wv * (16 * 136);
  #pragma unroll
  for (int i = 0; i < 16; ++i) {
    float z0 = 0.f, z1 = 0.f;
    #pragma unroll
    for (int w = 0; w < 4; ++w) {
      unsigned u = __shfl(eaw, 4 * i + w, 64);
      float e0 = bf_lo(u), e1 = bf_hi(u);
      z0 += e0 * we[2 * w][0] + e1 * we[2 * w + 1][0];
      z1 += e0 * we[2 * w][1] + e1 * we[2 * w + 1][1];
    }
    float h0 = fmaxf(bf_lo(ys[i]) + bf_lo(yd[i]) + z0, 0.f);
    float h1 = fmaxf(bf_hi(ys[i]) + bf_hi(yd[i]) + z1, 0.f);
    unsigned hv = (unsigned)(unsigned short)f2bf(h0) |
                  ((unsigned)(unsigned short)f2bf(h1) << 16);
    *(unsigned*)(sh + i * 136 + 2 * ln) = hv;
  }

  // GEMM2: 128->64 (4 n-tiles), A-frags from LDS
  f4_t acc2[4];
  #pragma unroll
  for (int nt = 0; nt < 4; ++nt) {
    float bv = b2[nt * 16 + m16];
    acc2[nt] = (f4_t){bv, bv, bv, bv};
  }
  const short* w2l = pw2f + ln * 8;
  #pragma unroll
  for (int ks = 0; ks < 4; ++ks) {
    bf8_t af = *(const bf8_t*)(sh + m16 * 136 + ks * 32 + g * 8);
    #pragma unroll
    for (int nt = 0; nt < 4; ++nt) {
      bf8_t bf = *(const bf8_t*)(w2l + (ks * 4 + nt) * 512);
      acc2[nt] = MFMA16(af, bf, acc2[nt]);
    }
  }

  // GEMM3 + tanh
  float w3v[4];
  #pragma unroll
  for (int nt = 0; nt < 4; ++nt) w3v[nt] = W3[nt * 16 + m16];
  const float b3v = b3[0];
  #pragma unroll
  for (int r = 0; r < 4; ++r) {
    float v = fmaxf(acc2[0][r], 0.f) * w3v[0] + fmaxf(acc2[1][r], 0.f) * w3v[1] +
              fmaxf(acc2[2][r], 0.f) * w3v[2] + fmaxf(acc2[3][r], 0.f) * w3v[3];
    #pragma unroll
    for (int off = 1; off < 16; off <<= 1) v += __shfl_xor(v, off, 64);
    int e = p0 + g * 4 + r;
    if (m16 == 0 && e < NE) out[e] = tanhf(v + b3v);
  }
}

extern "C" void kernel_launch(void* const* d_in, const int* in_sizes, int n_in,
                              void* d_out, int out_size, void* d_ws, size_t ws_size,
                              hipStream_t stream)
{
  (void)in_sizes; (void)n_in; (void)out_size; (void)ws_size;
  const float* nf  = (const float*)d_in[0];
  const float* ea  = (const float*)d_in[1];
  const float* eW  = (const float*)d_in[2];
  const float* eb  = (const float*)d_in[3];
  const float* mW1 = (const float*)d_in[4];
  const float* mb1 = (const float*)d_in[5];
  const float* mW2 = (const float*)d_in[6];
  const float* mb2 = (const float*)d_in[7];
  const float* uW  = (const float*)d_in[8];
  const float* ub  = (const float*)d_in[9];
  const float* lg  = (const float*)d_in[10];
  const float* lb  = (const float*)d_in[11];
  const float* pW1 = (const float*)d_in[12];
  const float* pb1 = (const float*)d_in[13];
  const float* pW2 = (const float*)d_in[14];
  const float* pb2 = (const float*)d_in[15];
  const float* pW3 = (const float*)d_in[16];
  const float* pb3 = (const float*)d_in[17];
  const int*   ei  = (const int*)d_in[18];
  const int* srcI = ei;
  const int* dstI = ei + NE;
  float* out = (float*)d_out;

  // workspace (~91 MB)
  char* w = (char*)d_ws;
  float* x    = (float*)w;  w += (size_t)NN * 64 * 4;
  float* hagg = (float*)w;  w += (size_t)NN * 128 * 4;
  short* xb   = (short*)w;  w += (size_t)NN * 64 * 2;
  short* eab  = (short*)w;  w += (size_t)NE * 8 * 2;
  short* eac  = (short*)w;  w += (size_t)(NE + 128) * 8 * 2;
  short* y1s  = (short*)w;  w += (size_t)NN * 128 * 2;   // reused as py1s for pred
  short* y1d  = (short*)w;  w += (size_t)NN * 128 * 2;   // reused as py1d for pred
  short* w1f  = (short*)w;  w += (size_t)3 * 20480 * 2;
  short* w2f  = (short*)w;  w += (size_t)3 * 16384 * 2;
  short* wuf  = (short*)w;  w += (size_t)3 * 12288 * 2;
  short* pw1f = (short*)w;  w += (size_t)20480 * 2;
  short* pw2f = (short*)w;  w += (size_t)8192 * 2;
  int*   cnt  = (int*)w;    w += (size_t)NN * 4;
  int*   ptr  = (int*)w;    w += (size_t)(NN + 4) * 4;
  int*   cur  = (int*)w;    w += (size_t)NN * 4;
  int*   dstc = (int*)w;    w += (size_t)(NE + 128) * 4;
  int*   srcc = (int*)w;    w += (size_t)(NE + 128) * 4;

  k_zero_i<<<64, 256, 0, stream>>>(cnt, NN);
  k_embed<<<(NN * 16 + 255) / 256, 256, 0, stream>>>(nf, eW, eb, x, xb);
  k_hist<<<(NE + 255) / 256, 256, 0, stream>>>(dstI, cnt);
  k_scan<<<1, 1024, 0, stream>>>(cnt, ptr, cur);
  k_prep_ea<<<(NE * 2 + 255) / 256, 256, 0, stream>>>(ea, eab);
  k_fill<<<(NE + 255) / 256, 256, 0, stream>>>(srcI, dstI, eab, cur, dstc, srcc, eac);
  k_prep_w1<<<240, 256, 0, stream>>>(mW1, w1f);
  k_prep_w2<<<192, 256, 0, stream>>>(mW2, w2f);
  k_prep_wu<<<144, 256, 0, stream>>>(uW, wuf);
  k_prep_pw1<<<80, 256, 0, stream>>>(pW1, pw1f);
  k_prep_pw2<<<32, 256, 0, stream>>>(pW2, pw2f);

  const int ngrid = (NN + 63) / 64;
  const int egrid = (NE + 63) / 64;
  for (int l = 0; l < 3; ++l) {
    k_zero_f4<<<1024, 256, 0, stream>>>((float4*)hagg, NN * 128 / 4);
    k_y1<<<ngrid, 256, 0, stream>>>(xb, w1f + (size_t)l * 20480,
        mb1 + (size_t)l * 128, y1s, y1d);
    k_msg_h<<<egrid, 256, 0, stream>>>(y1s, y1d, eac, srcc, dstc,
        mW1 + (size_t)l * 136 * 128, hagg);
    k_node<<<ngrid, 256, 0, stream>>>(x, xb, hagg, cnt,
        w2f + (size_t)l * 16384, mb2 + (size_t)l * 128,
        wuf + (size_t)l * 12288, ub + (size_t)l * 64,
        lg + (size_t)l * 64, lb + (size_t)l * 64);
  }
  // predictor: reuse k_y1 with pred weights into y1s/y1d
  k_y1<<<ngrid, 256, 0, stream>>>(xb, pw1f, pb1, y1s, y1d);
  k_pred2<<<egrid, 256, 0, stream>>>(y1s, y1d, eab, srcI, dstI,
      pW1, pw2f, pb2, pW3, pb3, out);
}

// Round 8
// 586.426 us; speedup vs baseline: 7.4803x; 1.1289x over previous
//
#include <hip/hip_runtime.h>

#define NN 50000
#define NE 500000
#define NBLK ((NN + 1023) / 1024)   // 49 scan blocks

typedef __attribute__((ext_vector_type(8))) short bf8_t;   // 8 x bf16
typedef __attribute__((ext_vector_type(4))) float f4_t;    // MFMA acc
#define MFMA16(a, b, c) __builtin_amdgcn_mfma_f32_16x16x32_bf16(a, b, c, 0, 0, 0)

__device__ __forceinline__ short f2bf(float f) {
  unsigned u = __float_as_uint(f);
  u += 0x7fffu + ((u >> 16) & 1u);   // RNE
  return (short)(u >> 16);
}
__device__ __forceinline__ float bf_lo(unsigned u) { return __uint_as_float(u << 16); }
__device__ __forceinline__ float bf_hi(unsigned u) { return __uint_as_float(u & 0xffff0000u); }

// ---------------- zero helpers ----------------
__global__ __launch_bounds__(256) void k_zero_f4(float4* __restrict__ p, int n4)
{
  for (int i = blockIdx.x * 256 + threadIdx.x; i < n4; i += gridDim.x * 256)
    p[i] = make_float4(0.f, 0.f, 0.f, 0.f);
}
__global__ __launch_bounds__(256) void k_zero_i(int* __restrict__ p, int n)
{
  for (int i = blockIdx.x * 256 + threadIdx.x; i < n; i += gridDim.x * 256)
    p[i] = 0;
}

// ---------------- weight prep: fragment-contiguous bf16 layouts -------------
__global__ __launch_bounds__(256) void k_prep_w1(const float* __restrict__ W1,
                                                 short* __restrict__ w1f)
{
  int idx = blockIdx.x * 256 + threadIdx.x;
  if (idx >= 3 * 5 * 8 * 64 * 8) return;
  int l = idx / 20480;
  int rem = idx - l * 20480;
  int ks = rem / 4096;
  int nt = (rem >> 9) & 7;
  int lane = (rem >> 3) & 63;
  int j = rem & 7;
  int k = ks * 32 + (lane >> 4) * 8 + j;
  int n = nt * 16 + (lane & 15);
  float v = (k < 136) ? W1[(size_t)l * 136 * 128 + (size_t)k * 128 + n] : 0.f;
  w1f[idx] = f2bf(v);
}
__global__ __launch_bounds__(256) void k_prep_w2(const float* __restrict__ W2,
                                                 short* __restrict__ w2f)
{
  int idx = blockIdx.x * 256 + threadIdx.x;
  if (idx >= 3 * 4 * 8 * 64 * 8) return;
  int l = idx / 16384;
  int rem = idx - l * 16384;
  int ks = rem / 4096;
  int nt = (rem >> 9) & 7;
  int lane = (rem >> 3) & 63;
  int j = rem & 7;
  int k = ks * 32 + (lane >> 4) * 8 + j;
  int n = nt * 16 + (lane & 15);
  w2f[idx] = f2bf(W2[(size_t)l * 128 * 128 + (size_t)k * 128 + n]);
}
__global__ __launch_bounds__(256) void k_prep_wu(const float* __restrict__ Wu,
                                                 short* __restrict__ wuf)
{
  int idx = blockIdx.x * 256 + threadIdx.x;
  if (idx >= 3 * 6 * 4 * 64 * 8) return;
  int l = idx / 12288;
  int rem = idx - l * 12288;
  int ks = rem / 2048;
  int nt = (rem >> 9) & 3;
  int lane = (rem >> 3) & 63;
  int j = rem & 7;
  int k = ks * 32 + (lane >> 4) * 8 + j;
  int n = nt * 16 + (lane & 15);
  wuf[idx] = f2bf(Wu[(size_t)l * 192 * 64 + (size_t)k * 64 + n]);
}
__global__ __launch_bounds__(256) void k_prep_pw1(const float* __restrict__ W1,
                                                  short* __restrict__ wf)
{
  int idx = blockIdx.x * 256 + threadIdx.x;
  if (idx >= 5 * 8 * 64 * 8) return;
  int ks = idx / 4096;
  int nt = (idx >> 9) & 7;
  int lane = (idx >> 3) & 63;
  int j = idx & 7;
  int k = ks * 32 + (lane >> 4) * 8 + j;
  int n = nt * 16 + (lane & 15);
  float v = (k < 136) ? W1[(size_t)k * 128 + n] : 0.f;
  wf[idx] = f2bf(v);
}
__global__ __launch_bounds__(256) void k_prep_pw2(const float* __restrict__ W2,
                                                  short* __restrict__ wf)
{
  int idx = blockIdx.x * 256 + threadIdx.x;
  if (idx >= 4 * 4 * 64 * 8) return;
  int ks = idx / 2048;
  int nt = (idx >> 9) & 3;
  int lane = (idx >> 3) & 63;
  int j = idx & 7;
  int k = ks * 32 + (lane >> 4) * 8 + j;
  int n = nt * 16 + (lane & 15);
  wf[idx] = f2bf(W2[(size_t)k * 64 + n]);
}
__global__ __launch_bounds__(256) void k_prep_ea(const float* __restrict__ ea,
                                                 short* __restrict__ eab)
{
  int i = blockIdx.x * 256 + threadIdx.x;
  if (i >= NE * 2) return;
  float4 v = *(const float4*)&ea[(size_t)i * 4];
  short4 o;
  o.x = f2bf(v.x); o.y = f2bf(v.y); o.z = f2bf(v.z); o.w = f2bf(v.w);
  *(short4*)&eab[(size_t)i * 4] = o;
}

// ---------------- embed: x = relu(nf @ We + be) ----------------
__global__ __launch_bounds__(256) void k_embed(
    const float* __restrict__ nf, const float* __restrict__ We,
    const float* __restrict__ be, float* __restrict__ x, short* __restrict__ xb)
{
  int idx = blockIdx.x * 256 + threadIdx.x;
  int n = idx >> 4, g = idx & 15;
  if (n >= NN) return;
  int j0 = g * 4;
  float4 b4 = *(const float4*)&be[j0];
  float a0 = b4.x, a1 = b4.y, a2 = b4.z, a3 = b4.w;
  #pragma unroll
  for (int k = 0; k < 7; ++k) {
    float v = nf[n * 7 + k];
    float4 w = *(const float4*)&We[k * 64 + j0];
    a0 += v * w.x; a1 += v * w.y; a2 += v * w.z; a3 += v * w.w;
  }
  a0 = fmaxf(a0, 0.f); a1 = fmaxf(a1, 0.f); a2 = fmaxf(a2, 0.f); a3 = fmaxf(a3, 0.f);
  *(float4*)&x[(size_t)n * 64 + j0] = make_float4(a0, a1, a2, a3);
  short4 o; o.x = f2bf(a0); o.y = f2bf(a1); o.z = f2bf(a2); o.w = f2bf(a3);
  *(short4*)&xb[(size_t)n * 64 + j0] = o;
}

// ---------------- degree histogram ----------------
__global__ __launch_bounds__(256) void k_hist(const int* __restrict__ dst, int* __restrict__ cnt)
{
  int e = blockIdx.x * 256 + threadIdx.x;
  if (e < NE) atomicAdd(&cnt[dst[e]], 1);
}

// ---------------- parallel exclusive scan (3 kernels) ----------------
// k_scan1: per-block (1024) exclusive scan + block sum, shfl-based
__global__ __launch_bounds__(1024) void k_scan1(const int* __restrict__ cnt,
                                                int* __restrict__ loc, int* __restrict__ bsum)
{
  __shared__ int ws[16];
  const int b = blockIdx.x, t = threadIdx.x;
  const int i = b * 1024 + t;
  const int ln = t & 63, wv = t >> 6;
  int v = (i < NN) ? cnt[i] : 0;
  int s = v;
  #pragma unroll
  for (int off = 1; off < 64; off <<= 1) {
    int u = __shfl_up(s, off, 64);
    if (ln >= off) s += u;
  }
  if (ln == 63) ws[wv] = s;
  __syncthreads();
  if (wv == 0) {
    int wsum = (ln < 16) ? ws[ln] : 0;
    #pragma unroll
    for (int off = 1; off < 16; off <<= 1) {
      int u = __shfl_up(wsum, off, 64);
      if (ln >= off) wsum += u;
    }
    if (ln < 16) ws[ln] = wsum;
  }
  __syncthreads();
  int woff = (wv > 0) ? ws[wv - 1] : 0;
  int incl = s + woff;
  if (i < NN) loc[i] = incl - v;
  if (t == 1023) bsum[b] = incl;
}
// k_scan2: single wave scans NBLK block sums -> exclusive offsets
__global__ __launch_bounds__(64) void k_scan2(const int* __restrict__ bsum,
                                              int* __restrict__ boff)
{
  const int ln = threadIdx.x;
  int v = (ln < NBLK) ? bsum[ln] : 0;
  int s = v;
  #pragma unroll
  for (int off = 1; off < 64; off <<= 1) {
    int u = __shfl_up(s, off, 64);
    if (ln >= off) s += u;
  }
  if (ln < NBLK) boff[ln] = s - v;
}
// k_scan3: cur[i] = loc[i] + boff[block]
__global__ __launch_bounds__(256) void k_scan3(const int* __restrict__ loc,
                                               const int* __restrict__ boff,
                                               int* __restrict__ cur)
{
  int i = blockIdx.x * 256 + threadIdx.x;
  if (i < NN) cur[i] = loc[i] + boff[i >> 10];
}

// ---------------- CSR fill: CSR-ordered dst, src, edge_attr ----------------
__global__ __launch_bounds__(256) void k_fill(
    const int* __restrict__ src, const int* __restrict__ dst,
    const short* __restrict__ eab, int* __restrict__ cur,
    int* __restrict__ dstc, int* __restrict__ srcc, short* __restrict__ eac)
{
  int e = blockIdx.x * 256 + threadIdx.x;
  if (e < 128) { dstc[NE + e] = 0; srcc[NE + e] = 0; }
  if (e < NE) {
    int d = dst[e];
    int s = atomicAdd(&cur[d], 1);
    dstc[s] = d;
    srcc[s] = src[e];
    *(bf8_t*)(eac + (size_t)s * 8) = *(const bf8_t*)(eab + (size_t)e * 8);
  }
}

// ---------------- k_y1: per-node dual projection (also used for pred) -------
__global__ __launch_bounds__(256, 4) void k_y1(
    const short* __restrict__ xb, const short* __restrict__ w1f_l,
    const float* __restrict__ b1,
    short* __restrict__ y1s, short* __restrict__ y1d)
{
  const int t = threadIdx.x;
  const int wv = t >> 6, l = t & 63;
  const int m16 = l & 15, g = l >> 4;
  const int nb = blockIdx.x * 64 + wv * 16;
  if (nb >= NN) return;
  int row = nb + m16; if (row >= NN) row = NN - 1;
  const short* xr = xb + (size_t)row * 64;
  bf8_t a0 = *(const bf8_t*)(xr + g * 8);
  bf8_t a1 = *(const bf8_t*)(xr + 32 + g * 8);
  const short* wl = w1f_l + l * 8;

  f4_t accS[8], accD[8];
  #pragma unroll
  for (int nt = 0; nt < 8; ++nt) {
    float bv = b1[nt * 16 + m16];
    accS[nt] = (f4_t){0.f, 0.f, 0.f, 0.f};
    accD[nt] = (f4_t){bv, bv, bv, bv};
  }
  #pragma unroll
  for (int nt = 0; nt < 8; ++nt) {
    bf8_t b0 = *(const bf8_t*)(wl + (0 * 8 + nt) * 512);
    bf8_t b1f = *(const bf8_t*)(wl + (1 * 8 + nt) * 512);
    bf8_t b2f = *(const bf8_t*)(wl + (2 * 8 + nt) * 512);
    bf8_t b3f = *(const bf8_t*)(wl + (3 * 8 + nt) * 512);
    accS[nt] = MFMA16(a0, b0, accS[nt]);
    accS[nt] = MFMA16(a1, b1f, accS[nt]);
    accD[nt] = MFMA16(a0, b2f, accD[nt]);
    accD[nt] = MFMA16(a1, b3f, accD[nt]);
  }
  #pragma unroll
  for (int nt = 0; nt < 8; ++nt) {
    #pragma unroll
    for (int r = 0; r < 4; ++r) {
      int n = nb + g * 4 + r;
      if (n < NN) {
        y1s[(size_t)n * 128 + nt * 16 + m16] = f2bf(accS[nt][r]);
        y1d[(size_t)n * 128 + nt * 16 + m16] = f2bf(accD[nt][r]);
      }
    }
  }
}

// ---------------- k_msg_h: streaming edge h + run-compressed atomic agg -----
__global__ __launch_bounds__(256, 4) void k_msg_h(
    const short* __restrict__ y1s, const short* __restrict__ y1d,
    const short* __restrict__ eac,
    const int* __restrict__ srcc, const int* __restrict__ dstc,
    const float* __restrict__ W1l,
    float* __restrict__ hagg)
{
  const int t = threadIdx.x;
  const int wv = t >> 6, ln = t & 63;
  const int p0 = blockIdx.x * 64 + wv * 16;
  if (p0 >= NE) return;

  float we[8][2];
  #pragma unroll
  for (int f = 0; f < 8; ++f) {
    we[f][0] = W1l[(128 + f) * 128 + 2 * ln];
    we[f][1] = W1l[(128 + f) * 128 + 2 * ln + 1];
  }
  const int li = ln & 15;
  int srcv = srcc[p0 + li];
  int dstv = dstc[p0 + li];
  unsigned eaw = ((const unsigned*)eac)[(size_t)(p0 + (ln >> 2)) * 4 + (ln & 3)];

  unsigned ys[16], yd[16];
  #pragma unroll
  for (int i = 0; i < 16; ++i) {
    int s = __shfl(srcv, i, 64);
    int d = __shfl(dstv, i, 64);
    ys[i] = *(const unsigned*)(y1s + (size_t)s * 128 + 2 * ln);
    yd[i] = *(const unsigned*)(y1d + (size_t)d * 128 + 2 * ln);
  }

  float s0 = 0.f, s1 = 0.f;
  int cur = -1;
  #pragma unroll
  for (int i = 0; i < 16; ++i) {
    if (p0 + i >= NE) break;
    int d = __shfl(dstv, i, 64);
    if (d != cur) {
      if (cur >= 0) {
        atomicAdd(&hagg[(size_t)cur * 128 + 2 * ln], s0);
        atomicAdd(&hagg[(size_t)cur * 128 + 2 * ln + 1], s1);
      }
      cur = d; s0 = 0.f; s1 = 0.f;
    }
    float z0 = 0.f, z1 = 0.f;
    #pragma unroll
    for (int w = 0; w < 4; ++w) {
      unsigned u = __shfl(eaw, 4 * i + w, 64);
      float e0 = bf_lo(u), e1 = bf_hi(u);
      z0 += e0 * we[2 * w][0] + e1 * we[2 * w + 1][0];
      z1 += e0 * we[2 * w][1] + e1 * we[2 * w + 1][1];
    }
    float h0 = fmaxf(bf_lo(ys[i]) + bf_lo(yd[i]) + z0, 0.f);
    float h1 = fmaxf(bf_hi(ys[i]) + bf_hi(yd[i]) + z1, 0.f);
    s0 += h0; s1 += h1;
  }
  if (cur >= 0) {
    atomicAdd(&hagg[(size_t)cur * 128 + 2 * ln], s0);
    atomicAdd(&hagg[(size_t)cur * 128 + 2 * ln + 1], s1);
  }
}

// ---------------- k_node: fused agg@W2 + update-MLP + residual + LN ---------
__global__ __launch_bounds__(256, 4) void k_node(
    float* __restrict__ x, short* __restrict__ xb,
    const float* __restrict__ hagg, const int* __restrict__ cnt,
    const short* __restrict__ w2f_l, const float* __restrict__ b2,
    const short* __restrict__ wuf_l, const float* __restrict__ bu,
    const float* __restrict__ lng, const float* __restrict__ lnb)
{
  __shared__ short sH[4 * 16 * 136];   // 17.4 KB
  const int t = threadIdx.x;
  const int wv = t >> 6, l = t & 63;
  const int m16 = l & 15, g = l >> 4;
  const int nb = blockIdx.x * 64 + wv * 16;
  if (nb >= NN) return;
  int row = nb + m16; if (row >= NN) row = NN - 1;

  const float* hr = hagg + (size_t)row * 128;
  bf8_t a2[4];
  #pragma unroll
  for (int ks = 0; ks < 4; ++ks) {
    float4 q0 = *(const float4*)(hr + ks * 32 + g * 8);
    float4 q1 = *(const float4*)(hr + ks * 32 + g * 8 + 4);
    bf8_t av = {f2bf(q0.x), f2bf(q0.y), f2bf(q0.z), f2bf(q0.w),
                f2bf(q1.x), f2bf(q1.y), f2bf(q1.z), f2bf(q1.w)};
    a2[ks] = av;
  }
  float dg[4], iv[4];
  #pragma unroll
  for (int r = 0; r < 4; ++r) {
    int n = nb + g * 4 + r;
    int c = (n < NN) ? cnt[n] : 0;
    dg[r] = (float)c;
    iv[r] = 1.f / ((float)c + 1e-6f);
  }

  const short* w2l = w2f_l + l * 8;
  f4_t aacc[8];
  #pragma unroll
  for (int nt = 0; nt < 8; ++nt) {
    float bv = b2[nt * 16 + m16];
    aacc[nt] = (f4_t){dg[0] * bv, dg[1] * bv, dg[2] * bv, dg[3] * bv};
  }
  #pragma unroll
  for (int ks = 0; ks < 4; ++ks) {
    #pragma unroll
    for (int nt = 0; nt < 8; ++nt) {
      bf8_t bf = *(const bf8_t*)(w2l + (ks * 8 + nt) * 512);
      aacc[nt] = MFMA16(a2[ks], bf, aacc[nt]);
    }
  }

  short* sh = sH + wv * (16 * 136);
  #pragma unroll
  for (int nt = 0; nt < 8; ++nt) {
    #pragma unroll
    for (int r = 0; r < 4; ++r) {
      sh[(g * 4 + r) * 136 + nt * 16 + m16] = f2bf(aacc[nt][r] * iv[r]);
    }
  }

  const short* xr = xb + (size_t)row * 64;
  bf8_t a0 = *(const bf8_t*)(xr + g * 8);
  bf8_t a1 = *(const bf8_t*)(xr + 32 + g * 8);
  const short* wul = wuf_l + l * 8;
  f4_t acc[4];
  #pragma unroll
  for (int nt = 0; nt < 4; ++nt) {
    float bv = bu[nt * 16 + m16];
    acc[nt] = (f4_t){bv, bv, bv, bv};
  }
  #pragma unroll
  for (int nt = 0; nt < 4; ++nt) {
    acc[nt] = MFMA16(a0, *(const bf8_t*)(wul + (0 * 4 + nt) * 512), acc[nt]);
    acc[nt] = MFMA16(a1, *(const bf8_t*)(wul + (1 * 4 + nt) * 512), acc[nt]);
  }
  #pragma unroll
  for (int ks = 0; ks < 4; ++ks) {
    bf8_t af = *(const bf8_t*)(sh + m16 * 136 + ks * 32 + g * 8);
    #pragma unroll
    for (int nt = 0; nt < 4; ++nt) {
      acc[nt] = MFMA16(af, *(const bf8_t*)(wul + ((2 + ks) * 4 + nt) * 512), acc[nt]);
    }
  }

  float ov[4][4];
  #pragma unroll
  for (int nt = 0; nt < 4; ++nt) {
    #pragma unroll
    for (int r = 0; r < 4; ++r) {
      int n = nb + g * 4 + r;
      float xv = (n < NN) ? x[(size_t)n * 64 + nt * 16 + m16] : 0.f;
      ov[nt][r] = xv + fmaxf(acc[nt][r], 0.f);
    }
  }
  #pragma unroll
  for (int r = 0; r < 4; ++r) {
    float s1 = ov[0][r] + ov[1][r] + ov[2][r] + ov[3][r];
    float s2 = ov[0][r] * ov[0][r] + ov[1][r] * ov[1][r] +
               ov[2][r] * ov[2][r] + ov[3][r] * ov[3][r];
    #pragma unroll
    for (int off = 1; off < 16; off <<= 1) {
      s1 += __shfl_xor(s1, off, 64);
      s2 += __shfl_xor(s2, off, 64);
    }
    float mu = s1 * 0.015625f;
    float var = s2 * 0.015625f - mu * mu;
    float rs = rsqrtf(var + 1e-5f);
    int n = nb + g * 4 + r;
    if (n < NN) {
      #pragma unroll
      for (int nt = 0; nt < 4; ++nt) {
        int col = nt * 16 + m16;
        float y = (ov[nt][r] - mu) * rs * lng[col] + lnb[col];
        x[(size_t)n * 64 + col] = y;
        xb[(size_t)n * 64 + col] = f2bf(y);
      }
    }
  }
}

// ---------------- k_pred2: edge predictor via linear split ------------------
__global__ __launch_bounds__(256, 4) void k_pred2(
    const short* __restrict__ py1s, const short* __restrict__ py1d,
    const short* __restrict__ eab,
    const int* __restrict__ src, const int* __restrict__ dst,
    const float* __restrict__ pW1,
    const short* __restrict__ pw2f, const float* __restrict__ b2,
    const float* __restrict__ W3, const float* __restrict__ b3,
    float* __restrict__ out)
{
  __shared__ short sH[4 * 16 * 136];   // 17.4 KB
  const int t = threadIdx.x;
  const int wv = t >> 6, ln = t & 63;
  const int m16 = ln & 15, g = ln >> 4;
  const int p0 = blockIdx.x * 64 + wv * 16;
  if (p0 >= NE) return;

  float we[8][2];
  #pragma unroll
  for (int f = 0; f < 8; ++f) {
    we[f][0] = pW1[(128 + f) * 128 + 2 * ln];
    we[f][1] = pW1[(128 + f) * 128 + 2 * ln + 1];
  }
  const int li = ln & 15;
  int ei0 = p0 + li; if (ei0 >= NE) ei0 = NE - 1;
  int srcv = src[ei0];
  int dstv = dst[ei0];
  int ee = p0 + (ln >> 2); if (ee >= NE) ee = NE - 1;
  unsigned eaw = ((const unsigned*)eab)[(size_t)ee * 4 + (ln & 3)];

  unsigned ys[16], yd[16];
  #pragma unroll
  for (int i = 0; i < 16; ++i) {
    int s = __shfl(srcv, i, 64);
    int d = __shfl(dstv, i, 64);
    ys[i] = *(const unsigned*)(py1s + (size_t)s * 128 + 2 * ln);
    yd[i] = *(const unsigned*)(py1d + (size_t)d * 128 + 2 * ln);
  }

  short* sh = sH + wv * (16 * 136);
  #pragma unroll
  for (int i = 0; i < 16; ++i) {
    float z0 = 0.f, z1 = 0.f;
    #pragma unroll
    for (int w = 0; w < 4; ++w) {
      unsigned u = __shfl(eaw, 4 * i + w, 64);
      float e0 = bf_lo(u), e1 = bf_hi(u);
      z0 += e0 * we[2 * w][0] + e1 * we[2 * w + 1][0];
      z1 += e0 * we[2 * w][1] + e1 * we[2 * w + 1][1];
    }
    float h0 = fmaxf(bf_lo(ys[i]) + bf_lo(yd[i]) + z0, 0.f);
    float h1 = fmaxf(bf_hi(ys[i]) + bf_hi(yd[i]) + z1, 0.f);
    unsigned hv = (unsigned)(unsigned short)f2bf(h0) |
                  ((unsigned)(unsigned short)f2bf(h1) << 16);
    *(unsigned*)(sh + i * 136 + 2 * ln) = hv;
  }

  f4_t acc2[4];
  #pragma unroll
  for (int nt = 0; nt < 4; ++nt) {
    float bv = b2[nt * 16 + m16];
    acc2[nt] = (f4_t){bv, bv, bv, bv};
  }
  const short* w2l = pw2f + ln * 8;
  #pragma unroll
  for (int ks = 0; ks < 4; ++ks) {
    bf8_t af = *(const bf8_t*)(sh + m16 * 136 + ks * 32 + g * 8);
    #pragma unroll
    for (int nt = 0; nt < 4; ++nt) {
      bf8_t bf = *(const bf8_t*)(w2l + (ks * 4 + nt) * 512);
      acc2[nt] = MFMA16(af, bf, acc2[nt]);
    }
  }

  float w3v[4];
  #pragma unroll
  for (int nt = 0; nt < 4; ++nt) w3v[nt] = W3[nt * 16 + m16];
  const float b3v = b3[0];
  #pragma unroll
  for (int r = 0; r < 4; ++r) {
    float v = fmaxf(acc2[0][r], 0.f) * w3v[0] + fmaxf(acc2[1][r], 0.f) * w3v[1] +
              fmaxf(acc2[2][r], 0.f) * w3v[2] + fmaxf(acc2[3][r], 0.f) * w3v[3];
    #pragma unroll
    for (int off = 1; off < 16; off <<= 1) v += __shfl_xor(v, off, 64);
    int e = p0 + g * 4 + r;
    if (m16 == 0 && e < NE) out[e] = tanhf(v + b3v);
  }
}

extern "C" void kernel_launch(void* const* d_in, const int* in_sizes, int n_in,
                              void* d_out, int out_size, void* d_ws, size_t ws_size,
                              hipStream_t stream)
{
  (void)in_sizes; (void)n_in; (void)out_size; (void)ws_size;
  const float* nf  = (const float*)d_in[0];
  const float* ea  = (const float*)d_in[1];
  const float* eW  = (const float*)d_in[2];
  const float* eb  = (const float*)d_in[3];
  const float* mW1 = (const float*)d_in[4];
  const float* mb1 = (const float*)d_in[5];
  const float* mW2 = (const float*)d_in[6];
  const float* mb2 = (const float*)d_in[7];
  const float* uW  = (const float*)d_in[8];
  const float* ub  = (const float*)d_in[9];
  const float* lg  = (const float*)d_in[10];
  const float* lb  = (const float*)d_in[11];
  const float* pW1 = (const float*)d_in[12];
  const float* pb1 = (const float*)d_in[13];
  const float* pW2 = (const float*)d_in[14];
  const float* pb2 = (const float*)d_in[15];
  const float* pW3 = (const float*)d_in[16];
  const float* pb3 = (const float*)d_in[17];
  const int*   ei  = (const int*)d_in[18];
  const int* srcI = ei;
  const int* dstI = ei + NE;
  float* out = (float*)d_out;

  // workspace (~91 MB)
  char* w = (char*)d_ws;
  float* x    = (float*)w;  w += (size_t)NN * 64 * 4;
  float* hagg = (float*)w;  w += (size_t)NN * 128 * 4;
  short* xb   = (short*)w;  w += (size_t)NN * 64 * 2;
  short* eab  = (short*)w;  w += (size_t)NE * 8 * 2;
  short* eac  = (short*)w;  w += (size_t)(NE + 128) * 8 * 2;
  short* y1s  = (short*)w;  w += (size_t)NN * 128 * 2;
  short* y1d  = (short*)w;  w += (size_t)NN * 128 * 2;
  short* w1f  = (short*)w;  w += (size_t)3 * 20480 * 2;
  short* w2f  = (short*)w;  w += (size_t)3 * 16384 * 2;
  short* wuf  = (short*)w;  w += (size_t)3 * 12288 * 2;
  short* pw1f = (short*)w;  w += (size_t)20480 * 2;
  short* pw2f = (short*)w;  w += (size_t)8192 * 2;
  int*   cnt  = (int*)w;    w += (size_t)NN * 4;
  int*   loc  = (int*)w;    w += (size_t)NN * 4;
  int*   cur  = (int*)w;    w += (size_t)NN * 4;
  int*   bsum = (int*)w;    w += (size_t)64 * 4;
  int*   boff = (int*)w;    w += (size_t)64 * 4;
  int*   dstc = (int*)w;    w += (size_t)(NE + 128) * 4;
  int*   srcc = (int*)w;    w += (size_t)(NE + 128) * 4;

  k_zero_i<<<64, 256, 0, stream>>>(cnt, NN);
  k_embed<<<(NN * 16 + 255) / 256, 256, 0, stream>>>(nf, eW, eb, x, xb);
  k_hist<<<(NE + 255) / 256, 256, 0, stream>>>(dstI, cnt);
  k_scan1<<<NBLK, 1024, 0, stream>>>(cnt, loc, bsum);
  k_scan2<<<1, 64, 0, stream>>>(bsum, boff);
  k_scan3<<<(NN + 255) / 256, 256, 0, stream>>>(loc, boff, cur);
  k_prep_ea<<<(NE * 2 + 255) / 256, 256, 0, stream>>>(ea, eab);
  k_fill<<<(NE + 255) / 256, 256, 0, stream>>>(srcI, dstI, eab, cur, dstc, srcc, eac);
  k_prep_w1<<<240, 256, 0, stream>>>(mW1, w1f);
  k_prep_w2<<<192, 256, 0, stream>>>(mW2, w2f);
  k_prep_wu<<<144, 256, 0, stream>>>(uW, wuf);
  k_prep_pw1<<<80, 256, 0, stream>>>(pW1, pw1f);
  k_prep_pw2<<<32, 256, 0, stream>>>(pW2, pw2f);

  const int ngrid = (NN + 63) / 64;
  const int egrid = (NE + 63) / 64;
  for (int l = 0; l < 3; ++l) {
    k_zero_f4<<<1024, 256, 0, stream>>>((float4*)hagg, NN * 128 / 4);
    k_y1<<<ngrid, 256, 0, stream>>>(xb, w1f + (size_t)l * 20480,
        mb1 + (size_t)l * 128, y1s, y1d);
    k_msg_h<<<egrid, 256, 0, stream>>>(y1s, y1d, eac, srcc, dstc,
        mW1 + (size_t)l * 136 * 128, hagg);
    k_node<<<ngrid, 256, 0, stream>>>(x, xb, hagg, cnt,
        w2f + (size_t)l * 16384, mb2 + (size_t)l * 128,
        wuf + (size_t)l * 12288, ub + (size_t)l * 64,
        lg + (size_t)l * 64, lb + (size_t)l * 64);
  }
  k_y1<<<ngrid, 256, 0, stream>>>(xb, pw1f, pb1, y1s, y1d);
  k_pred2<<<egrid, 256, 0, stream>>>(y1s, y1d, eab, srcI, dstI,
      pW1, pw2f, pb2, pW3, pb3, out);
}

// Round 10
// 537.814 us; speedup vs baseline: 8.1564x; 1.0904x over previous
//
#include <hip/hip_runtime.h>

#define NN 50000
#define NE 500000
#define NBLK ((NN + 1023) / 1024)   // 49 scan blocks

typedef __attribute__((ext_vector_type(8))) short bf8_t;   // 8 x bf16
typedef __attribute__((ext_vector_type(4))) float f4_t;    // MFMA acc
#define MFMA16(a, b, c) __builtin_amdgcn_mfma_f32_16x16x32_bf16(a, b, c, 0, 0, 0)

__device__ __forceinline__ short f2bf(float f) {
  unsigned u = __float_as_uint(f);
  u += 0x7fffu + ((u >> 16) & 1u);   // RNE
  return (short)(u >> 16);
}
__device__ __forceinline__ float bf_lo(unsigned u) { return __uint_as_float(u << 16); }
__device__ __forceinline__ float bf_hi(unsigned u) { return __uint_as_float(u & 0xffff0000u); }
__device__ __forceinline__ float bf2f(short s) {
  return __uint_as_float(((unsigned)(unsigned short)s) << 16);
}

// ---------------- zero helpers ----------------
__global__ __launch_bounds__(256) void k_zero_i(int* __restrict__ p, int n)
{
  for (int i = blockIdx.x * 256 + threadIdx.x; i < n; i += gridDim.x * 256)
    p[i] = 0;
}

// ---------------- weight prep: fragment-contiguous bf16 layouts -------------
__global__ __launch_bounds__(256) void k_prep_w1(const float* __restrict__ W1,
                                                 short* __restrict__ w1f)
{
  int idx = blockIdx.x * 256 + threadIdx.x;
  if (idx >= 3 * 5 * 8 * 64 * 8) return;
  int l = idx / 20480;
  int rem = idx - l * 20480;
  int ks = rem / 4096;
  int nt = (rem >> 9) & 7;
  int lane = (rem >> 3) & 63;
  int j = rem & 7;
  int k = ks * 32 + (lane >> 4) * 8 + j;
  int n = nt * 16 + (lane & 15);
  float v = (k < 136) ? W1[(size_t)l * 136 * 128 + (size_t)k * 128 + n] : 0.f;
  w1f[idx] = f2bf(v);
}
__global__ __launch_bounds__(256) void k_prep_w2(const float* __restrict__ W2,
                                                 short* __restrict__ w2f)
{
  int idx = blockIdx.x * 256 + threadIdx.x;
  if (idx >= 3 * 4 * 8 * 64 * 8) return;
  int l = idx / 16384;
  int rem = idx - l * 16384;
  int ks = rem / 4096;
  int nt = (rem >> 9) & 7;
  int lane = (rem >> 3) & 63;
  int j = rem & 7;
  int k = ks * 32 + (lane >> 4) * 8 + j;
  int n = nt * 16 + (lane & 15);
  w2f[idx] = f2bf(W2[(size_t)l * 128 * 128 + (size_t)k * 128 + n]);
}
__global__ __launch_bounds__(256) void k_prep_wu(const float* __restrict__ Wu,
                                                 short* __restrict__ wuf)
{
  int idx = blockIdx.x * 256 + threadIdx.x;
  if (idx >= 3 * 6 * 4 * 64 * 8) return;
  int l = idx / 12288;
  int rem = idx - l * 12288;
  int ks = rem / 2048;
  int nt = (rem >> 9) & 3;
  int lane = (rem >> 3) & 63;
  int j = rem & 7;
  int k = ks * 32 + (lane >> 4) * 8 + j;
  int n = nt * 16 + (lane & 15);
  wuf[idx] = f2bf(Wu[(size_t)l * 192 * 64 + (size_t)k * 64 + n]);
}
__global__ __launch_bounds__(256) void k_prep_pw1(const float* __restrict__ W1,
                                                  short* __restrict__ wf)
{
  int idx = blockIdx.x * 256 + threadIdx.x;
  if (idx >= 5 * 8 * 64 * 8) return;
  int ks = idx / 4096;
  int nt = (idx >> 9) & 7;
  int lane = (idx >> 3) & 63;
  int j = idx & 7;
  int k = ks * 32 + (lane >> 4) * 8 + j;
  int n = nt * 16 + (lane & 15);
  float v = (k < 136) ? W1[(size_t)k * 128 + n] : 0.f;
  wf[idx] = f2bf(v);
}
__global__ __launch_bounds__(256) void k_prep_pw2(const float* __restrict__ W2,
                                                  short* __restrict__ wf)
{
  int idx = blockIdx.x * 256 + threadIdx.x;
  if (idx >= 4 * 4 * 64 * 8) return;
  int ks = idx / 2048;
  int nt = (idx >> 9) & 3;
  int lane = (idx >> 3) & 63;
  int j = idx & 7;
  int k = ks * 32 + (lane >> 4) * 8 + j;
  int n = nt * 16 + (lane & 15);
  wf[idx] = f2bf(W2[(size_t)k * 64 + n]);
}
__global__ __launch_bounds__(256) void k_prep_ea(const float* __restrict__ ea,
                                                 short* __restrict__ eab)
{
  int i = blockIdx.x * 256 + threadIdx.x;
  if (i >= NE * 2) return;
  float4 v = *(const float4*)&ea[(size_t)i * 4];
  short4 o;
  o.x = f2bf(v.x); o.y = f2bf(v.y); o.z = f2bf(v.z); o.w = f2bf(v.w);
  *(short4*)&eab[(size_t)i * 4] = o;
}

// ---------------- embed: x = relu(nf @ We + be) ----------------
__global__ __launch_bounds__(256) void k_embed(
    const float* __restrict__ nf, const float* __restrict__ We,
    const float* __restrict__ be, float* __restrict__ x, short* __restrict__ xb)
{
  int idx = blockIdx.x * 256 + threadIdx.x;
  int n = idx >> 4, g = idx & 15;
  if (n >= NN) return;
  int j0 = g * 4;
  float4 b4 = *(const float4*)&be[j0];
  float a0 = b4.x, a1 = b4.y, a2 = b4.z, a3 = b4.w;
  #pragma unroll
  for (int k = 0; k < 7; ++k) {
    float v = nf[n * 7 + k];
    float4 w = *(const float4*)&We[k * 64 + j0];
    a0 += v * w.x; a1 += v * w.y; a2 += v * w.z; a3 += v * w.w;
  }
  a0 = fmaxf(a0, 0.f); a1 = fmaxf(a1, 0.f); a2 = fmaxf(a2, 0.f); a3 = fmaxf(a3, 0.f);
  *(float4*)&x[(size_t)n * 64 + j0] = make_float4(a0, a1, a2, a3);
  short4 o; o.x = f2bf(a0); o.y = f2bf(a1); o.z = f2bf(a2); o.w = f2bf(a3);
  *(short4*)&xb[(size_t)n * 64 + j0] = o;
}

// ---------------- degree histogram ----------------
__global__ __launch_bounds__(256) void k_hist(const int* __restrict__ dst, int* __restrict__ cnt)
{
  int e = blockIdx.x * 256 + threadIdx.x;
  if (e < NE) atomicAdd(&cnt[dst[e]], 1);
}

// ---------------- parallel exclusive scan (3 kernels) ----------------
__global__ __launch_bounds__(1024) void k_scan1(const int* __restrict__ cnt,
                                                int* __restrict__ loc, int* __restrict__ bsum)
{
  __shared__ int ws[16];
  const int b = blockIdx.x, t = threadIdx.x;
  const int i = b * 1024 + t;
  const int ln = t & 63, wv = t >> 6;
  int v = (i < NN) ? cnt[i] : 0;
  int s = v;
  #pragma unroll
  for (int off = 1; off < 64; off <<= 1) {
    int u = __shfl_up(s, off, 64);
    if (ln >= off) s += u;
  }
  if (ln == 63) ws[wv] = s;
  __syncthreads();
  if (wv == 0) {
    int wsum = (ln < 16) ? ws[ln] : 0;
    #pragma unroll
    for (int off = 1; off < 16; off <<= 1) {
      int u = __shfl_up(wsum, off, 64);
      if (ln >= off) wsum += u;
    }
    if (ln < 16) ws[ln] = wsum;
  }
  __syncthreads();
  int woff = (wv > 0) ? ws[wv - 1] : 0;
  int incl = s + woff;
  if (i < NN) loc[i] = incl - v;
  if (t == 1023) bsum[b] = incl;
}
__global__ __launch_bounds__(64) void k_scan2(const int* __restrict__ bsum,
                                              int* __restrict__ boff)
{
  const int ln = threadIdx.x;
  int v = (ln < NBLK) ? bsum[ln] : 0;
  int s = v;
  #pragma unroll
  for (int off = 1; off < 64; off <<= 1) {
    int u = __shfl_up(s, off, 64);
    if (ln >= off) s += u;
  }
  if (ln < NBLK) boff[ln] = s - v;
}
// writes BOTH the immutable start-offset array (ptr) and the mutable cursor (cur)
__global__ __launch_bounds__(256) void k_scan3(const int* __restrict__ loc,
                                               const int* __restrict__ boff,
                                               int* __restrict__ ptr,
                                               int* __restrict__ cur)
{
  int i = blockIdx.x * 256 + threadIdx.x;
  if (i < NN) {
    int v = loc[i] + boff[i >> 10];
    ptr[i] = v;
    cur[i] = v;
  }
}

// ---------------- CSR fill: CSR-ordered src, edge_attr ----------------
__global__ __launch_bounds__(256) void k_fill(
    const int* __restrict__ src, const int* __restrict__ dst,
    const short* __restrict__ eab, int* __restrict__ cur,
    int* __restrict__ srcc, short* __restrict__ eac)
{
  int e = blockIdx.x * 256 + threadIdx.x;
  if (e < 128) srcc[NE + e] = 0;
  if (e < NE) {
    int d = dst[e];
    int s = atomicAdd(&cur[d], 1);
    srcc[s] = src[e];
    *(bf8_t*)(eac + (size_t)s * 8) = *(const bf8_t*)(eab + (size_t)e * 8);
  }
}

// ---------------- k_y1: per-node dual projection (also used for pred) -------
__global__ __launch_bounds__(256, 4) void k_y1(
    const short* __restrict__ xb, const short* __restrict__ w1f_l,
    const float* __restrict__ b1,
    short* __restrict__ y1s, short* __restrict__ y1d)
{
  const int t = threadIdx.x;
  const int wv = t >> 6, l = t & 63;
  const int m16 = l & 15, g = l >> 4;
  const int nb = blockIdx.x * 64 + wv * 16;
  if (nb >= NN) return;
  int row = nb + m16; if (row >= NN) row = NN - 1;
  const short* xr = xb + (size_t)row * 64;
  bf8_t a0 = *(const bf8_t*)(xr + g * 8);
  bf8_t a1 = *(const bf8_t*)(xr + 32 + g * 8);
  const short* wl = w1f_l + l * 8;

  f4_t accS[8], accD[8];
  #pragma unroll
  for (int nt = 0; nt < 8; ++nt) {
    float bv = b1[nt * 16 + m16];
    accS[nt] = (f4_t){0.f, 0.f, 0.f, 0.f};
    accD[nt] = (f4_t){bv, bv, bv, bv};
  }
  #pragma unroll
  for (int nt = 0; nt < 8; ++nt) {
    bf8_t b0 = *(const bf8_t*)(wl + (0 * 8 + nt) * 512);
    bf8_t b1f = *(const bf8_t*)(wl + (1 * 8 + nt) * 512);
    bf8_t b2f = *(const bf8_t*)(wl + (2 * 8 + nt) * 512);
    bf8_t b3f = *(const bf8_t*)(wl + (3 * 8 + nt) * 512);
    accS[nt] = MFMA16(a0, b0, accS[nt]);
    accS[nt] = MFMA16(a1, b1f, accS[nt]);
    accD[nt] = MFMA16(a0, b2f, accD[nt]);
    accD[nt] = MFMA16(a1, b3f, accD[nt]);
  }
  #pragma unroll
  for (int nt = 0; nt < 8; ++nt) {
    #pragma unroll
    for (int r = 0; r < 4; ++r) {
      int n = nb + g * 4 + r;
      if (n < NN) {
        y1s[(size_t)n * 128 + nt * 16 + m16] = f2bf(accS[nt][r]);
        y1d[(size_t)n * 128 + nt * 16 + m16] = f2bf(accD[nt][r]);
      }
    }
  }
}

// ---------------- k_msg_n: node-centric edge h + direct store ---------------
// Wave = one dst node n. Edges [ptr[n], ptr[n]+cnt[n]) are CSR-contiguous.
// h = relu(y1s[src] + y1d[n] + ea@W1e); hagg[n] = sum over edges (plain store).
// All control flow and index loads are wave-uniform; no shuffles.
__global__ __launch_bounds__(256, 4) void k_msg_n(
    const short* __restrict__ y1s, const short* __restrict__ y1d,
    const short* __restrict__ eac, const int* __restrict__ srcc,
    const int* __restrict__ ptr, const int* __restrict__ cnt,
    const float* __restrict__ W1l,
    float* __restrict__ hagg)
{
  const int t = threadIdx.x;
  const int wv = t >> 6, ln = t & 63;
  const int n = blockIdx.x * 4 + wv;
  if (n >= NN) return;

  // W1e columns for this lane's col pair (fp32, L2-hot)
  float we[8][2];
  #pragma unroll
  for (int f = 0; f < 8; ++f) {
    we[f][0] = W1l[(128 + f) * 128 + 2 * ln];
    we[f][1] = W1l[(128 + f) * 128 + 2 * ln + 1];
  }
  const int p0 = ptr[n];
  const int p1 = p0 + cnt[n];

  unsigned ydu = *(const unsigned*)(y1d + (size_t)n * 128 + 2 * ln);
  const float yd0 = bf_lo(ydu), yd1 = bf_hi(ydu);

  float s0 = 0.f, s1 = 0.f;
  for (int e = p0; e < p1; ++e) {
    int s = srcc[e];                                   // wave-uniform scalar load
    unsigned ysu = *(const unsigned*)(y1s + (size_t)s * 128 + 2 * ln);
    bf8_t eav = *(const bf8_t*)(eac + (size_t)e * 8);  // wave-uniform 16B load
    float z0 = 0.f, z1 = 0.f;
    #pragma unroll
    for (int f = 0; f < 8; ++f) {
      float ef = bf2f(eav[f]);
      z0 += ef * we[f][0];
      z1 += ef * we[f][1];
    }
    s0 += fmaxf(bf_lo(ysu) + yd0 + z0, 0.f);
    s1 += fmaxf(bf_hi(ysu) + yd1 + z1, 0.f);
  }
  *(float2*)(hagg + (size_t)n * 128 + 2 * ln) = make_float2(s0, s1);
}

// ---------------- k_node: fused agg@W2 + update-MLP + residual + LN ---------
__global__ __launch_bounds__(256, 4) void k_node(
    float* __restrict__ x, short* __restrict__ xb,
    const float* __restrict__ hagg, const int* __restrict__ cnt,
    const short* __restrict__ w2f_l, const float* __restrict__ b2,
    const short* __restrict__ wuf_l, const float* __restrict__ bu,
    const float* __restrict__ lng, const float* __restrict__ lnb)
{
  __shared__ short sH[4 * 16 * 136];   // 17.4 KB
  const int t = threadIdx.x;
  const int wv = t >> 6, l = t & 63;
  const int m16 = l & 15, g = l >> 4;
  const int nb = blockIdx.x * 64 + wv * 16;
  if (nb >= NN) return;
  int row = nb + m16; if (row >= NN) row = NN - 1;

  const float* hr = hagg + (size_t)row * 128;
  bf8_t a2[4];
  #pragma unroll
  for (int ks = 0; ks < 4; ++ks) {
    float4 q0 = *(const float4*)(hr + ks * 32 + g * 8);
    float4 q1 = *(const float4*)(hr + ks * 32 + g * 8 + 4);
    bf8_t av = {f2bf(q0.x), f2bf(q0.y), f2bf(q0.z), f2bf(q0.w),
                f2bf(q1.x), f2bf(q1.y), f2bf(q1.z), f2bf(q1.w)};
    a2[ks] = av;
  }
  float dg[4], iv[4];
  #pragma unroll
  for (int r = 0; r < 4; ++r) {
    int n = nb + g * 4 + r;
    int c = (n < NN) ? cnt[n] : 0;
    dg[r] = (float)c;
    iv[r] = 1.f / ((float)c + 1e-6f);
  }

  const short* w2l = w2f_l + l * 8;
  f4_t aacc[8];
  #pragma unroll
  for (int nt = 0; nt < 8; ++nt) {
    float bv = b2[nt * 16 + m16];
    aacc[nt] = (f4_t){dg[0] * bv, dg[1] * bv, dg[2] * bv, dg[3] * bv};
  }
  #pragma unroll
  for (int ks = 0; ks < 4; ++ks) {
    #pragma unroll
    for (int nt = 0; nt < 8; ++nt) {
      bf8_t bf = *(const bf8_t*)(w2l + (ks * 8 + nt) * 512);
      aacc[nt] = MFMA16(a2[ks], bf, aacc[nt]);
    }
  }

  short* sh = sH + wv * (16 * 136);
  #pragma unroll
  for (int nt = 0; nt < 8; ++nt) {
    #pragma unroll
    for (int r = 0; r < 4; ++r) {
      sh[(g * 4 + r) * 136 + nt * 16 + m16] = f2bf(aacc[nt][r] * iv[r]);
    }
  }

  const short* xr = xb + (size_t)row * 64;
  bf8_t a0 = *(const bf8_t*)(xr + g * 8);
  bf8_t a1 = *(const bf8_t*)(xr + 32 + g * 8);
  const short* wul = wuf_l + l * 8;
  f4_t acc[4];
  #pragma unroll
  for (int nt = 0; nt < 4; ++nt) {
    float bv = bu[nt * 16 + m16];
    acc[nt] = (f4_t){bv, bv, bv, bv};
  }
  #pragma unroll
  for (int nt = 0; nt < 4; ++nt) {
    acc[nt] = MFMA16(a0, *(const bf8_t*)(wul + (0 * 4 + nt) * 512), acc[nt]);
    acc[nt] = MFMA16(a1, *(const bf8_t*)(wul + (1 * 4 + nt) * 512), acc[nt]);
  }
  #pragma unroll
  for (int ks = 0; ks < 4; ++ks) {
    bf8_t af = *(const bf8_t*)(sh + m16 * 136 + ks * 32 + g * 8);
    #pragma unroll
    for (int nt = 0; nt < 4; ++nt) {
      acc[nt] = MFMA16(af, *(const bf8_t*)(wul + ((2 + ks) * 4 + nt) * 512), acc[nt]);
    }
  }

  float ov[4][4];
  #pragma unroll
  for (int nt = 0; nt < 4; ++nt) {
    #pragma unroll
    for (int r = 0; r < 4; ++r) {
      int n = nb + g * 4 + r;
      float xv = (n < NN) ? x[(size_t)n * 64 + nt * 16 + m16] : 0.f;
      ov[nt][r] = xv + fmaxf(acc[nt][r], 0.f);
    }
  }
  #pragma unroll
  for (int r = 0; r < 4; ++r) {
    float s1 = ov[0][r] + ov[1][r] + ov[2][r] + ov[3][r];
    float s2 = ov[0][r] * ov[0][r] + ov[1][r] * ov[1][r] +
               ov[2][r] * ov[2][r] + ov[3][r] * ov[3][r];
    #pragma unroll
    for (int off = 1; off < 16; off <<= 1) {
      s1 += __shfl_xor(s1, off, 64);
      s2 += __shfl_xor(s2, off, 64);
    }
    float mu = s1 * 0.015625f;
    float var = s2 * 0.015625f - mu * mu;
    float rs = rsqrtf(var + 1e-5f);
    int n = nb + g * 4 + r;
    if (n < NN) {
      #pragma unroll
      for (int nt = 0; nt < 4; ++nt) {
        int col = nt * 16 + m16;
        float y = (ov[nt][r] - mu) * rs * lng[col] + lnb[col];
        x[(size_t)n * 64 + col] = y;
        xb[(size_t)n * 64 + col] = f2bf(y);
      }
    }
  }
}

// ---------------- k_pred2: edge predictor via linear split ------------------
__global__ __launch_bounds__(256, 4) void k_pred2(
    const short* __restrict__ py1s, const short* __restrict__ py1d,
    const short* __restrict__ eab,
    const int* __restrict__ src, const int* __restrict__ dst,
    const float* __restrict__ pW1,
    const short* __restrict__ pw2f, const float* __restrict__ b2,
    const float* __restrict__ W3, const float* __restrict__ b3,
    float* __restrict__ out)
{
  __shared__ short sH[4 * 16 * 136];   // 17.4 KB
  const int t = threadIdx.x;
  const int wv = t >> 6, ln = t & 63;
  const int m16 = ln & 15, g = ln >> 4;
  const int p0 = blockIdx.x * 64 + wv * 16;
  if (p0 >= NE) return;

  float we[8][2];
  #pragma unroll
  for (int f = 0; f < 8; ++f) {
    we[f][0] = pW1[(128 + f) * 128 + 2 * ln];
    we[f][1] = pW1[(128 + f) * 128 + 2 * ln + 1];
  }
  const int li = ln & 15;
  int ei0 = p0 + li; if (ei0 >= NE) ei0 = NE - 1;
  int srcv = src[ei0];
  int dstv = dst[ei0];
  int ee = p0 + (ln >> 2); if (ee >= NE) ee = NE - 1;
  unsigned eaw = ((const unsigned*)eab)[(size_t)ee * 4 + (ln & 3)];

  unsigned ys[16], yd[16];
  #pragma unroll
  for (int i = 0; i < 16; ++i) {
    int s = __shfl(srcv, i, 64);
    int d = __shfl(dstv, i, 64);
    ys[i] = *(const unsigned*)(py1s + (size_t)s * 128 + 2 * ln);
    yd[i] = *(const unsigned*)(py1d + (size_t)d * 128 + 2 * ln);
  }

  short* sh = sH + wv * (16 * 136);
  #pragma unroll
  for (int i = 0; i < 16; ++i) {
    float z0 = 0.f, z1 = 0.f;
    #pragma unroll
    for (int w = 0; w < 4; ++w) {
      unsigned u = __shfl(eaw, 4 * i + w, 64);
      float e0 = bf_lo(u), e1 = bf_hi(u);
      z0 += e0 * we[2 * w][0] + e1 * we[2 * w + 1][0];
      z1 += e0 * we[2 * w][1] + e1 * we[2 * w + 1][1];
    }
    float h0 = fmaxf(bf_lo(ys[i]) + bf_lo(yd[i]) + z0, 0.f);
    float h1 = fmaxf(bf_hi(ys[i]) + bf_hi(yd[i]) + z1, 0.f);
    unsigned hv = (unsigned)(unsigned short)f2bf(h0) |
                  ((unsigned)(unsigned short)f2bf(h1) << 16);
    *(unsigned*)(sh + i * 136 + 2 * ln) = hv;
  }

  f4_t acc2[4];
  #pragma unroll
  for (int nt = 0; nt < 4; ++nt) {
    float bv = b2[nt * 16 + m16];
    acc2[nt] = (f4_t){bv, bv, bv, bv};
  }
  const short* w2l = pw2f + ln * 8;
  #pragma unroll
  for (int ks = 0; ks < 4; ++ks) {
    bf8_t af = *(const bf8_t*)(sh + m16 * 136 + ks * 32 + g * 8);
    #pragma unroll
    for (int nt = 0; nt < 4; ++nt) {
      bf8_t bf = *(const bf8_t*)(w2l + (ks * 4 + nt) * 512);
      acc2[nt] = MFMA16(af, bf, acc2[nt]);
    }
  }

  float w3v[4];
  #pragma unroll
  for (int nt = 0; nt < 4; ++nt) w3v[nt] = W3[nt * 16 + m16];
  const float b3v = b3[0];
  #pragma unroll
  for (int r = 0; r < 4; ++r) {
    float v = fmaxf(acc2[0][r], 0.f) * w3v[0] + fmaxf(acc2[1][r], 0.f) * w3v[1] +
              fmaxf(acc2[2][r], 0.f) * w3v[2] + fmaxf(acc2[3][r], 0.f) * w3v[3];
    #pragma unroll
    for (int off = 1; off < 16; off <<= 1) v += __shfl_xor(v, off, 64);
    int e = p0 + g * 4 + r;
    if (m16 == 0 && e < NE) out[e] = tanhf(v + b3v);
  }
}

extern "C" void kernel_launch(void* const* d_in, const int* in_sizes, int n_in,
                              void* d_out, int out_size, void* d_ws, size_t ws_size,
                              hipStream_t stream)
{
  (void)in_sizes; (void)n_in; (void)out_size; (void)ws_size;
  const float* nf  = (const float*)d_in[0];
  const float* ea  = (const float*)d_in[1];
  const float* eW  = (const float*)d_in[2];
  const float* eb  = (const float*)d_in[3];
  const float* mW1 = (const float*)d_in[4];
  const float* mb1 = (const float*)d_in[5];
  const float* mW2 = (const float*)d_in[6];
  const float* mb2 = (const float*)d_in[7];
  const float* uW  = (const float*)d_in[8];
  const float* ub  = (const float*)d_in[9];
  const float* lg  = (const float*)d_in[10];
  const float* lb  = (const float*)d_in[11];
  const float* pW1 = (const float*)d_in[12];
  const float* pb1 = (const float*)d_in[13];
  const float* pW2 = (const float*)d_in[14];
  const float* pb2 = (const float*)d_in[15];
  const float* pW3 = (const float*)d_in[16];
  const float* pb3 = (const float*)d_in[17];
  const int*   ei  = (const int*)d_in[18];
  const int* srcI = ei;
  const int* dstI = ei + NE;
  float* out = (float*)d_out;

  // workspace (~90 MB)
  char* w = (char*)d_ws;
  float* x    = (float*)w;  w += (size_t)NN * 64 * 4;
  float* hagg = (float*)w;  w += (size_t)NN * 128 * 4;
  short* xb   = (short*)w;  w += (size_t)NN * 64 * 2;
  short* eab  = (short*)w;  w += (size_t)NE * 8 * 2;
  short* eac  = (short*)w;  w += (size_t)(NE + 128) * 8 * 2;
  short* y1s  = (short*)w;  w += (size_t)NN * 128 * 2;
  short* y1d  = (short*)w;  w += (size_t)NN * 128 * 2;
  short* w1f  = (short*)w;  w += (size_t)3 * 20480 * 2;
  short* w2f  = (short*)w;  w += (size_t)3 * 16384 * 2;
  short* wuf  = (short*)w;  w += (size_t)3 * 12288 * 2;
  short* pw1f = (short*)w;  w += (size_t)20480 * 2;
  short* pw2f = (short*)w;  w += (size_t)8192 * 2;
  int*   cnt  = (int*)w;    w += (size_t)NN * 4;
  int*   loc  = (int*)w;    w += (size_t)NN * 4;
  int*   ptr  = (int*)w;    w += (size_t)NN * 4;
  int*   cur  = (int*)w;    w += (size_t)NN * 4;
  int*   bsum = (int*)w;    w += (size_t)64 * 4;
  int*   boff = (int*)w;    w += (size_t)64 * 4;
  int*   srcc = (int*)w;    w += (size_t)(NE + 128) * 4;

  k_zero_i<<<64, 256, 0, stream>>>(cnt, NN);
  k_embed<<<(NN * 16 + 255) / 256, 256, 0, stream>>>(nf, eW, eb, x, xb);
  k_hist<<<(NE + 255) / 256, 256, 0, stream>>>(dstI, cnt);
  k_scan1<<<NBLK, 1024, 0, stream>>>(cnt, loc, bsum);
  k_scan2<<<1, 64, 0, stream>>>(bsum, boff);
  k_scan3<<<(NN + 255) / 256, 256, 0, stream>>>(loc, boff, ptr, cur);
  k_prep_ea<<<(NE * 2 + 255) / 256, 256, 0, stream>>>(ea, eab);
  k_fill<<<(NE + 255) / 256, 256, 0, stream>>>(srcI, dstI, eab, cur, srcc, eac);
  k_prep_w1<<<240, 256, 0, stream>>>(mW1, w1f);
  k_prep_w2<<<192, 256, 0, stream>>>(mW2, w2f);
  k_prep_wu<<<144, 256, 0, stream>>>(uW, wuf);
  k_prep_pw1<<<80, 256, 0, stream>>>(pW1, pw1f);
  k_prep_pw2<<<32, 256, 0, stream>>>(pW2, pw2f);

  const int ngrid = (NN + 63) / 64;
  const int egrid = (NE + 63) / 64;
  const int mgrid = (NN + 3) / 4;
  for (int l = 0; l < 3; ++l) {
    k_y1<<<ngrid, 256, 0, stream>>>(xb, w1f + (size_t)l * 20480,
        mb1 + (size_t)l * 128, y1s, y1d);
    k_msg_n<<<mgrid, 256, 0, stream>>>(y1s, y1d, eac, srcc, ptr, cnt,
        mW1 + (size_t)l * 136 * 128, hagg);
    k_node<<<ngrid, 256, 0, stream>>>(x, xb, hagg, cnt,
        w2f + (size_t)l * 16384, mb2 + (size_t)l * 128,
        wuf + (size_t)l * 12288, ub + (size_t)l * 64,
        lg + (size_t)l * 64, lb + (size_t)l * 64);
  }
  k_y1<<<ngrid, 256, 0, stream>>>(xb, pw1f, pb1, y1s, y1d);
  k_pred2<<<egrid, 256, 0, stream>>>(y1s, y1d, eab, srcI, dstI,
      pW1, pw2f, pb2, pW3, pb3, out);
}

// Round 11
// 533.371 us; speedup vs baseline: 8.2243x; 1.0083x over previous
//
#include <hip/hip_runtime.h>

#define NN 50000
#define NE 500000
#define NBLK ((NN + 1023) / 1024)   // 49 scan blocks

typedef __attribute__((ext_vector_type(8))) short bf8_t;   // 8 x bf16
typedef __attribute__((ext_vector_type(4))) float f4_t;    // MFMA acc
#define MFMA16(a, b, c) __builtin_amdgcn_mfma_f32_16x16x32_bf16(a, b, c, 0, 0, 0)

__device__ __forceinline__ short f2bf(float f) {
  unsigned u = __float_as_uint(f);
  u += 0x7fffu + ((u >> 16) & 1u);   // RNE
  return (short)(u >> 16);
}
__device__ __forceinline__ float bf_lo(unsigned u) { return __uint_as_float(u << 16); }
__device__ __forceinline__ float bf_hi(unsigned u) { return __uint_as_float(u & 0xffff0000u); }

// ---------------- zero helper ----------------
__global__ __launch_bounds__(256) void k_zero_i(int* __restrict__ p, int n)
{
  for (int i = blockIdx.x * 256 + threadIdx.x; i < n; i += gridDim.x * 256)
    p[i] = 0;
}

// ---------------- merged weight prep: fragment-contiguous bf16 --------------
// ranges: [0,61440) w1f | [61440,110592) w2f | [110592,147456) wuf
//         [147456,167936) pw1f | [167936,176128) pw2f
__global__ __launch_bounds__(256) void k_prep_all(
    const float* __restrict__ mW1, const float* __restrict__ mW2,
    const float* __restrict__ uW,
    const float* __restrict__ pW1, const float* __restrict__ pW2,
    short* __restrict__ w1f, short* __restrict__ w2f, short* __restrict__ wuf,
    short* __restrict__ pw1f, short* __restrict__ pw2f)
{
  int idx = blockIdx.x * 256 + threadIdx.x;
  if (idx < 61440) {
    int l = idx / 20480;
    int rem = idx - l * 20480;
    int ks = rem / 4096;
    int nt = (rem >> 9) & 7;
    int lane = (rem >> 3) & 63;
    int j = rem & 7;
    int k = ks * 32 + (lane >> 4) * 8 + j;
    int n = nt * 16 + (lane & 15);
    float v = (k < 136) ? mW1[(size_t)l * 136 * 128 + (size_t)k * 128 + n] : 0.f;
    w1f[idx] = f2bf(v);
  } else if (idx < 110592) {
    int i2 = idx - 61440;
    int l = i2 / 16384;
    int rem = i2 - l * 16384;
    int ks = rem / 4096;
    int nt = (rem >> 9) & 7;
    int lane = (rem >> 3) & 63;
    int j = rem & 7;
    int k = ks * 32 + (lane >> 4) * 8 + j;
    int n = nt * 16 + (lane & 15);
    w2f[i2] = f2bf(mW2[(size_t)l * 128 * 128 + (size_t)k * 128 + n]);
  } else if (idx < 147456) {
    int i3 = idx - 110592;
    int l = i3 / 12288;
    int rem = i3 - l * 12288;
    int ks = rem / 2048;
    int nt = (rem >> 9) & 3;
    int lane = (rem >> 3) & 63;
    int j = rem & 7;
    int k = ks * 32 + (lane >> 4) * 8 + j;
    int n = nt * 16 + (lane & 15);
    wuf[i3] = f2bf(uW[(size_t)l * 192 * 64 + (size_t)k * 64 + n]);
  } else if (idx < 167936) {
    int i4 = idx - 147456;
    int ks = i4 / 4096;
    int nt = (i4 >> 9) & 7;
    int lane = (i4 >> 3) & 63;
    int j = i4 & 7;
    int k = ks * 32 + (lane >> 4) * 8 + j;
    int n = nt * 16 + (lane & 15);
    float v = (k < 136) ? pW1[(size_t)k * 128 + n] : 0.f;
    pw1f[i4] = f2bf(v);
  } else if (idx < 176128) {
    int i5 = idx - 167936;
    int ks = i5 / 2048;
    int nt = (i5 >> 9) & 3;
    int lane = (i5 >> 3) & 63;
    int j = i5 & 7;
    int k = ks * 32 + (lane >> 4) * 8 + j;
    int n = nt * 16 + (lane & 15);
    pw2f[i5] = f2bf(pW2[(size_t)k * 64 + n]);
  }
}

__global__ __launch_bounds__(256) void k_prep_ea(const float* __restrict__ ea,
                                                 short* __restrict__ eab)
{
  int i = blockIdx.x * 256 + threadIdx.x;
  if (i >= NE * 2) return;
  float4 v = *(const float4*)&ea[(size_t)i * 4];
  short4 o;
  o.x = f2bf(v.x); o.y = f2bf(v.y); o.z = f2bf(v.z); o.w = f2bf(v.w);
  *(short4*)&eab[(size_t)i * 4] = o;
}

// ---------------- degree histogram ----------------
__global__ __launch_bounds__(256) void k_hist(const int* __restrict__ dst, int* __restrict__ cnt)
{
  int e = blockIdx.x * 256 + threadIdx.x;
  if (e < NE) atomicAdd(&cnt[dst[e]], 1);
}

// ---------------- parallel exclusive scan (3 kernels) ----------------
__global__ __launch_bounds__(1024) void k_scan1(const int* __restrict__ cnt,
                                                int* __restrict__ loc, int* __restrict__ bsum)
{
  __shared__ int ws[16];
  const int b = blockIdx.x, t = threadIdx.x;
  const int i = b * 1024 + t;
  const int ln = t & 63, wv = t >> 6;
  int v = (i < NN) ? cnt[i] : 0;
  int s = v;
  #pragma unroll
  for (int off = 1; off < 64; off <<= 1) {
    int u = __shfl_up(s, off, 64);
    if (ln >= off) s += u;
  }
  if (ln == 63) ws[wv] = s;
  __syncthreads();
  if (wv == 0) {
    int wsum = (ln < 16) ? ws[ln] : 0;
    #pragma unroll
    for (int off = 1; off < 16; off <<= 1) {
      int u = __shfl_up(wsum, off, 64);
      if (ln >= off) wsum += u;
    }
    if (ln < 16) ws[ln] = wsum;
  }
  __syncthreads();
  int woff = (wv > 0) ? ws[wv - 1] : 0;
  int incl = s + woff;
  if (i < NN) loc[i] = incl - v;
  if (t == 1023) bsum[b] = incl;
}
__global__ __launch_bounds__(64) void k_scan2(const int* __restrict__ bsum,
                                              int* __restrict__ boff)
{
  const int ln = threadIdx.x;
  int v = (ln < NBLK) ? bsum[ln] : 0;
  int s = v;
  #pragma unroll
  for (int off = 1; off < 64; off <<= 1) {
    int u = __shfl_up(s, off, 64);
    if (ln >= off) s += u;
  }
  if (ln < NBLK) boff[ln] = s - v;
}
__global__ __launch_bounds__(256) void k_scan3(const int* __restrict__ loc,
                                               const int* __restrict__ boff,
                                               int* __restrict__ ptr,
                                               int* __restrict__ cur)
{
  int i = blockIdx.x * 256 + threadIdx.x;
  if (i < NN) {
    int v = loc[i] + boff[i >> 10];
    ptr[i] = v;
    cur[i] = v;
  }
}

// ---------------- CSR fill: CSR-ordered src + fp32 edge_attr ----------------
__global__ __launch_bounds__(256) void k_fill(
    const int* __restrict__ src, const int* __restrict__ dst,
    const float* __restrict__ ea, int* __restrict__ cur,
    int* __restrict__ srcc, float* __restrict__ eacf)
{
  int e = blockIdx.x * 256 + threadIdx.x;
  if (e < 128) srcc[NE + e] = 0;
  if (e < NE) {
    int d = dst[e];
    int s = atomicAdd(&cur[d], 1);
    srcc[s] = src[e];
    float4 q0 = *(const float4*)(ea + (size_t)e * 8);
    float4 q1 = *(const float4*)(ea + (size_t)e * 8 + 4);
    *(float4*)(eacf + (size_t)s * 8) = q0;
    *(float4*)(eacf + (size_t)s * 8 + 4) = q1;
  }
}

// ---------------- k_embed_y1: embed + layer-0 dual projection (fused) -------
// x = relu(nf@We+be); y1s = xb@W1[0:64]; y1d = xb@W1[64:128]+b1
__global__ __launch_bounds__(256, 4) void k_embed_y1(
    const float* __restrict__ nf, const float* __restrict__ We,
    const float* __restrict__ be,
    const short* __restrict__ w1f0, const float* __restrict__ b10,
    float* __restrict__ x, short* __restrict__ xb,
    short* __restrict__ y1s, short* __restrict__ y1d)
{
  const int t = threadIdx.x;
  const int wv = t >> 6, l = t & 63;
  const int m16 = l & 15, g = l >> 4;
  const int nb = blockIdx.x * 64 + wv * 16;
  if (nb >= NN) return;
  int row = nb + m16;
  const bool valid = row < NN;
  if (!valid) row = NN - 1;

  float nfv[7];
  #pragma unroll
  for (int k = 0; k < 7; ++k) nfv[k] = nf[row * 7 + k];
  float va[8], vb[8];
  #pragma unroll
  for (int j = 0; j < 8; ++j) {
    int cA = g * 8 + j, cB = 32 + g * 8 + j;
    float sa = be[cA], sb = be[cB];
    #pragma unroll
    for (int k = 0; k < 7; ++k) {
      sa += nfv[k] * We[k * 64 + cA];
      sb += nfv[k] * We[k * 64 + cB];
    }
    va[j] = fmaxf(sa, 0.f);
    vb[j] = fmaxf(sb, 0.f);
  }
  bf8_t a0, a1;
  #pragma unroll
  for (int j = 0; j < 8; ++j) { a0[j] = f2bf(va[j]); a1[j] = f2bf(vb[j]); }
  if (valid) {
    *(float4*)&x[(size_t)row * 64 + g * 8]          = make_float4(va[0], va[1], va[2], va[3]);
    *(float4*)&x[(size_t)row * 64 + g * 8 + 4]      = make_float4(va[4], va[5], va[6], va[7]);
    *(float4*)&x[(size_t)row * 64 + 32 + g * 8]     = make_float4(vb[0], vb[1], vb[2], vb[3]);
    *(float4*)&x[(size_t)row * 64 + 32 + g * 8 + 4] = make_float4(vb[4], vb[5], vb[6], vb[7]);
    *(bf8_t*)(xb + (size_t)row * 64 + g * 8) = a0;
    *(bf8_t*)(xb + (size_t)row * 64 + 32 + g * 8) = a1;
  }

  const short* wl = w1f0 + l * 8;
  f4_t accS[8], accD[8];
  #pragma unroll
  for (int nt = 0; nt < 8; ++nt) {
    float bv = b10[nt * 16 + m16];
    accS[nt] = (f4_t){0.f, 0.f, 0.f, 0.f};
    accD[nt] = (f4_t){bv, bv, bv, bv};
  }
  #pragma unroll
  for (int nt = 0; nt < 8; ++nt) {
    bf8_t b0 = *(const bf8_t*)(wl + (0 * 8 + nt) * 512);
    bf8_t b1f = *(const bf8_t*)(wl + (1 * 8 + nt) * 512);
    bf8_t b2f = *(const bf8_t*)(wl + (2 * 8 + nt) * 512);
    bf8_t b3f = *(const bf8_t*)(wl + (3 * 8 + nt) * 512);
    accS[nt] = MFMA16(a0, b0, accS[nt]);
    accS[nt] = MFMA16(a1, b1f, accS[nt]);
    accD[nt] = MFMA16(a0, b2f, accD[nt]);
    accD[nt] = MFMA16(a1, b3f, accD[nt]);
  }
  #pragma unroll
  for (int nt = 0; nt < 8; ++nt) {
    #pragma unroll
    for (int r = 0; r < 4; ++r) {
      int n = nb + g * 4 + r;
      if (n < NN) {
        y1s[(size_t)n * 128 + nt * 16 + m16] = f2bf(accS[nt][r]);
        y1d[(size_t)n * 128 + nt * 16 + m16] = f2bf(accD[nt][r]);
      }
    }
  }
}

// ---------------- k_msg_n: node-centric edge h + direct store ---------------
// Wave = one dst node n; edges [ptr[n], ptr[n]+cnt[n]) CSR-contiguous.
// h = relu(y1s[src] + y1d[n] + ea@W1e); hagg[n] = sum (plain store, no atomics)
__global__ __launch_bounds__(256, 8) void k_msg_n(
    const short* __restrict__ y1s, const short* __restrict__ y1d,
    const float* __restrict__ eacf, const int* __restrict__ srcc,
    const int* __restrict__ ptr, const int* __restrict__ cnt,
    const float* __restrict__ W1l,
    float* __restrict__ hagg)
{
  const int t = threadIdx.x;
  const int wv = t >> 6, ln = t & 63;
  const int n = blockIdx.x * 4 + wv;
  if (n >= NN) return;

  float we[8][2];
  #pragma unroll
  for (int f = 0; f < 8; ++f) {
    we[f][0] = W1l[(128 + f) * 128 + 2 * ln];
    we[f][1] = W1l[(128 + f) * 128 + 2 * ln + 1];
  }
  const int p0 = ptr[n];
  const int p1 = p0 + cnt[n];

  unsigned ydu = *(const unsigned*)(y1d + (size_t)n * 128 + 2 * ln);
  const float yd0 = bf_lo(ydu), yd1 = bf_hi(ydu);

  float s0 = 0.f, s1 = 0.f;
  int e = p0;
  for (; e + 2 <= p1; e += 2) {
    int sA = srcc[e];
    int sB = srcc[e + 1];
    unsigned ysA = *(const unsigned*)(y1s + (size_t)sA * 128 + 2 * ln);
    unsigned ysB = *(const unsigned*)(y1s + (size_t)sB * 128 + 2 * ln);
    float4 qa0 = *(const float4*)(eacf + (size_t)e * 8);
    float4 qa1 = *(const float4*)(eacf + (size_t)e * 8 + 4);
    float4 qb0 = *(const float4*)(eacf + (size_t)(e + 1) * 8);
    float4 qb1 = *(const float4*)(eacf + (size_t)(e + 1) * 8 + 4);
    float za0 = qa0.x * we[0][0] + qa0.y * we[1][0] + qa0.z * we[2][0] + qa0.w * we[3][0]
              + qa1.x * we[4][0] + qa1.y * we[5][0] + qa1.z * we[6][0] + qa1.w * we[7][0];
    float za1 = qa0.x * we[0][1] + qa0.y * we[1][1] + qa0.z * we[2][1] + qa0.w * we[3][1]
              + qa1.x * we[4][1] + qa1.y * we[5][1] + qa1.z * we[6][1] + qa1.w * we[7][1];
    float zb0 = qb0.x * we[0][0] + qb0.y * we[1][0] + qb0.z * we[2][0] + qb0.w * we[3][0]
              + qb1.x * we[4][0] + qb1.y * we[5][0] + qb1.z * we[6][0] + qb1.w * we[7][0];
    float zb1 = qb0.x * we[0][1] + qb0.y * we[1][1] + qb0.z * we[2][1] + qb0.w * we[3][1]
              + qb1.x * we[4][1] + qb1.y * we[5][1] + qb1.z * we[6][1] + qb1.w * we[7][1];
    s0 += fmaxf(bf_lo(ysA) + yd0 + za0, 0.f);
    s1 += fmaxf(bf_hi(ysA) + yd1 + za1, 0.f);
    s0 += fmaxf(bf_lo(ysB) + yd0 + zb0, 0.f);
    s1 += fmaxf(bf_hi(ysB) + yd1 + zb1, 0.f);
  }
  if (e < p1) {
    int sA = srcc[e];
    unsigned ysA = *(const unsigned*)(y1s + (size_t)sA * 128 + 2 * ln);
    float4 qa0 = *(const float4*)(eacf + (size_t)e * 8);
    float4 qa1 = *(const float4*)(eacf + (size_t)e * 8 + 4);
    float za0 = qa0.x * we[0][0] + qa0.y * we[1][0] + qa0.z * we[2][0] + qa0.w * we[3][0]
              + qa1.x * we[4][0] + qa1.y * we[5][0] + qa1.z * we[6][0] + qa1.w * we[7][0];
    float za1 = qa0.x * we[0][1] + qa0.y * we[1][1] + qa0.z * we[2][1] + qa0.w * we[3][1]
              + qa1.x * we[4][1] + qa1.y * we[5][1] + qa1.z * we[6][1] + qa1.w * we[7][1];
    s0 += fmaxf(bf_lo(ysA) + yd0 + za0, 0.f);
    s1 += fmaxf(bf_hi(ysA) + yd1 + za1, 0.f);
  }
  *(float2*)(hagg + (size_t)n * 128 + 2 * ln) = make_float2(s0, s1);
}

// ---------------- k_node: agg@W2 + update-MLP + residual + LN + next-y1 -----
// Fused epilogue: after LN, stage new x tile in per-wave LDS and compute the
// next stage's dual projection (wfn/b1n = msg W1[l+1] or pred W1).
__global__ __launch_bounds__(256, 4) void k_node(
    float* __restrict__ x, short* __restrict__ xb,
    const float* __restrict__ hagg, const int* __restrict__ cnt,
    const short* __restrict__ w2f_l, const float* __restrict__ b2,
    const short* __restrict__ wuf_l, const float* __restrict__ bu,
    const float* __restrict__ lng, const float* __restrict__ lnb,
    const short* __restrict__ wfn, const float* __restrict__ b1n,
    short* __restrict__ y1s, short* __restrict__ y1d)
{
  __shared__ short sH[4 * 16 * 136];   // 17.4 KB
  const int t = threadIdx.x;
  const int wv = t >> 6, l = t & 63;
  const int m16 = l & 15, g = l >> 4;
  const int nb = blockIdx.x * 64 + wv * 16;
  if (nb >= NN) return;
  int row = nb + m16; if (row >= NN) row = NN - 1;

  const float* hr = hagg + (size_t)row * 128;
  bf8_t a2[4];
  #pragma unroll
  for (int ks = 0; ks < 4; ++ks) {
    float4 q0 = *(const float4*)(hr + ks * 32 + g * 8);
    float4 q1 = *(const float4*)(hr + ks * 32 + g * 8 + 4);
    bf8_t av = {f2bf(q0.x), f2bf(q0.y), f2bf(q0.z), f2bf(q0.w),
                f2bf(q1.x), f2bf(q1.y), f2bf(q1.z), f2bf(q1.w)};
    a2[ks] = av;
  }
  float dg[4], iv[4];
  #pragma unroll
  for (int r = 0; r < 4; ++r) {
    int n = nb + g * 4 + r;
    int c = (n < NN) ? cnt[n] : 0;
    dg[r] = (float)c;
    iv[r] = 1.f / ((float)c + 1e-6f);
  }

  const short* w2l = w2f_l + l * 8;
  f4_t aacc[8];
  #pragma unroll
  for (int nt = 0; nt < 8; ++nt) {
    float bv = b2[nt * 16 + m16];
    aacc[nt] = (f4_t){dg[0] * bv, dg[1] * bv, dg[2] * bv, dg[3] * bv};
  }
  #pragma unroll
  for (int ks = 0; ks < 4; ++ks) {
    #pragma unroll
    for (int nt = 0; nt < 8; ++nt) {
      bf8_t bf = *(const bf8_t*)(w2l + (ks * 8 + nt) * 512);
      aacc[nt] = MFMA16(a2[ks], bf, aacc[nt]);
    }
  }

  short* sh = sH + wv * (16 * 136);
  #pragma unroll
  for (int nt = 0; nt < 8; ++nt) {
    #pragma unroll
    for (int r = 0; r < 4; ++r) {
      sh[(g * 4 + r) * 136 + nt * 16 + m16] = f2bf(aacc[nt][r] * iv[r]);
    }
  }

  const short* xr = xb + (size_t)row * 64;
  bf8_t a0 = *(const bf8_t*)(xr + g * 8);
  bf8_t a1 = *(const bf8_t*)(xr + 32 + g * 8);
  const short* wul = wuf_l + l * 8;
  f4_t acc[4];
  #pragma unroll
  for (int nt = 0; nt < 4; ++nt) {
    float bv = bu[nt * 16 + m16];
    acc[nt] = (f4_t){bv, bv, bv, bv};
  }
  #pragma unroll
  for (int nt = 0; nt < 4; ++nt) {
    acc[nt] = MFMA16(a0, *(const bf8_t*)(wul + (0 * 4 + nt) * 512), acc[nt]);
    acc[nt] = MFMA16(a1, *(const bf8_t*)(wul + (1 * 4 + nt) * 512), acc[nt]);
  }
  #pragma unroll
  for (int ks = 0; ks < 4; ++ks) {
    bf8_t af = *(const bf8_t*)(sh + m16 * 136 + ks * 32 + g * 8);
    #pragma unroll
    for (int nt = 0; nt < 4; ++nt) {
      acc[nt] = MFMA16(af, *(const bf8_t*)(wul + ((2 + ks) * 4 + nt) * 512), acc[nt]);
    }
  }

  float ov[4][4];
  #pragma unroll
  for (int nt = 0; nt < 4; ++nt) {
    #pragma unroll
    for (int r = 0; r < 4; ++r) {
      int n = nb + g * 4 + r;
      float xv = (n < NN) ? x[(size_t)n * 64 + nt * 16 + m16] : 0.f;
      ov[nt][r] = xv + fmaxf(acc[nt][r], 0.f);
    }
  }
  // LN + write x/xb + stage new x into per-wave LDS (for next-y1 MFMA)
  #pragma unroll
  for (int r = 0; r < 4; ++r) {
    float s1 = ov[0][r] + ov[1][r] + ov[2][r] + ov[3][r];
    float s2 = ov[0][r] * ov[0][r] + ov[1][r] * ov[1][r] +
               ov[2][r] * ov[2][r] + ov[3][r] * ov[3][r];
    #pragma unroll
    for (int off = 1; off < 16; off <<= 1) {
      s1 += __shfl_xor(s1, off, 64);
      s2 += __shfl_xor(s2, off, 64);
    }
    float mu = s1 * 0.015625f;
    float var = s2 * 0.015625f - mu * mu;
    float rs = rsqrtf(var + 1e-5f);
    int n = nb + g * 4 + r;
    #pragma unroll
    for (int nt = 0; nt < 4; ++nt) {
      int col = nt * 16 + m16;
      float y = (ov[nt][r] - mu) * rs * lng[col] + lnb[col];
      short yb = f2bf(y);
      sh[(g * 4 + r) * 136 + col] = yb;
      if (n < NN) {
        x[(size_t)n * 64 + col] = y;
        xb[(size_t)n * 64 + col] = yb;
      }
    }
  }

  // ---- next-stage dual projection from the fresh x tile (same-wave LDS) ----
  bf8_t ya0 = *(const bf8_t*)(sh + m16 * 136 + g * 8);
  bf8_t ya1 = *(const bf8_t*)(sh + m16 * 136 + 32 + g * 8);
  const short* wl = wfn + l * 8;
  f4_t accS[8], accD[8];
  #pragma unroll
  for (int nt = 0; nt < 8; ++nt) {
    float bv = b1n[nt * 16 + m16];
    accS[nt] = (f4_t){0.f, 0.f, 0.f, 0.f};
    accD[nt] = (f4_t){bv, bv, bv, bv};
  }
  #pragma unroll
  for (int nt = 0; nt < 8; ++nt) {
    bf8_t b0 = *(const bf8_t*)(wl + (0 * 8 + nt) * 512);
    bf8_t b1f = *(const bf8_t*)(wl + (1 * 8 + nt) * 512);
    bf8_t b2f = *(const bf8_t*)(wl + (2 * 8 + nt) * 512);
    bf8_t b3f = *(const bf8_t*)(wl + (3 * 8 + nt) * 512);
    accS[nt] = MFMA16(ya0, b0, accS[nt]);
    accS[nt] = MFMA16(ya1, b1f, accS[nt]);
    accD[nt] = MFMA16(ya0, b2f, accD[nt]);
    accD[nt] = MFMA16(ya1, b3f, accD[nt]);
  }
  #pragma unroll
  for (int nt = 0; nt < 8; ++nt) {
    #pragma unroll
    for (int r = 0; r < 4; ++r) {
      int n = nb + g * 4 + r;
      if (n < NN) {
        y1s[(size_t)n * 128 + nt * 16 + m16] = f2bf(accS[nt][r]);
        y1d[(size_t)n * 128 + nt * 16 + m16] = f2bf(accD[nt][r]);
      }
    }
  }
}

// ---------------- k_pred2: edge predictor via linear split ------------------
__global__ __launch_bounds__(256, 4) void k_pred2(
    const short* __restrict__ py1s, const short* __restrict__ py1d,
    const short* __restrict__ eab,
    const int* __restrict__ src, const int* __restrict__ dst,
    const float* __restrict__ pW1,
    const short* __restrict__ pw2f, const float* __restrict__ b2,
    const float* __restrict__ W3, const float* __restrict__ b3,
    float* __restrict__ out)
{
  __shared__ short sH[4 * 16 * 136];   // 17.4 KB
  const int t = threadIdx.x;
  const int wv = t >> 6, ln = t & 63;
  const int m16 = ln & 15, g = ln >> 4;
  const int p0 = blockIdx.x * 64 + wv * 16;
  if (p0 >= NE) return;

  float we[8][2];
  #pragma unroll
  for (int f = 0; f < 8; ++f) {
    we[f][0] = pW1[(128 + f) * 128 + 2 * ln];
    we[f][1] = pW1[(128 + f) * 128 + 2 * ln + 1];
  }
  const int li = ln & 15;
  int ei0 = p0 + li; if (ei0 >= NE) ei0 = NE - 1;
  int srcv = src[ei0];
  int dstv = dst[ei0];
  int ee = p0 + (ln >> 2); if (ee >= NE) ee = NE - 1;
  unsigned eaw = ((const unsigned*)eab)[(size_t)ee * 4 + (ln & 3)];

  unsigned ys[16], yd[16];
  #pragma unroll
  for (int i = 0; i < 16; ++i) {
    int s = __shfl(srcv, i, 64);
    int d = __shfl(dstv, i, 64);
    ys[i] = *(const unsigned*)(py1s + (size_t)s * 128 + 2 * ln);
    yd[i] = *(const unsigned*)(py1d + (size_t)d * 128 + 2 * ln);
  }

  short* sh = sH + wv * (16 * 136);
  #pragma unroll
  for (int i = 0; i < 16; ++i) {
    float z0 = 0.f, z1 = 0.f;
    #pragma unroll
    for (int w = 0; w < 4; ++w) {
      unsigned u = __shfl(eaw, 4 * i + w, 64);
      float e0 = bf_lo(u), e1 = bf_hi(u);
      z0 += e0 * we[2 * w][0] + e1 * we[2 * w + 1][0];
      z1 += e0 * we[2 * w][1] + e1 * we[2 * w + 1][1];
    }
    float h0 = fmaxf(bf_lo(ys[i]) + bf_lo(yd[i]) + z0, 0.f);
    float h1 = fmaxf(bf_hi(ys[i]) + bf_hi(yd[i]) + z1, 0.f);
    unsigned hv = (unsigned)(unsigned short)f2bf(h0) |
                  ((unsigned)(unsigned short)f2bf(h1) << 16);
    *(unsigned*)(sh + i * 136 + 2 * ln) = hv;
  }

  f4_t acc2[4];
  #pragma unroll
  for (int nt = 0; nt < 4; ++nt) {
    float bv = b2[nt * 16 + m16];
    acc2[nt] = (f4_t){bv, bv, bv, bv};
  }
  const short* w2l = pw2f + ln * 8;
  #pragma unroll
  for (int ks = 0; ks < 4; ++ks) {
    bf8_t af = *(const bf8_t*)(sh + m16 * 136 + ks * 32 + g * 8);
    #pragma unroll
    for (int nt = 0; nt < 4; ++nt) {
      bf8_t bf = *(const bf8_t*)(w2l + (ks * 4 + nt) * 512);
      acc2[nt] = MFMA16(af, bf, acc2[nt]);
    }
  }

  float w3v[4];
  #pragma unroll
  for (int nt = 0; nt < 4; ++nt) w3v[nt] = W3[nt * 16 + m16];
  const float b3v = b3[0];
  #pragma unroll
  for (int r = 0; r < 4; ++r) {
    float v = fmaxf(acc2[0][r], 0.f) * w3v[0] + fmaxf(acc2[1][r], 0.f) * w3v[1] +
              fmaxf(acc2[2][r], 0.f) * w3v[2] + fmaxf(acc2[3][r], 0.f) * w3v[3];
    #pragma unroll
    for (int off = 1; off < 16; off <<= 1) v += __shfl_xor(v, off, 64);
    int e = p0 + g * 4 + r;
    if (m16 == 0 && e < NE) out[e] = tanhf(v + b3v);
  }
}

extern "C" void kernel_launch(void* const* d_in, const int* in_sizes, int n_in,
                              void* d_out, int out_size, void* d_ws, size_t ws_size,
                              hipStream_t stream)
{
  (void)in_sizes; (void)n_in; (void)out_size; (void)ws_size;
  const float* nf  = (const float*)d_in[0];
  const float* ea  = (const float*)d_in[1];
  const float* eW  = (const float*)d_in[2];
  const float* eb  = (const float*)d_in[3];
  const float* mW1 = (const float*)d_in[4];
  const float* mb1 = (const float*)d_in[5];
  const float* mW2 = (const float*)d_in[6];
  const float* mb2 = (const float*)d_in[7];
  const float* uW  = (const float*)d_in[8];
  const float* ub  = (const float*)d_in[9];
  const float* lg  = (const float*)d_in[10];
  const float* lb  = (const float*)d_in[11];
  const float* pW1 = (const float*)d_in[12];
  const float* pb1 = (const float*)d_in[13];
  const float* pW2 = (const float*)d_in[14];
  const float* pb2 = (const float*)d_in[15];
  const float* pW3 = (const float*)d_in[16];
  const float* pb3 = (const float*)d_in[17];
  const int*   ei  = (const int*)d_in[18];
  const int* srcI = ei;
  const int* dstI = ei + NE;
  float* out = (float*)d_out;

  // workspace (~98 MB)
  char* w = (char*)d_ws;
  float* x    = (float*)w;  w += (size_t)NN * 64 * 4;
  float* hagg = (float*)w;  w += (size_t)NN * 128 * 4;
  short* xb   = (short*)w;  w += (size_t)NN * 64 * 2;
  short* eab  = (short*)w;  w += (size_t)NE * 8 * 2;
  float* eacf = (float*)w;  w += (size_t)NE * 8 * 4;
  short* y1s  = (short*)w;  w += (size_t)NN * 128 * 2;
  short* y1d  = (short*)w;  w += (size_t)NN * 128 * 2;
  short* w1f  = (short*)w;  w += (size_t)3 * 20480 * 2;
  short* w2f  = (short*)w;  w += (size_t)3 * 16384 * 2;
  short* wuf  = (short*)w;  w += (size_t)3 * 12288 * 2;
  short* pw1f = (short*)w;  w += (size_t)20480 * 2;
  short* pw2f = (short*)w;  w += (size_t)8192 * 2;
  int*   cnt  = (int*)w;    w += (size_t)NN * 4;
  int*   loc  = (int*)w;    w += (size_t)NN * 4;
  int*   ptr  = (int*)w;    w += (size_t)NN * 4;
  int*   cur  = (int*)w;    w += (size_t)NN * 4;
  int*   bsum = (int*)w;    w += (size_t)64 * 4;
  int*   boff = (int*)w;    w += (size_t)64 * 4;
  int*   srcc = (int*)w;    w += (size_t)(NE + 128) * 4;

  k_zero_i<<<64, 256, 0, stream>>>(cnt, NN);
  k_hist<<<(NE + 255) / 256, 256, 0, stream>>>(dstI, cnt);
  k_scan1<<<NBLK, 1024, 0, stream>>>(cnt, loc, bsum);
  k_scan2<<<1, 64, 0, stream>>>(bsum, boff);
  k_scan3<<<(NN + 255) / 256, 256, 0, stream>>>(loc, boff, ptr, cur);
  k_fill<<<(NE + 255) / 256, 256, 0, stream>>>(srcI, dstI, ea, cur, srcc, eacf);
  k_prep_ea<<<(NE * 2 + 255) / 256, 256, 0, stream>>>(ea, eab);
  k_prep_all<<<(176128 + 255) / 256, 256, 0, stream>>>(
      mW1, mW2, uW, pW1, pW2, w1f, w2f, wuf, pw1f, pw2f);

  const int ngrid = (NN + 63) / 64;
  const int egrid = (NE + 63) / 64;
  const int mgrid = (NN + 3) / 4;

  k_embed_y1<<<ngrid, 256, 0, stream>>>(nf, eW, eb, w1f, mb1, x, xb, y1s, y1d);

  for (int l = 0; l < 3; ++l) {
    k_msg_n<<<mgrid, 256, 0, stream>>>(y1s, y1d, eacf, srcc, ptr, cnt,
        mW1 + (size_t)l * 136 * 128, hagg);
    const short* wfn = (l < 2) ? (w1f + (size_t)(l + 1) * 20480) : pw1f;
    const float* b1n = (l < 2) ? (mb1 + (size_t)(l + 1) * 128) : pb1;
    k_node<<<ngrid, 256, 0, stream>>>(x, xb, hagg, cnt,
        w2f + (size_t)l * 16384, mb2 + (size_t)l * 128,
        wuf + (size_t)l * 12288, ub + (size_t)l * 64,
        lg + (size_t)l * 64, lb + (size_t)l * 64,
        wfn, b1n, y1s, y1d);
  }
  k_pred2<<<egrid, 256, 0, stream>>>(y1s, y1d, eab, srcI, dstI,
      pW1, pw2f, pb2, pW3, pb3, out);
}